// Round 1
// baseline (502.541 us; speedup 1.0000x reference)
//
#include <hip/hip_runtime.h>
#include <cstdio>

// ---------------------------------------------------------------------------
// PairAttnDecoderRNN forward, MI355X/gfx950.
// Pipeline: conv->bf16, GEMMs via mfma_f32_16x16x32_bf16 (128x128 tile,
// BK=64, XOR-swizzled LDS), fused attention/gather kernels, GRU pointwise.
// Weights converted/transposed to (N,K) bf16 in workspace each launch.
// ---------------------------------------------------------------------------

using f32x4  = __attribute__((ext_vector_type(4))) float;
using bf16x8 = __attribute__((ext_vector_type(8))) short;

__device__ __forceinline__ unsigned short f2bf(float x) {
    unsigned u = __builtin_bit_cast(unsigned, x);
    u += 0x7fffu + ((u >> 16) & 1u);          // RNE
    return (unsigned short)(u >> 16);
}
__device__ __forceinline__ float bf2f(unsigned short u) {
    return __builtin_bit_cast(float, ((unsigned)u) << 16);
}

// ---------------- elementwise fp32 -> bf16 ----------------
__global__ __launch_bounds__(256) void conv_bf16_kernel(
    const float* __restrict__ in, unsigned short* __restrict__ out, int n4)
{
    int i = blockIdx.x * 256 + threadIdx.x;
    if (i >= n4) return;
    float4 v = ((const float4*)in)[i];
    ushort4 o = make_ushort4(f2bf(v.x), f2bf(v.y), f2bf(v.z), f2bf(v.w));
    ((ushort4*)out)[i] = o;
}

// ---------------- (R,C) fp32 -> (C,R) bf16 transpose ----------------
__global__ __launch_bounds__(256) void transpose_conv_kernel(
    const float* __restrict__ in, unsigned short* __restrict__ out, int R, int C)
{
    __shared__ float t[32][33];
    int tx = threadIdx.x & 31, ty = threadIdx.x >> 5;   // 32 x 8
    int c0 = blockIdx.x * 32, r0 = blockIdx.y * 32;
    #pragma unroll
    for (int i = 0; i < 4; ++i)
        t[ty + 8*i][tx] = in[(size_t)(r0 + ty + 8*i) * C + (c0 + tx)];
    __syncthreads();
    #pragma unroll
    for (int i = 0; i < 4; ++i)
        out[(size_t)(c0 + ty + 8*i) * R + (r0 + tx)] = f2bf(t[tx][ty + 8*i]);
}

// ---------------- bf16 MFMA GEMM: C(M,N) = A(M,K) * Bt(N,K)^T (+bias) -------
// 128x128 tile, BK=64, 4 waves in 2x2, each wave 64x64 = 4x4 frags of 16x16.
// LDS XOR swizzle: byte ^= (row&7)<<4  (G4 fix for stride-128B b128 reads).
template<bool HAS_BIAS, bool OUT_BF16>
__global__ __launch_bounds__(256) void gemm_kernel(
    const unsigned short* __restrict__ A, const unsigned short* __restrict__ Bt,
    const float* __restrict__ bias, void* __restrict__ Cout,
    int M, int N, int K)
{
    __shared__ unsigned short lA[128 * 64];
    __shared__ unsigned short lB[128 * 64];
    const int tid  = threadIdx.x;
    const int lane = tid & 63;
    const int wave = tid >> 6;
    const int wr = wave >> 1, wc = wave & 1;
    const int m0 = blockIdx.y * 128, n0 = blockIdx.x * 128;
    const int srow = tid >> 3;     // 0..31
    const int schunk = tid & 7;    // 0..7 (16B chunks within a 64-elem row)
    const int lm = lane & 15;
    const int lk = (lane >> 4) * 8;

    f32x4 acc[4][4];
    #pragma unroll
    for (int m = 0; m < 4; ++m)
        #pragma unroll
        for (int n = 0; n < 4; ++n) {
            f32x4 z = {0.f, 0.f, 0.f, 0.f};
            acc[m][n] = z;
        }

    for (int kt = 0; kt < K; kt += 64) {
        #pragma unroll
        for (int i = 0; i < 4; ++i) {
            int r = srow + 32 * i;
            int wbyte = r * 128 + ((schunk ^ (r & 7)) * 16);
            *(int4*)((char*)lA + wbyte) =
                *(const int4*)(A + (size_t)(m0 + r) * K + kt + schunk * 8);
            *(int4*)((char*)lB + wbyte) =
                *(const int4*)(Bt + (size_t)(n0 + r) * K + kt + schunk * 8);
        }
        __syncthreads();
        #pragma unroll
        for (int kk = 0; kk < 2; ++kk) {
            bf16x8 af[4], bv[4];
            #pragma unroll
            for (int m = 0; m < 4; ++m) {
                int r = wr * 64 + m * 16 + lm;
                int byte = (r * 128 + (kk * 32 + lk) * 2) ^ ((r & 7) << 4);
                af[m] = *(const bf16x8*)((const char*)lA + byte);
            }
            #pragma unroll
            for (int n = 0; n < 4; ++n) {
                int r = wc * 64 + n * 16 + lm;
                int byte = (r * 128 + (kk * 32 + lk) * 2) ^ ((r & 7) << 4);
                bv[n] = *(const bf16x8*)((const char*)lB + byte);
            }
            #pragma unroll
            for (int m = 0; m < 4; ++m)
                #pragma unroll
                for (int n = 0; n < 4; ++n)
                    acc[m][n] = __builtin_amdgcn_mfma_f32_16x16x32_bf16(
                        af[m], bv[n], acc[m][n], 0, 0, 0);
        }
        __syncthreads();
    }

    // epilogue: C/D layout col=lane&15, row=(lane>>4)*4+j  [m89/m91 verified]
    const int rbase = m0 + wr * 64 + (lane >> 4) * 4;
    const int cbase = n0 + wc * 64 + lm;
    #pragma unroll
    for (int m = 0; m < 4; ++m) {
        #pragma unroll
        for (int n = 0; n < 4; ++n) {
            int col = cbase + n * 16;
            float bvv = HAS_BIAS ? bias[col] : 0.0f;
            #pragma unroll
            for (int j = 0; j < 4; ++j) {
                int row = rbase + m * 16 + j;
                float v = acc[m][n][j] + bvv;
                if (OUT_BF16)
                    ((unsigned short*)Cout)[(size_t)row * N + col] = f2bf(v);
                else
                    ((float*)Cout)[(size_t)row * N + col] = v;
            }
        }
    }
}

// ---------------- ingredient attention: scores -> argmax -> gather ----------
// scores_i[m] = sum_h tanh(q[h]+key[b,m,h])*wa[h]; softmax skipped (monotone,
// only argmax consumed). Gathers comp_emb rows to bf16.
__global__ __launch_bounds__(256) void attn_ingr_kernel(
    const float* __restrict__ query, const float* __restrict__ key,
    const float* __restrict__ wa,
    const int* __restrict__ input_tensor, const int* __restrict__ pairing_ids,
    const float* __restrict__ enc_emb,
    unsigned short* __restrict__ comp_embb)
{
    const int b = blockIdx.x;
    const int tid = threadIdx.x;
    const int lane = tid & 63, wave = tid >> 6;
    __shared__ float s_sc[20];
    __shared__ int s_cids[20];
    __shared__ int s_ing;
    const float* q = query + (size_t)b * 1024;
    for (int m = wave; m < 20; m += 4) {
        const float* kr = key + ((size_t)b * 20 + m) * 1024;
        float p = 0.f;
        for (int h = lane; h < 1024; h += 64)
            p += tanhf(q[h] + kr[h]) * wa[h];
        #pragma unroll
        for (int off = 32; off > 0; off >>= 1)
            p += __shfl_down(p, off);
        if (lane == 0) s_sc[m] = p;
    }
    __syncthreads();
    if (tid == 0) {
        float best = s_sc[0]; int bi = 0;
        for (int m = 1; m < 20; ++m)
            if (s_sc[m] > best) { best = s_sc[m]; bi = m; }   // first-max tiebreak
        s_ing = input_tensor[b * 20 + bi];
    }
    __syncthreads();
    if (tid < 20) s_cids[tid] = pairing_ids[s_ing * 20 + tid];
    __syncthreads();
    for (int idx = tid; idx < 20 * 512; idx += 256) {        // float4 units
        int k = idx >> 9, c = idx & 511;
        float4 v = ((const float4*)(enc_emb + (size_t)s_cids[k] * 2048))[c];
        ushort4 o = make_ushort4(f2bf(v.x), f2bf(v.y), f2bf(v.z), f2bf(v.w));
        ((ushort4*)(comp_embb + ((size_t)b * 20 + k) * 2048))[c] = o;
    }
}

// ---------------- pairing attention + out_pair assembly ----------------
__global__ __launch_bounds__(256) void attn_pair_kernel(
    const float* __restrict__ qp, const float* __restrict__ kp,
    const float* __restrict__ wa, const float* __restrict__ ba_p,
    const unsigned short* __restrict__ comp_embb,
    const float* __restrict__ emb_dec, const int* __restrict__ input_ids,
    unsigned short* __restrict__ out_pairb)
{
    const int b = blockIdx.x;
    const int tid = threadIdx.x;
    const int lane = tid & 63, wave = tid >> 6;
    __shared__ float s_s[20];
    __shared__ float s_as[20];
    const float* q = qp + (size_t)b * 1024;
    for (int m = wave; m < 20; m += 4) {
        const float* kr = kp + ((size_t)b * 20 + m) * 1024;
        float p = 0.f;
        for (int h = lane; h < 1024; h += 64)
            p += tanhf(q[h] + kr[h]) * wa[h];
        #pragma unroll
        for (int off = 32; off > 0; off >>= 1)
            p += __shfl_down(p, off);
        if (lane == 0) s_s[m] = p + ba_p[0];
    }
    __syncthreads();
    if (tid == 0) {
        float mx = s_s[0];
        for (int m = 1; m < 20; ++m) mx = fmaxf(mx, s_s[m]);
        float e[20]; float den = 0.f;
        for (int m = 0; m < 20; ++m) { e[m] = expf(s_s[m] - mx); den += e[m]; }
        float inv = 1.f / den;
        for (int m = 0; m < 20; ++m) s_as[m] = e[m] * inv * s_s[m]; // a_p * s_p
    }
    __syncthreads();
    // emb part: out_pair[:,0:1024]
    {
        float4 v = ((const float4*)(emb_dec + (size_t)input_ids[b] * 1024))[tid];
        ushort4 o = make_ushort4(f2bf(v.x), f2bf(v.y), f2bf(v.z), f2bf(v.w));
        ((ushort4*)(out_pairb + (size_t)b * 3072))[tid] = o;
    }
    // attn_app part: out_pair[:,1024:3072], thread handles 8 contiguous d
    float a0[8] = {0,0,0,0,0,0,0,0};
    for (int k = 0; k < 20; ++k) {
        float a = s_as[k];
        const ushort4* crow =
            (const ushort4*)(comp_embb + ((size_t)b * 20 + k) * 2048 + tid * 8);
        ushort4 u0 = crow[0], u1 = crow[1];
        a0[0] += a * bf2f(u0.x); a0[1] += a * bf2f(u0.y);
        a0[2] += a * bf2f(u0.z); a0[3] += a * bf2f(u0.w);
        a0[4] += a * bf2f(u1.x); a0[5] += a * bf2f(u1.y);
        a0[6] += a * bf2f(u1.z); a0[7] += a * bf2f(u1.w);
    }
    unsigned short* op = out_pairb + (size_t)b * 3072 + 1024 + tid * 8;
    #pragma unroll
    for (int j = 0; j < 8; ++j) op[j] = f2bf(a0[j]);
}

// ---------------- GRU pointwise (torch gate order r,z,n) ----------------
__global__ __launch_bounds__(256) void gru_kernel(
    const float* __restrict__ gi, const float* __restrict__ gh,
    const float* __restrict__ h, unsigned short* __restrict__ hnewb)
{
    int idx = blockIdx.x * 256 + threadIdx.x;       // 262144 total
    int b = idx >> 10, j = idx & 1023;
    const float* gib = gi + (size_t)b * 3072;
    const float* ghb = gh + (size_t)b * 3072;
    float r = 1.f / (1.f + expf(-(gib[j] + ghb[j])));
    float z = 1.f / (1.f + expf(-(gib[1024 + j] + ghb[1024 + j])));
    float n = tanhf(gib[2048 + j] + r * ghb[2048 + j]);
    float hv = h[idx];
    hnewb[idx] = f2bf((1.f - z) * n + z * hv);
}

// ---------------------------------------------------------------------------
extern "C" void kernel_launch(void* const* d_in, const int* in_sizes, int n_in,
                              void* d_out, int out_size, void* d_ws, size_t ws_size,
                              hipStream_t stream)
{
    const int*   input_ids    = (const int*)  d_in[0];
    const float* hidden       = (const float*)d_in[1];
    const float* enc_out      = (const float*)d_in[2];
    const int*   input_tensor = (const int*)  d_in[3];
    const int*   pairing_ids  = (const int*)  d_in[4];
    const float* emb_dec      = (const float*)d_in[5];
    const float* enc_emb      = (const float*)d_in[6];
    const float* Wq_i  = (const float*)d_in[7];
    const float* Wk_i  = (const float*)d_in[8];
    const float* wa_i  = (const float*)d_in[9];
    const float* Wq_p  = (const float*)d_in[10];
    const float* Wk_p  = (const float*)d_in[11];
    const float* wa_p  = (const float*)d_in[12];
    const float* ba_p  = (const float*)d_in[13];
    const float* W_lin = (const float*)d_in[14];
    const float* b_lin = (const float*)d_in[15];
    const float* W_ih  = (const float*)d_in[16];
    const float* W_hh  = (const float*)d_in[17];
    const float* b_ih  = (const float*)d_in[18];
    const float* b_hh  = (const float*)d_in[19];
    const float* W_out = (const float*)d_in[20];
    const float* b_out = (const float*)d_in[21];

    // Workspace layout (79,167,488 B total). Arena is overlaid: the 65.5 MB
    // W_out^T transpose reuses buffers that are dead by the time it runs.
    constexpr size_t OFF_HB    = 0;          // 524,288
    constexpr size_t OFF_HNEW  = 524288;     // 524,288
    constexpr size_t OFF_WT    = 1048576;    // 12,582,912 (largest small weight)
    constexpr size_t OFF_ARENA = 13631488;   // 65,536,000
    constexpr size_t NEED      = OFF_ARENA + 65536000;
    if (ws_size < NEED) {
        fprintf(stderr, "kernel_launch: ws_size %zu < needed %zu\n", ws_size, NEED);
        return;
    }
    char* ws    = (char*)d_ws;
    unsigned short* hb    = (unsigned short*)(ws + OFF_HB);
    unsigned short* hnewb = (unsigned short*)(ws + OFF_HNEW);
    unsigned short* Wt    = (unsigned short*)(ws + OFF_WT);
    char* arena = ws + OFF_ARENA;
    unsigned short* encb  = (unsigned short*)(arena + 0);         // -> comp_embb
    float*          query = (float*)         (arena + 20971520);  // -> q_p
    float*          key   = (float*)         (arena + 22020096);  // -> k_p
    unsigned short* outp  = (unsigned short*)(arena + 42991616);
    unsigned short* xb    = (unsigned short*)(arena + 44564480);
    float*          gi    = (float*)         (arena + 45613056);
    float*          gh    = (float*)         (arena + 48758784);
    unsigned short* Wbig  = (unsigned short*)arena;               // W_out^T (step 13)

    // 1,2: activations -> bf16
    conv_bf16_kernel<<<256,   256, 0, stream>>>(hidden,  hb,   65536);
    conv_bf16_kernel<<<10240, 256, 0, stream>>>(enc_out, encb, 2621440);

    // G1: query = h @ Wq_i               (256,1024,K=1024)
    transpose_conv_kernel<<<dim3(32, 32), 256, 0, stream>>>(Wq_i, Wt, 1024, 1024);
    gemm_kernel<false,false><<<dim3(8, 2), 256, 0, stream>>>(hb, Wt, nullptr, query, 256, 1024, 1024);

    // G2: key = enc @ Wk_i               (5120,1024,K=2048)
    transpose_conv_kernel<<<dim3(32, 64), 256, 0, stream>>>(Wk_i, Wt, 2048, 1024);
    gemm_kernel<false,false><<<dim3(8, 40), 256, 0, stream>>>(encb, Wt, nullptr, key, 5120, 1024, 2048);

    // ingredient attention + gather (comp_embb overlays encb — encb is dead)
    attn_ingr_kernel<<<256, 256, 0, stream>>>(query, key, wa_i, input_tensor,
                                              pairing_ids, enc_emb, encb);

    // G3: q_p = h @ Wq_p
    transpose_conv_kernel<<<dim3(32, 32), 256, 0, stream>>>(Wq_p, Wt, 1024, 1024);
    gemm_kernel<false,false><<<dim3(8, 2), 256, 0, stream>>>(hb, Wt, nullptr, query, 256, 1024, 1024);

    // G4: k_p = comp_emb @ Wk_p          (5120,1024,K=2048)
    transpose_conv_kernel<<<dim3(32, 64), 256, 0, stream>>>(Wk_p, Wt, 2048, 1024);
    gemm_kernel<false,false><<<dim3(8, 40), 256, 0, stream>>>(encb, Wt, nullptr, key, 5120, 1024, 2048);

    // pairing attention -> out_pair (emb | attn_app) bf16
    attn_pair_kernel<<<256, 256, 0, stream>>>(query, key, wa_p, ba_p, encb,
                                              emb_dec, input_ids, outp);

    // G5: x = out_pair @ W_lin + b_lin   (256,2048,K=3072) -> bf16
    transpose_conv_kernel<<<dim3(64, 96), 256, 0, stream>>>(W_lin, Wt, 3072, 2048);
    gemm_kernel<true,true><<<dim3(16, 2), 256, 0, stream>>>(outp, Wt, b_lin, xb, 256, 2048, 3072);

    // G6: gi = x @ W_ih^T + b_ih         (256,3072,K=2048); W_ih already (N,K)
    conv_bf16_kernel<<<6144, 256, 0, stream>>>(W_ih, Wt, 1572864);
    gemm_kernel<true,false><<<dim3(24, 2), 256, 0, stream>>>(xb, Wt, b_ih, gi, 256, 3072, 2048);

    // G7: gh = h @ W_hh^T + b_hh         (256,3072,K=1024)
    conv_bf16_kernel<<<3072, 256, 0, stream>>>(W_hh, Wt, 786432);
    gemm_kernel<true,false><<<dim3(24, 2), 256, 0, stream>>>(hb, Wt, b_hh, gh, 256, 3072, 1024);

    // GRU pointwise -> h_new bf16
    gru_kernel<<<1024, 256, 0, stream>>>(gi, gh, hidden, hnewb);

    // G8: logits = h_new @ W_out + b_out (256,32000,K=1024)
    transpose_conv_kernel<<<dim3(1000, 32), 256, 0, stream>>>(W_out, Wbig, 1024, 32000);
    gemm_kernel<true,false><<<dim3(250, 2), 256, 0, stream>>>(hnewb, Wbig, b_out,
                                                              (float*)d_out, 256, 32000, 1024);
}

// Round 2
// 438.976 us; speedup vs baseline: 1.1448x; 1.1448x over previous
//
#include <hip/hip_runtime.h>
#include <cstdio>

// ---------------------------------------------------------------------------
// PairAttnDecoderRNN forward, MI355X/gfx950.  Round 2:
//  - attention glue split into high-parallelism stages (was 75us latency-bound)
//  - GEMM staging via global_load_lds width=16, linear LDS (m97 structure)
// ---------------------------------------------------------------------------

using f32x4  = __attribute__((ext_vector_type(4))) float;
using bf16x8 = __attribute__((ext_vector_type(8))) short;

__device__ __forceinline__ unsigned short f2bf(float x) {
    unsigned u = __builtin_bit_cast(unsigned, x);
    u += 0x7fffu + ((u >> 16) & 1u);          // RNE
    return (unsigned short)(u >> 16);
}
__device__ __forceinline__ float bf2f(unsigned short u) {
    return __builtin_bit_cast(float, ((unsigned)u) << 16);
}

// async global->LDS, 16B per lane. LDS dest must be wave-uniform-base + lane*16.
__device__ __forceinline__ void gload16(const void* g, void* l) {
    auto gp = (const __attribute__((address_space(1))) void*)g;
    auto lp = (__attribute__((address_space(3))) void*)l;
    __builtin_amdgcn_global_load_lds(gp, lp, 16, 0, 0);
}

// ---------------- elementwise fp32 -> bf16 ----------------
__global__ __launch_bounds__(256) void conv_bf16_kernel(
    const float* __restrict__ in, unsigned short* __restrict__ out, int n4)
{
    int i = blockIdx.x * 256 + threadIdx.x;
    if (i >= n4) return;
    float4 v = ((const float4*)in)[i];
    ushort4 o = make_ushort4(f2bf(v.x), f2bf(v.y), f2bf(v.z), f2bf(v.w));
    ((ushort4*)out)[i] = o;
}

// ---------------- (R,C) fp32 -> (C,R) bf16 transpose ----------------
__global__ __launch_bounds__(256) void transpose_conv_kernel(
    const float* __restrict__ in, unsigned short* __restrict__ out, int R, int C)
{
    __shared__ float t[32][33];
    int tx = threadIdx.x & 31, ty = threadIdx.x >> 5;   // 32 x 8
    int c0 = blockIdx.x * 32, r0 = blockIdx.y * 32;
    #pragma unroll
    for (int i = 0; i < 4; ++i)
        t[ty + 8*i][tx] = in[(size_t)(r0 + ty + 8*i) * C + (c0 + tx)];
    __syncthreads();
    #pragma unroll
    for (int i = 0; i < 4; ++i)
        out[(size_t)(c0 + ty + 8*i) * R + (r0 + tx)] = f2bf(t[tx][ty + 8*i]);
}

// ---------------- bf16 MFMA GEMM: C(M,N) = A(M,K) * Bt(N,K)^T (+bias) -------
// 128x128 tile, BK=64, 4 waves 2x2, 16x16x32 MFMA. Linear LDS [row][64],
// staged with global_load_lds width=16 (m97 structure; LDS must stay linear).
template<bool HAS_BIAS, bool OUT_BF16>
__global__ __launch_bounds__(256) void gemm_kernel(
    const unsigned short* __restrict__ A, const unsigned short* __restrict__ Bt,
    const float* __restrict__ bias, void* __restrict__ Cout,
    int M, int N, int K)
{
    __shared__ unsigned short lA[128 * 64];
    __shared__ unsigned short lB[128 * 64];
    const int tid  = threadIdx.x;
    const int lane = tid & 63;
    const int wave = tid >> 6;
    const int wr = wave >> 1, wc = wave & 1;
    const int m0 = blockIdx.y * 128, n0 = blockIdx.x * 128;
    const int srow = tid >> 3;     // 0..31
    const int schunk = tid & 7;    // 16B chunk in a 64-elem row
    const int lm = lane & 15;
    const int lk = (lane >> 4) * 8;

    f32x4 acc[4][4];
    #pragma unroll
    for (int m = 0; m < 4; ++m)
        #pragma unroll
        for (int n = 0; n < 4; ++n) {
            f32x4 z = {0.f, 0.f, 0.f, 0.f};
            acc[m][n] = z;
        }

    const unsigned short* Ag = A  + (size_t)(m0 + srow) * K + schunk * 8;
    const unsigned short* Bg = Bt + (size_t)(n0 + srow) * K + schunk * 8;
    // LDS dest: linear layout => byte offset = tid*16 + i*4096 (row=tid>>3)
    char* lAp = (char*)lA + tid * 16;
    char* lBp = (char*)lB + tid * 16;

    for (int kt = 0; kt < K; kt += 64) {
        #pragma unroll
        for (int i = 0; i < 4; ++i) {
            gload16(Ag + (size_t)(32 * i) * K + kt, lAp + i * 4096);
            gload16(Bg + (size_t)(32 * i) * K + kt, lBp + i * 4096);
        }
        __syncthreads();   // compiler emits vmcnt(0) drain before barrier
        #pragma unroll
        for (int kk = 0; kk < 2; ++kk) {
            bf16x8 af[4], bv[4];
            #pragma unroll
            for (int m = 0; m < 4; ++m)
                af[m] = *(const bf16x8*)((const char*)lA +
                          (wr * 64 + m * 16 + lm) * 128 + (kk * 32 + lk) * 2);
            #pragma unroll
            for (int n = 0; n < 4; ++n)
                bv[n] = *(const bf16x8*)((const char*)lB +
                          (wc * 64 + n * 16 + lm) * 128 + (kk * 32 + lk) * 2);
            #pragma unroll
            for (int m = 0; m < 4; ++m)
                #pragma unroll
                for (int n = 0; n < 4; ++n)
                    acc[m][n] = __builtin_amdgcn_mfma_f32_16x16x32_bf16(
                        af[m], bv[n], acc[m][n], 0, 0, 0);
        }
        __syncthreads();
    }

    // epilogue: C/D layout col=lane&15, row=(lane>>4)*4+j  [m89/m91 verified]
    const int rbase = m0 + wr * 64 + (lane >> 4) * 4;
    const int cbase = n0 + wc * 64 + lm;
    #pragma unroll
    for (int m = 0; m < 4; ++m) {
        #pragma unroll
        for (int n = 0; n < 4; ++n) {
            int col = cbase + n * 16;
            float bvv = HAS_BIAS ? bias[col] : 0.0f;
            #pragma unroll
            for (int j = 0; j < 4; ++j) {
                int row = rbase + m * 16 + j;
                float v = acc[m][n][j] + bvv;
                if (OUT_BF16)
                    ((unsigned short*)Cout)[(size_t)row * N + col] = f2bf(v);
                else
                    ((float*)Cout)[(size_t)row * N + col] = v;
            }
        }
    }
}

// ---------------- additive-attention scores: one block per (b,m) ----------
// scores[b*20+m] = sum_h tanh(q[b,h]+k[b,m,h])*wa[h]  (+ optional scalar bias)
__global__ __launch_bounds__(256) void attn_scores_kernel(
    const float* __restrict__ q, const float* __restrict__ k,
    const float* __restrict__ wa, const float* __restrict__ bias,
    float* __restrict__ scores)
{
    const int bm = blockIdx.x;          // b*20 + m
    const int b  = bm / 20;
    const int tid = threadIdx.x;
    float4 qv = ((const float4*)(q + (size_t)b  * 1024))[tid];
    float4 kv = ((const float4*)(k + (size_t)bm * 1024))[tid];
    float4 wv = ((const float4*)wa)[tid];
    float p = tanhf(qv.x + kv.x) * wv.x + tanhf(qv.y + kv.y) * wv.y
            + tanhf(qv.z + kv.z) * wv.z + tanhf(qv.w + kv.w) * wv.w;
    #pragma unroll
    for (int off = 32; off > 0; off >>= 1) p += __shfl_down(p, off);
    __shared__ float sp[4];
    if ((tid & 63) == 0) sp[tid >> 6] = p;
    __syncthreads();
    if (tid == 0) {
        float s = sp[0] + sp[1] + sp[2] + sp[3];
        if (bias) s += bias[0];
        scores[bm] = s;
    }
}

// ---------------- argmax over ingredients -> pairing ids -------------------
// softmax skipped (monotone; only argmax consumed). First-max tiebreak = jnp.
__global__ __launch_bounds__(256) void argmax_ids_kernel(
    const float* __restrict__ scores, const int* __restrict__ input_tensor,
    const int* __restrict__ pairing_ids, int* __restrict__ comp_ids)
{
    const int b = threadIdx.x;          // one block, 256 threads
    float best = scores[b * 20]; int bi = 0;
    #pragma unroll
    for (int m = 1; m < 20; ++m) {
        float v = scores[b * 20 + m];
        if (v > best) { best = v; bi = m; }
    }
    const int ing = input_tensor[b * 20 + bi];
    #pragma unroll
    for (int kk = 0; kk < 20; ++kk)
        comp_ids[b * 20 + kk] = pairing_ids[ing * 20 + kk];
}

// ---------------- gather comp_emb rows -> bf16, one block per (b,k) --------
__global__ __launch_bounds__(256) void gather_comp_kernel(
    const int* __restrict__ comp_ids, const float* __restrict__ enc_emb,
    unsigned short* __restrict__ comp_embb)
{
    const int bk = blockIdx.x;          // b*20 + k
    const int cid = comp_ids[bk];
    const float4* src = (const float4*)(enc_emb + (size_t)cid * 2048);
    ushort4* dst = (ushort4*)(comp_embb + (size_t)bk * 2048);
    const int tid = threadIdx.x;
    #pragma unroll
    for (int i = 0; i < 2; ++i) {
        float4 v = src[tid + 256 * i];
        dst[tid + 256 * i] = make_ushort4(f2bf(v.x), f2bf(v.y), f2bf(v.z), f2bf(v.w));
    }
}

// ---------------- pairing softmax weights: s_as = softmax(s)*s -------------
__global__ __launch_bounds__(256) void pair_weights_kernel(
    const float* __restrict__ s, float* __restrict__ s_as)
{
    const int b = threadIdx.x;          // one block, 256 threads
    float v[20]; float mx = -1e30f;
    #pragma unroll
    for (int m = 0; m < 20; ++m) { v[m] = s[b * 20 + m]; mx = fmaxf(mx, v[m]); }
    float den = 0.f;
    float e[20];
    #pragma unroll
    for (int m = 0; m < 20; ++m) { e[m] = expf(v[m] - mx); den += e[m]; }
    const float inv = 1.f / den;
    #pragma unroll
    for (int m = 0; m < 20; ++m) s_as[b * 20 + m] = e[m] * inv * v[m];
}

// ---------------- out_pair assembly: [emb | attn_app] -> bf16 --------------
// grid = B*6 blocks; each block covers 512 of the 3072 dims (2 per thread).
__global__ __launch_bounds__(256) void out_pair_kernel(
    const float* __restrict__ s_as, const unsigned short* __restrict__ comp_embb,
    const float* __restrict__ emb_dec, const int* __restrict__ input_ids,
    unsigned short* __restrict__ out_pairb)
{
    const int b = blockIdx.x / 6, seg = blockIdx.x % 6;
    const int d = seg * 512 + threadIdx.x * 2;
    ushort2 o;
    if (d < 1024) {
        float2 v = *(const float2*)(emb_dec + (size_t)input_ids[b] * 1024 + d);
        o.x = f2bf(v.x); o.y = f2bf(v.y);
    } else {
        const int dd = d - 1024;
        float a0 = 0.f, a1 = 0.f;
        #pragma unroll
        for (int k = 0; k < 20; ++k) {
            float a = s_as[b * 20 + k];
            unsigned u = *(const unsigned*)(comp_embb + ((size_t)b * 20 + k) * 2048 + dd);
            a0 += a * bf2f((unsigned short)(u & 0xffff));
            a1 += a * bf2f((unsigned short)(u >> 16));
        }
        o.x = f2bf(a0); o.y = f2bf(a1);
    }
    *(ushort2*)(out_pairb + (size_t)b * 3072 + d) = o;
}

// ---------------- GRU pointwise (torch gate order r,z,n) ----------------
__global__ __launch_bounds__(256) void gru_kernel(
    const float* __restrict__ gi, const float* __restrict__ gh,
    const float* __restrict__ h, unsigned short* __restrict__ hnewb)
{
    int idx = blockIdx.x * 256 + threadIdx.x;       // 262144 total
    int b = idx >> 10, j = idx & 1023;
    const float* gib = gi + (size_t)b * 3072;
    const float* ghb = gh + (size_t)b * 3072;
    float r = 1.f / (1.f + expf(-(gib[j] + ghb[j])));
    float z = 1.f / (1.f + expf(-(gib[1024 + j] + ghb[1024 + j])));
    float n = tanhf(gib[2048 + j] + r * ghb[2048 + j]);
    float hv = h[idx];
    hnewb[idx] = f2bf((1.f - z) * n + z * hv);
}

// ---------------------------------------------------------------------------
extern "C" void kernel_launch(void* const* d_in, const int* in_sizes, int n_in,
                              void* d_out, int out_size, void* d_ws, size_t ws_size,
                              hipStream_t stream)
{
    const int*   input_ids    = (const int*)  d_in[0];
    const float* hidden       = (const float*)d_in[1];
    const float* enc_out      = (const float*)d_in[2];
    const int*   input_tensor = (const int*)  d_in[3];
    const int*   pairing_ids  = (const int*)  d_in[4];
    const float* emb_dec      = (const float*)d_in[5];
    const float* enc_emb      = (const float*)d_in[6];
    const float* Wq_i  = (const float*)d_in[7];
    const float* Wk_i  = (const float*)d_in[8];
    const float* wa_i  = (const float*)d_in[9];
    const float* Wq_p  = (const float*)d_in[10];
    const float* Wk_p  = (const float*)d_in[11];
    const float* wa_p  = (const float*)d_in[12];
    const float* ba_p  = (const float*)d_in[13];
    const float* W_lin = (const float*)d_in[14];
    const float* b_lin = (const float*)d_in[15];
    const float* W_ih  = (const float*)d_in[16];
    const float* W_hh  = (const float*)d_in[17];
    const float* b_ih  = (const float*)d_in[18];
    const float* b_hh  = (const float*)d_in[19];
    const float* W_out = (const float*)d_in[20];
    const float* b_out = (const float*)d_in[21];

    // Workspace layout (79,167,488 B). Arena overlaid; W_out^T reuses all of it.
    constexpr size_t OFF_HB    = 0;          // 524,288
    constexpr size_t OFF_HNEW  = 524288;     // 524,288
    constexpr size_t OFF_WT    = 1048576;    // 12,582,912
    constexpr size_t OFF_ARENA = 13631488;   // 65,536,000
    constexpr size_t NEED      = OFF_ARENA + 65536000;
    if (ws_size < NEED) {
        fprintf(stderr, "kernel_launch: ws_size %zu < needed %zu\n", ws_size, NEED);
        return;
    }
    char* ws    = (char*)d_ws;
    unsigned short* hb    = (unsigned short*)(ws + OFF_HB);
    unsigned short* hnewb = (unsigned short*)(ws + OFF_HNEW);
    unsigned short* Wt    = (unsigned short*)(ws + OFF_WT);
    char* arena = ws + OFF_ARENA;
    unsigned short* encb  = (unsigned short*)(arena + 0);         // -> comp_embb
    float*          query = (float*)         (arena + 20971520);  // -> q_p
    float*          key   = (float*)         (arena + 22020096);  // -> k_p
    unsigned short* outp  = (unsigned short*)(arena + 42991616);
    unsigned short* xb    = (unsigned short*)(arena + 44564480);
    float*          gi    = (float*)         (arena + 45613056);
    float*          gh    = (float*)         (arena + 48758784);
    float*          scores= (float*)         (arena + 51904512);  // 20,480
    float*          s_as  = (float*)         (arena + 51924992);  // 20,480
    int*            cids  = (int*)           (arena + 51945472);  // 20,480
    unsigned short* Wbig  = (unsigned short*)arena;               // W_out^T (last)

    // activations -> bf16
    conv_bf16_kernel<<<256,   256, 0, stream>>>(hidden,  hb,   65536);
    conv_bf16_kernel<<<10240, 256, 0, stream>>>(enc_out, encb, 2621440);

    // G1: query = h @ Wq_i               (256,1024,K=1024)
    transpose_conv_kernel<<<dim3(32, 32), 256, 0, stream>>>(Wq_i, Wt, 1024, 1024);
    gemm_kernel<false,false><<<dim3(8, 2), 256, 0, stream>>>(hb, Wt, nullptr, query, 256, 1024, 1024);

    // G2: key = enc @ Wk_i               (5120,1024,K=2048)
    transpose_conv_kernel<<<dim3(32, 64), 256, 0, stream>>>(Wk_i, Wt, 2048, 1024);
    gemm_kernel<false,false><<<dim3(8, 40), 256, 0, stream>>>(encb, Wt, nullptr, key, 5120, 1024, 2048);

    // ingredient attention: scores -> argmax/ids -> gather (overlays encb)
    attn_scores_kernel<<<5120, 256, 0, stream>>>(query, key, wa_i, nullptr, scores);
    argmax_ids_kernel<<<1, 256, 0, stream>>>(scores, input_tensor, pairing_ids, cids);
    gather_comp_kernel<<<5120, 256, 0, stream>>>(cids, enc_emb, encb);

    // G3: q_p = h @ Wq_p
    transpose_conv_kernel<<<dim3(32, 32), 256, 0, stream>>>(Wq_p, Wt, 1024, 1024);
    gemm_kernel<false,false><<<dim3(8, 2), 256, 0, stream>>>(hb, Wt, nullptr, query, 256, 1024, 1024);

    // G4: k_p = comp_emb @ Wk_p          (5120,1024,K=2048)
    transpose_conv_kernel<<<dim3(32, 64), 256, 0, stream>>>(Wk_p, Wt, 2048, 1024);
    gemm_kernel<false,false><<<dim3(8, 40), 256, 0, stream>>>(encb, Wt, nullptr, key, 5120, 1024, 2048);

    // pairing attention: scores -> softmax weights -> out_pair assembly
    attn_scores_kernel<<<5120, 256, 0, stream>>>(query, key, wa_p, ba_p, scores);
    pair_weights_kernel<<<1, 256, 0, stream>>>(scores, s_as);
    out_pair_kernel<<<1536, 256, 0, stream>>>(s_as, encb, emb_dec, input_ids, outp);

    // G5: x = out_pair @ W_lin + b_lin   (256,2048,K=3072) -> bf16
    transpose_conv_kernel<<<dim3(64, 96), 256, 0, stream>>>(W_lin, Wt, 3072, 2048);
    gemm_kernel<true,true><<<dim3(16, 2), 256, 0, stream>>>(outp, Wt, b_lin, xb, 256, 2048, 3072);

    // G6: gi = x @ W_ih^T + b_ih         (256,3072,K=2048); W_ih already (N,K)
    conv_bf16_kernel<<<6144, 256, 0, stream>>>(W_ih, Wt, 1572864);
    gemm_kernel<true,false><<<dim3(24, 2), 256, 0, stream>>>(xb, Wt, b_ih, gi, 256, 3072, 2048);

    // G7: gh = h @ W_hh^T + b_hh         (256,3072,K=1024)
    conv_bf16_kernel<<<3072, 256, 0, stream>>>(W_hh, Wt, 786432);
    gemm_kernel<true,false><<<dim3(24, 2), 256, 0, stream>>>(hb, Wt, b_hh, gh, 256, 3072, 1024);

    // GRU pointwise -> h_new bf16
    gru_kernel<<<1024, 256, 0, stream>>>(gi, gh, hidden, hnewb);

    // G8: logits = h_new @ W_out + b_out (256,32000,K=1024)
    transpose_conv_kernel<<<dim3(1000, 32), 256, 0, stream>>>(W_out, Wbig, 1024, 32000);
    gemm_kernel<true,false><<<dim3(250, 2), 256, 0, stream>>>(hnewb, Wbig, b_out,
                                                              (float*)d_out, 256, 32000, 1024);
}

// Round 3
// 306.489 us; speedup vs baseline: 1.6397x; 1.4323x over previous
//
#include <hip/hip_runtime.h>
#include <cstdio>

// ---------------------------------------------------------------------------
// PairAttnDecoderRNN forward, MI355X/gfx950.  Round 3:
//  - depth-1 pipelined GEMM (distinct dbuf LDS objects, prefetch-before-compute)
//  - split-K for skinny GEMMs (G5 SK4; G6+G7 merged SK2, reduced inside GRU)
//  - merged launches (G1+G3 dual, batched Wq/Wk transposes)
//  - key/k_p stored bf16; 128-row transpose tiles with 16B stores
// ---------------------------------------------------------------------------

using f32x4   = __attribute__((ext_vector_type(4))) float;
using bf16x8  = __attribute__((ext_vector_type(8))) short;
using ushort8 = __attribute__((ext_vector_type(8))) unsigned short;

__device__ __forceinline__ unsigned short f2bf(float x) {
    unsigned u = __builtin_bit_cast(unsigned, x);
    u += 0x7fffu + ((u >> 16) & 1u);          // RNE
    return (unsigned short)(u >> 16);
}
__device__ __forceinline__ float bf2f(unsigned short u) {
    return __builtin_bit_cast(float, ((unsigned)u) << 16);
}

// async global->LDS, 16B per lane. LDS dest = wave-uniform base + lane*16.
__device__ __forceinline__ void gload16(const void* g, void* l) {
    auto gp = (const __attribute__((address_space(1))) void*)g;
    auto lp = (__attribute__((address_space(3))) void*)l;
    __builtin_amdgcn_global_load_lds(gp, lp, 16, 0, 0);
}

// ---------------- elementwise fp32 -> bf16 ----------------
__global__ __launch_bounds__(256) void conv_bf16_kernel(
    const float* __restrict__ in, unsigned short* __restrict__ out, int n4)
{
    int i = blockIdx.x * 256 + threadIdx.x;
    if (i >= n4) return;
    float4 v = ((const float4*)in)[i];
    ((ushort4*)out)[i] = make_ushort4(f2bf(v.x), f2bf(v.y), f2bf(v.z), f2bf(v.w));
}

// ---------------- (R,C) fp32 -> (C,R) bf16 transpose, 128r x 32c tile -------
__device__ __forceinline__ void transpose_body(
    const float* __restrict__ in, unsigned short* __restrict__ out, int R, int C)
{
    __shared__ float t[32][129];
    const int tid = threadIdx.x;
    const int c0 = blockIdx.x * 32, r0 = blockIdx.y * 128;
    const int lr = tid >> 3;              // 0..31
    const int cc = (tid & 7) * 4;         // col chunk
    #pragma unroll
    for (int i = 0; i < 4; ++i) {
        int r = lr + 32 * i;
        float4 v = *(const float4*)(in + (size_t)(r0 + r) * C + c0 + cc);
        t[cc + 0][r] = v.x; t[cc + 1][r] = v.y;
        t[cc + 2][r] = v.z; t[cc + 3][r] = v.w;
    }
    __syncthreads();
    const int rc = (tid & 15) * 8;        // r chunk (8 outputs = 16B store)
    #pragma unroll
    for (int p = 0; p < 2; ++p) {
        int c = (tid >> 4) + 16 * p;
        const float* src = &t[c][rc];
        ushort8 o;
        #pragma unroll
        for (int j = 0; j < 8; ++j) o[j] = f2bf(src[j]);
        *(ushort8*)(out + (size_t)(c0 + c) * R + r0 + rc) = o;
    }
}
__global__ __launch_bounds__(256) void transpose1_kernel(
    const float* in, unsigned short* out, int R, int C)
{ transpose_body(in, out, R, C); }

__global__ __launch_bounds__(256) void transpose2_kernel(
    const float* in0, const float* in1, unsigned short* out0, unsigned short* out1,
    int R, int C)
{ transpose_body(blockIdx.z ? in1 : in0, blockIdx.z ? out1 : out0, R, C); }

// ---------------- bf16 MFMA GEMM core: C(M,N) = A(M,K) * Bt(N,K)^T ----------
// 128x128 tile, BK=64, 4 waves 2x2, 16x16x32 MFMA, global_load_lds width=16.
// Depth-1 pipeline: stage(next) issued BEFORE compute(cur); __syncthreads'
// vmcnt(0) drain then waits on loads that had a full MFMA phase in flight.
// Buffers are DISTINCT __shared__ objects selected at compile time.
template<int OUTBF, bool HAS_BIAS>
__device__ __forceinline__ void gemm_core(
    const unsigned short* __restrict__ A, const unsigned short* __restrict__ Bt,
    const float* __restrict__ bias, void* __restrict__ Cout, int Ncols,
    int sA, int sB, int kLen,
    unsigned short* lA0, unsigned short* lA1,
    unsigned short* lB0, unsigned short* lB1)
{
    const int tid = threadIdx.x;
    const int lane = tid & 63, wave = tid >> 6;
    const int wr = wave >> 1, wc = wave & 1;
    const int m0 = blockIdx.y * 128, n0 = blockIdx.x * 128;
    const int srow = tid >> 3, schunk = tid & 7;
    const int lm = lane & 15, lk = (lane >> 4) * 8;

    f32x4 acc[4][4];
    #pragma unroll
    for (int m = 0; m < 4; ++m)
        #pragma unroll
        for (int n = 0; n < 4; ++n) { f32x4 z = {0.f,0.f,0.f,0.f}; acc[m][n] = z; }

    const unsigned short* Ag = A  + (size_t)(m0 + srow) * sA + schunk * 8;
    const unsigned short* Bg = Bt + (size_t)(n0 + srow) * sB + schunk * 8;
    const int nt = kLen >> 6;

    auto stage = [&](unsigned short* la_, unsigned short* lb_, int t) {
        char* la = (char*)la_ + tid * 16;
        char* lb = (char*)lb_ + tid * 16;
        #pragma unroll
        for (int i = 0; i < 4; ++i) {
            gload16(Ag + (size_t)(32 * i) * sA + t * 64, la + i * 4096);
            gload16(Bg + (size_t)(32 * i) * sB + t * 64, lb + i * 4096);
        }
    };
    auto compute = [&](const unsigned short* la_, const unsigned short* lb_) {
        #pragma unroll
        for (int kk = 0; kk < 2; ++kk) {
            bf16x8 af[4], bv[4];
            #pragma unroll
            for (int m = 0; m < 4; ++m)
                af[m] = *(const bf16x8*)((const char*)la_ +
                          (wr * 64 + m * 16 + lm) * 128 + (kk * 32 + lk) * 2);
            #pragma unroll
            for (int n = 0; n < 4; ++n)
                bv[n] = *(const bf16x8*)((const char*)lb_ +
                          (wc * 64 + n * 16 + lm) * 128 + (kk * 32 + lk) * 2);
            #pragma unroll
            for (int m = 0; m < 4; ++m)
                #pragma unroll
                for (int n = 0; n < 4; ++n)
                    acc[m][n] = __builtin_amdgcn_mfma_f32_16x16x32_bf16(
                        af[m], bv[n], acc[m][n], 0, 0, 0);
        }
    };

    stage(lA0, lB0, 0);
    __syncthreads();
    for (int t = 0; t < nt; t += 2) {
        if (t + 1 < nt) stage(lA1, lB1, t + 1);
        compute(lA0, lB0);
        __syncthreads();
        if (t + 1 < nt) {
            if (t + 2 < nt) stage(lA0, lB0, t + 2);
            compute(lA1, lB1);
            __syncthreads();
        }
    }

    // epilogue: C/D layout col=lane&15, row=(lane>>4)*4+j  [m89/m91 verified]
    const int rbase = m0 + wr * 64 + (lane >> 4) * 4;
    const int cbase = n0 + wc * 64 + lm;
    #pragma unroll
    for (int m = 0; m < 4; ++m) {
        #pragma unroll
        for (int n = 0; n < 4; ++n) {
            int col = cbase + n * 16;
            float bvv = HAS_BIAS ? bias[col] : 0.0f;
            #pragma unroll
            for (int j = 0; j < 4; ++j) {
                int row = rbase + m * 16 + j;
                float v = acc[m][n][j] + bvv;
                if (OUTBF)
                    ((unsigned short*)Cout)[(size_t)row * Ncols + col] = f2bf(v);
                else
                    ((float*)Cout)[(size_t)row * Ncols + col] = v;
            }
        }
    }
}

#define GEMM_SHARED \
    __shared__ unsigned short lA0[8192]; __shared__ unsigned short lA1[8192]; \
    __shared__ unsigned short lB0[8192]; __shared__ unsigned short lB1[8192];

__global__ __launch_bounds__(256) void gemm_bf16_kernel(
    const unsigned short* A, const unsigned short* Bt, unsigned short* C,
    int N, int sA, int sB, int kLen)
{
    GEMM_SHARED
    gemm_core<1,false>(A, Bt, nullptr, C, N, sA, sB, kLen, lA0, lA1, lB0, lB1);
}

__global__ __launch_bounds__(256) void gemm_f32b_kernel(
    const unsigned short* A, const unsigned short* Bt, const float* bias, float* C,
    int N, int sA, int sB, int kLen)
{
    GEMM_SHARED
    gemm_core<0,true>(A, Bt, bias, C, N, sA, sB, kLen, lA0, lA1, lB0, lB1);
}

__global__ __launch_bounds__(256) void gemm_dual_kernel(
    const unsigned short* A, const unsigned short* B0, const unsigned short* B1,
    float* C0, float* C1, int N, int K)
{
    GEMM_SHARED
    const unsigned short* Bt = blockIdx.z ? B1 : B0;
    float* C = blockIdx.z ? C1 : C0;
    gemm_core<0,false>(A, Bt, nullptr, C, N, K, K, K, lA0, lA1, lB0, lB1);
}

__global__ __launch_bounds__(256) void gemm5_kernel(
    const unsigned short* A, const unsigned short* Bt, float* P)
{
    GEMM_SHARED
    const int z = blockIdx.z;
    gemm_core<0,false>(A + z * 768, Bt + z * 768, nullptr,
                       P + (size_t)z * 524288, 2048, 3072, 3072, 768,
                       lA0, lA1, lB0, lB1);
}

__global__ __launch_bounds__(256) void gemm67_kernel(
    const unsigned short* xb, const unsigned short* hb,
    const unsigned short* Wih, const unsigned short* Whh, float* pg)
{
    GEMM_SHARED
    const int g = blockIdx.z >> 1, s = blockIdx.z & 1;
    const unsigned short* A  = g ? hb  + s * 512 : xb  + s * 1024;
    const unsigned short* Bt = g ? Whh + s * 512 : Wih + s * 1024;
    const int sAB  = g ? 1024 : 2048;
    const int kLen = g ? 512  : 1024;
    float* C = pg + (size_t)blockIdx.z * 786432;
    gemm_core<0,false>(A, Bt, nullptr, C, 3072, sAB, sAB, kLen, lA0, lA1, lB0, lB1);
}

// ---------------- additive-attention scores (k in bf16) --------------------
__global__ __launch_bounds__(256) void attn_scores_kernel(
    const float* __restrict__ q, const unsigned short* __restrict__ k,
    const float* __restrict__ wa, const float* __restrict__ bias,
    float* __restrict__ scores)
{
    const int bm = blockIdx.x;          // b*20 + m
    const int b  = bm / 20;
    const int tid = threadIdx.x;
    float4 qv  = ((const float4*)(q + (size_t)b * 1024))[tid];
    ushort4 kv = ((const ushort4*)(k + (size_t)bm * 1024))[tid];
    float4 wv  = ((const float4*)wa)[tid];
    float p = tanhf(qv.x + bf2f(kv.x)) * wv.x + tanhf(qv.y + bf2f(kv.y)) * wv.y
            + tanhf(qv.z + bf2f(kv.z)) * wv.z + tanhf(qv.w + bf2f(kv.w)) * wv.w;
    #pragma unroll
    for (int off = 32; off > 0; off >>= 1) p += __shfl_down(p, off);
    __shared__ float sp[4];
    if ((tid & 63) == 0) sp[tid >> 6] = p;
    __syncthreads();
    if (tid == 0) {
        float s = sp[0] + sp[1] + sp[2] + sp[3];
        if (bias) s += bias[0];
        scores[bm] = s;
    }
}

// ---------------- argmax over ingredients -> pairing ids -------------------
__global__ __launch_bounds__(256) void argmax_ids_kernel(
    const float* __restrict__ scores, const int* __restrict__ input_tensor,
    const int* __restrict__ pairing_ids, int* __restrict__ comp_ids)
{
    const int b = threadIdx.x;
    float best = scores[b * 20]; int bi = 0;
    #pragma unroll
    for (int m = 1; m < 20; ++m) {
        float v = scores[b * 20 + m];
        if (v > best) { best = v; bi = m; }   // first-max tiebreak = jnp
    }
    const int ing = input_tensor[b * 20 + bi];
    #pragma unroll
    for (int kk = 0; kk < 20; ++kk)
        comp_ids[b * 20 + kk] = pairing_ids[ing * 20 + kk];
}

// ---------------- gather comp_emb rows -> bf16 ------------------------------
__global__ __launch_bounds__(256) void gather_comp_kernel(
    const int* __restrict__ comp_ids, const float* __restrict__ enc_emb,
    unsigned short* __restrict__ comp_embb)
{
    const int bk = blockIdx.x;
    const int cid = comp_ids[bk];
    const float4* src = (const float4*)(enc_emb + (size_t)cid * 2048);
    ushort4* dst = (ushort4*)(comp_embb + (size_t)bk * 2048);
    const int tid = threadIdx.x;
    #pragma unroll
    for (int i = 0; i < 2; ++i) {
        float4 v = src[tid + 256 * i];
        dst[tid + 256 * i] = make_ushort4(f2bf(v.x), f2bf(v.y), f2bf(v.z), f2bf(v.w));
    }
}

// ---------------- pairing softmax weights: s_as = softmax(s)*s --------------
__global__ __launch_bounds__(256) void pair_weights_kernel(
    const float* __restrict__ s, float* __restrict__ s_as)
{
    const int b = threadIdx.x;
    float v[20]; float mx = -1e30f;
    #pragma unroll
    for (int m = 0; m < 20; ++m) { v[m] = s[b * 20 + m]; mx = fmaxf(mx, v[m]); }
    float den = 0.f; float e[20];
    #pragma unroll
    for (int m = 0; m < 20; ++m) { e[m] = expf(v[m] - mx); den += e[m]; }
    const float inv = 1.f / den;
    #pragma unroll
    for (int m = 0; m < 20; ++m) s_as[b * 20 + m] = e[m] * inv * v[m];
}

// ---------------- out_pair assembly: [emb | attn_app] -> bf16 ---------------
__global__ __launch_bounds__(256) void out_pair_kernel(
    const float* __restrict__ s_as, const unsigned short* __restrict__ comp_embb,
    const float* __restrict__ emb_dec, const int* __restrict__ input_ids,
    unsigned short* __restrict__ out_pairb)
{
    const int b = blockIdx.x / 6, seg = blockIdx.x % 6;
    const int d = seg * 512 + threadIdx.x * 2;
    ushort2 o;
    if (d < 1024) {
        float2 v = *(const float2*)(emb_dec + (size_t)input_ids[b] * 1024 + d);
        o.x = f2bf(v.x); o.y = f2bf(v.y);
    } else {
        const int dd = d - 1024;
        float a0 = 0.f, a1 = 0.f;
        #pragma unroll
        for (int k = 0; k < 20; ++k) {
            float a = s_as[b * 20 + k];
            unsigned u = *(const unsigned*)(comp_embb + ((size_t)b * 20 + k) * 2048 + dd);
            a0 += a * bf2f((unsigned short)(u & 0xffff));
            a1 += a * bf2f((unsigned short)(u >> 16));
        }
        o.x = f2bf(a0); o.y = f2bf(a1);
    }
    *(ushort2*)(out_pairb + (size_t)b * 3072 + d) = o;
}

// ---------------- G5 split-K reduce + bias -> bf16 x ------------------------
__global__ __launch_bounds__(256) void reduce5_kernel(
    const float* __restrict__ P, const float* __restrict__ bias,
    unsigned short* __restrict__ xb)
{
    int i = blockIdx.x * 256 + threadIdx.x;        // 131072 float4s
    const float4* p = (const float4*)P;
    float4 a = p[i], b = p[i + 131072], c = p[i + 262144], d = p[i + 393216];
    float4 bb = ((const float4*)bias)[i & 511];
    ((ushort4*)xb)[i] = make_ushort4(f2bf(a.x + b.x + c.x + d.x + bb.x),
                                     f2bf(a.y + b.y + c.y + d.y + bb.y),
                                     f2bf(a.z + b.z + c.z + d.z + bb.z),
                                     f2bf(a.w + b.w + c.w + d.w + bb.w));
}

// ---------------- GRU pointwise + split-K reduce (gate order r,z,n) ---------
__global__ __launch_bounds__(256) void gru_kernel(
    const float* __restrict__ pg, const float* __restrict__ b_ih,
    const float* __restrict__ b_hh, const float* __restrict__ h,
    unsigned short* __restrict__ hnewb)
{
    int idx = blockIdx.x * 256 + threadIdx.x;       // 262144
    int b = idx >> 10, j = idx & 1023;
    const float* gi0 = pg + (size_t)b * 3072;
    const float* gi1 = gi0 + 786432;
    const float* gh0 = gi0 + 2 * 786432;
    const float* gh1 = gi0 + 3 * 786432;
    float ir  = gi0[j]        + gi1[j]        + b_ih[j];
    float iz  = gi0[1024 + j] + gi1[1024 + j] + b_ih[1024 + j];
    float in_ = gi0[2048 + j] + gi1[2048 + j] + b_ih[2048 + j];
    float hr  = gh0[j]        + gh1[j]        + b_hh[j];
    float hz  = gh0[1024 + j] + gh1[1024 + j] + b_hh[1024 + j];
    float hn  = gh0[2048 + j] + gh1[2048 + j] + b_hh[2048 + j];
    float r = 1.f / (1.f + expf(-(ir + hr)));
    float z = 1.f / (1.f + expf(-(iz + hz)));
    float n = tanhf(in_ + r * hn);
    hnewb[idx] = f2bf((1.f - z) * n + z * h[idx]);
}

// ---------------------------------------------------------------------------
extern "C" void kernel_launch(void* const* d_in, const int* in_sizes, int n_in,
                              void* d_out, int out_size, void* d_ws, size_t ws_size,
                              hipStream_t stream)
{
    const int*   input_ids    = (const int*)  d_in[0];
    const float* hidden       = (const float*)d_in[1];
    const float* enc_out      = (const float*)d_in[2];
    const int*   input_tensor = (const int*)  d_in[3];
    const int*   pairing_ids  = (const int*)  d_in[4];
    const float* emb_dec      = (const float*)d_in[5];
    const float* enc_emb      = (const float*)d_in[6];
    const float* Wq_i  = (const float*)d_in[7];
    const float* Wk_i  = (const float*)d_in[8];
    const float* wa_i  = (const float*)d_in[9];
    const float* Wq_p  = (const float*)d_in[10];
    const float* Wk_p  = (const float*)d_in[11];
    const float* wa_p  = (const float*)d_in[12];
    const float* ba_p  = (const float*)d_in[13];
    const float* W_lin = (const float*)d_in[14];
    const float* b_lin = (const float*)d_in[15];
    const float* W_ih  = (const float*)d_in[16];
    const float* W_hh  = (const float*)d_in[17];
    const float* b_ih  = (const float*)d_in[18];
    const float* b_hh  = (const float*)d_in[19];
    const float* W_out = (const float*)d_in[20];
    const float* b_out = (const float*)d_in[21];

    // ---- workspace layout (lifetime-checked overlays; max end 77.2MB) ----
    constexpr size_t OFF_HB    = 0;
    constexpr size_t OFF_HNEW  = 524288;
    constexpr size_t OFF_WQI   = 1048576;
    constexpr size_t OFF_WQP   = 3145728;
    constexpr size_t OFF_WKI   = 5242880;
    constexpr size_t OFF_WKP   = 9437184;
    constexpr size_t OFF_ENC   = 13631488;
    constexpr size_t OFF_KEY   = 34603008;
    constexpr size_t OFF_QUERY = 45088768;
    constexpr size_t OFF_QP    = 46137344;
    constexpr size_t OFF_OUTP  = 47185920;
    constexpr size_t OFF_SC    = 48758784;
    constexpr size_t OFF_SAS   = 48791552;
    constexpr size_t OFF_CIDS  = 48824320;
    constexpr size_t OFF_PG5   = 48857088;   // 4 x 2MB, dead after reduce5
    constexpr size_t OFF_XB    = 57245696;
    constexpr size_t OFF_WIH   = 58294272;   // holds W_lin^T for G5, then W_ih
    constexpr size_t OFF_WHH   = 70877184;
    constexpr size_t OFF_PGI   = 1048576;    // overlays dead WqT/WkT (G67..GRU)
    constexpr size_t OFF_WOUT  = 1048576;    // overlays everything dead (..G8)
    constexpr size_t NEED      = 79167488;
    if (ws_size < NEED) {
        fprintf(stderr, "kernel_launch: ws_size %zu < needed %zu\n", ws_size, NEED);
        return;
    }
    char* ws = (char*)d_ws;
    unsigned short* hb    = (unsigned short*)(ws + OFF_HB);
    unsigned short* hnewb = (unsigned short*)(ws + OFF_HNEW);
    unsigned short* WqiT  = (unsigned short*)(ws + OFF_WQI);
    unsigned short* WqpT  = (unsigned short*)(ws + OFF_WQP);
    unsigned short* WkiT  = (unsigned short*)(ws + OFF_WKI);
    unsigned short* WkpT  = (unsigned short*)(ws + OFF_WKP);
    unsigned short* encb  = (unsigned short*)(ws + OFF_ENC);   // -> comp_embb
    unsigned short* keyb  = (unsigned short*)(ws + OFF_KEY);
    float*          query = (float*)         (ws + OFF_QUERY);
    float*          qp    = (float*)         (ws + OFF_QP);
    unsigned short* outp  = (unsigned short*)(ws + OFF_OUTP);
    float*          scores= (float*)         (ws + OFF_SC);
    float*          s_as  = (float*)         (ws + OFF_SAS);
    int*            cids  = (int*)           (ws + OFF_CIDS);
    float*          pG5   = (float*)         (ws + OFF_PG5);
    unsigned short* xb    = (unsigned short*)(ws + OFF_XB);
    unsigned short* WlinT = (unsigned short*)(ws + OFF_WIH);   // slot shared
    unsigned short* Wihb  = (unsigned short*)(ws + OFF_WIH);
    unsigned short* Whhb  = (unsigned short*)(ws + OFF_WHH);
    float*          pgi   = (float*)         (ws + OFF_PGI);
    unsigned short* WoutT = (unsigned short*)(ws + OFF_WOUT);

    // activations -> bf16
    conv_bf16_kernel<<<256,   256, 0, stream>>>(hidden,  hb,   65536);
    conv_bf16_kernel<<<10240, 256, 0, stream>>>(enc_out, encb, 2621440);

    // Wq transposes (batched); G1+G3 dual: query/q_p = h @ Wq_{i,p}
    transpose2_kernel<<<dim3(32, 8, 2), 256, 0, stream>>>(Wq_i, Wq_p, WqiT, WqpT, 1024, 1024);
    gemm_dual_kernel<<<dim3(8, 2, 2), 256, 0, stream>>>(hb, WqiT, WqpT, query, qp, 1024, 1024);

    // Wk transposes (batched); G2: key = enc @ Wk_i -> bf16
    transpose2_kernel<<<dim3(32, 16, 2), 256, 0, stream>>>(Wk_i, Wk_p, WkiT, WkpT, 2048, 1024);
    gemm_bf16_kernel<<<dim3(8, 40), 256, 0, stream>>>(encb, WkiT, keyb, 1024, 2048, 2048, 2048);

    // ingredient attention: scores -> argmax/ids -> gather (overlays encb)
    attn_scores_kernel<<<5120, 256, 0, stream>>>(query, keyb, wa_i, nullptr, scores);
    argmax_ids_kernel<<<1, 256, 0, stream>>>(scores, input_tensor, pairing_ids, cids);
    gather_comp_kernel<<<5120, 256, 0, stream>>>(cids, enc_emb, encb);

    // G4: k_p = comp_emb @ Wk_p -> bf16 (reuses keyb)
    gemm_bf16_kernel<<<dim3(8, 40), 256, 0, stream>>>(encb, WkpT, keyb, 1024, 2048, 2048, 2048);

    // pairing attention -> out_pair
    attn_scores_kernel<<<5120, 256, 0, stream>>>(qp, keyb, wa_p, ba_p, scores);
    pair_weights_kernel<<<1, 256, 0, stream>>>(scores, s_as);
    out_pair_kernel<<<1536, 256, 0, stream>>>(s_as, encb, emb_dec, input_ids, outp);

    // G5: x = out_pair @ W_lin + b_lin  (split-K4 -> partials -> reduce bf16)
    transpose1_kernel<<<dim3(64, 24), 256, 0, stream>>>(W_lin, WlinT, 3072, 2048);
    gemm5_kernel<<<dim3(16, 2, 4), 256, 0, stream>>>(outp, WlinT, pG5);
    reduce5_kernel<<<512, 256, 0, stream>>>(pG5, b_lin, xb);

    // G6+G7 merged, split-K2 each: gi/gh partials (Wihb overwrites WlinT - dead)
    conv_bf16_kernel<<<6144, 256, 0, stream>>>(W_ih, Wihb, 1572864);
    conv_bf16_kernel<<<3072, 256, 0, stream>>>(W_hh, Whhb, 786432);
    gemm67_kernel<<<dim3(24, 2, 4), 256, 0, stream>>>(xb, hb, Wihb, Whhb, pgi);

    // GRU pointwise (+ split-K reduce + biases) -> h_new bf16
    gru_kernel<<<1024, 256, 0, stream>>>(pgi, b_ih, b_hh, hidden, hnewb);

    // G8: logits = h_new @ W_out + b_out
    transpose1_kernel<<<dim3(1000, 8), 256, 0, stream>>>(W_out, WoutT, 1024, 32000);
    gemm_f32b_kernel<<<dim3(250, 2), 256, 0, stream>>>(hnewb, WoutT, b_out,
                                                       (float*)d_out, 32000, 1024, 1024, 1024);
}

// Round 5
// 297.125 us; speedup vs baseline: 1.6913x; 1.0315x over previous
//
#include <hip/hip_runtime.h>
#include <cstdio>

// ---------------------------------------------------------------------------
// PairAttnDecoderRNN forward, MI355X/gfx950.  Round 5 (= round 4 + bugfix):
//  - FIX: conv2w_kernel grid was 4x too small (2304 blocks / split 393216);
//    W_ih needs 1,572,864 float4s, W_hh 786,432 -> 9216 blocks, split 1572864.
//    Round-4 failure (absmax 2.9) was poisoned Wihb/Whhb -> garbage GRU gates.
//  - G4' as kp_all = enc_emb @ Wk_p (10.5 GF) + row gather in scores_p
//  - split-K2 on G2/G4' (grid 640), bf16 partials summed in consumers
//  - folded launches: argmax into consumers, softmax into out_pair, converts
//    merged. 18 launches total.
// ---------------------------------------------------------------------------

using f32x4   = __attribute__((ext_vector_type(4))) float;
using bf16x8  = __attribute__((ext_vector_type(8))) short;
using ushort8 = __attribute__((ext_vector_type(8))) unsigned short;

__device__ __forceinline__ unsigned short f2bf(float x) {
    unsigned u = __builtin_bit_cast(unsigned, x);
    u += 0x7fffu + ((u >> 16) & 1u);          // RNE
    return (unsigned short)(u >> 16);
}
__device__ __forceinline__ float bf2f(unsigned short u) {
    return __builtin_bit_cast(float, ((unsigned)u) << 16);
}

// async global->LDS, 16B per lane. LDS dest = wave-uniform base + lane*16.
__device__ __forceinline__ void gload16(const void* g, void* l) {
    auto gp = (const __attribute__((address_space(1))) void*)g;
    auto lp = (__attribute__((address_space(3))) void*)l;
    __builtin_amdgcn_global_load_lds(gp, lp, 16, 0, 0);
}

// ---------------- fused fp32 -> bf16 converts (hidden | enc_out | enc_emb) --
__global__ __launch_bounds__(256) void prep_conv_kernel(
    const float* __restrict__ hidden, const float* __restrict__ enc_out,
    const float* __restrict__ enc_emb,
    unsigned short* __restrict__ hb, unsigned short* __restrict__ encb,
    unsigned short* __restrict__ encembb)
{
    int i = blockIdx.x * 256 + threadIdx.x;   // float4 units; total 5,246,976
    const float* src; unsigned short* dst; int j;
    if (i < 65536)            { src = hidden;  dst = hb;      j = i; }
    else if (i < 2686976)     { src = enc_out; dst = encb;    j = i - 65536; }
    else                      { src = enc_emb; dst = encembb; j = i - 2686976; }
    float4 v = ((const float4*)src)[j];
    ((ushort4*)dst)[j] = make_ushort4(f2bf(v.x), f2bf(v.y), f2bf(v.z), f2bf(v.w));
}

// ---------------- W_ih | W_hh fp32 -> bf16 (one launch) ---------------------
// W_ih: 3072x2048 f32 = 1,572,864 float4s; W_hh: 3072x1024 = 786,432.
// Total 2,359,296 quads -> 9216 blocks. (Round-4 bug: 2304 blocks/393216 split.)
__global__ __launch_bounds__(256) void conv2w_kernel(
    const float* __restrict__ Wih, const float* __restrict__ Whh,
    unsigned short* __restrict__ ob0, unsigned short* __restrict__ ob1)
{
    int i = blockIdx.x * 256 + threadIdx.x;
    const float* src; unsigned short* dst; int j;
    if (i < 1572864) { src = Wih; dst = ob0; j = i; }
    else             { src = Whh; dst = ob1; j = i - 1572864; }
    float4 v = ((const float4*)src)[j];
    ((ushort4*)dst)[j] = make_ushort4(f2bf(v.x), f2bf(v.y), f2bf(v.z), f2bf(v.w));
}

// ---------------- (R,C) fp32 -> (C,R) bf16 transpose, 128r x 32c tile -------
__device__ __forceinline__ void transpose_body(
    const float* __restrict__ in, unsigned short* __restrict__ out, int R, int C)
{
    __shared__ float t[32][129];
    const int tid = threadIdx.x;
    const int c0 = blockIdx.x * 32, r0 = blockIdx.y * 128;
    const int lr = tid >> 3;              // 0..31
    const int cc = (tid & 7) * 4;         // col chunk
    #pragma unroll
    for (int i = 0; i < 4; ++i) {
        int r = lr + 32 * i;
        float4 v = *(const float4*)(in + (size_t)(r0 + r) * C + c0 + cc);
        t[cc + 0][r] = v.x; t[cc + 1][r] = v.y;
        t[cc + 2][r] = v.z; t[cc + 3][r] = v.w;
    }
    __syncthreads();
    const int rc = (tid & 15) * 8;        // r chunk (8 outputs = 16B store)
    #pragma unroll
    for (int p = 0; p < 2; ++p) {
        int c = (tid >> 4) + 16 * p;
        const float* src = &t[c][rc];
        ushort8 o;
        #pragma unroll
        for (int j = 0; j < 8; ++j) o[j] = f2bf(src[j]);
        *(ushort8*)(out + (size_t)(c0 + c) * R + r0 + rc) = o;
    }
}
__global__ __launch_bounds__(256) void transpose1_kernel(
    const float* in, unsigned short* out, int R, int C)
{ transpose_body(in, out, R, C); }

__global__ __launch_bounds__(256) void transpose2_kernel(
    const float* in0, const float* in1, unsigned short* out0, unsigned short* out1,
    int R, int C)
{ transpose_body(blockIdx.z ? in1 : in0, blockIdx.z ? out1 : out0, R, C); }

// ---------------- bf16 MFMA GEMM core: C(M,N) = A(M,K) * Bt(N,K)^T ----------
// 128x128 tile, BK=64, 4 waves 2x2, 16x16x32 MFMA, global_load_lds width=16.
// Depth-1 pipeline: stage(next) issued BEFORE compute(cur).
template<int OUTBF, bool HAS_BIAS>
__device__ __forceinline__ void gemm_core(
    const unsigned short* __restrict__ A, const unsigned short* __restrict__ Bt,
    const float* __restrict__ bias, void* __restrict__ Cout, int Ncols,
    int sA, int sB, int kLen,
    unsigned short* lA0, unsigned short* lA1,
    unsigned short* lB0, unsigned short* lB1)
{
    const int tid = threadIdx.x;
    const int lane = tid & 63, wave = tid >> 6;
    const int wr = wave >> 1, wc = wave & 1;
    const int m0 = blockIdx.y * 128, n0 = blockIdx.x * 128;
    const int srow = tid >> 3, schunk = tid & 7;
    const int lm = lane & 15, lk = (lane >> 4) * 8;

    f32x4 acc[4][4];
    #pragma unroll
    for (int m = 0; m < 4; ++m)
        #pragma unroll
        for (int n = 0; n < 4; ++n) { f32x4 z = {0.f,0.f,0.f,0.f}; acc[m][n] = z; }

    const unsigned short* Ag = A  + (size_t)(m0 + srow) * sA + schunk * 8;
    const unsigned short* Bg = Bt + (size_t)(n0 + srow) * sB + schunk * 8;
    const int nt = kLen >> 6;

    auto stage = [&](unsigned short* la_, unsigned short* lb_, int t) {
        char* la = (char*)la_ + tid * 16;
        char* lb = (char*)lb_ + tid * 16;
        #pragma unroll
        for (int i = 0; i < 4; ++i) {
            gload16(Ag + (size_t)(32 * i) * sA + t * 64, la + i * 4096);
            gload16(Bg + (size_t)(32 * i) * sB + t * 64, lb + i * 4096);
        }
    };
    auto compute = [&](const unsigned short* la_, const unsigned short* lb_) {
        #pragma unroll
        for (int kk = 0; kk < 2; ++kk) {
            bf16x8 af[4], bv[4];
            #pragma unroll
            for (int m = 0; m < 4; ++m)
                af[m] = *(const bf16x8*)((const char*)la_ +
                          (wr * 64 + m * 16 + lm) * 128 + (kk * 32 + lk) * 2);
            #pragma unroll
            for (int n = 0; n < 4; ++n)
                bv[n] = *(const bf16x8*)((const char*)lb_ +
                          (wc * 64 + n * 16 + lm) * 128 + (kk * 32 + lk) * 2);
            #pragma unroll
            for (int m = 0; m < 4; ++m)
                #pragma unroll
                for (int n = 0; n < 4; ++n)
                    acc[m][n] = __builtin_amdgcn_mfma_f32_16x16x32_bf16(
                        af[m], bv[n], acc[m][n], 0, 0, 0);
        }
    };

    stage(lA0, lB0, 0);
    __syncthreads();
    for (int t = 0; t < nt; t += 2) {
        if (t + 1 < nt) stage(lA1, lB1, t + 1);
        compute(lA0, lB0);
        __syncthreads();
        if (t + 1 < nt) {
            if (t + 2 < nt) stage(lA0, lB0, t + 2);
            compute(lA1, lB1);
            __syncthreads();
        }
    }

    // epilogue: C/D layout col=lane&15, row=(lane>>4)*4+j  [m89/m91 verified]
    const int rbase = m0 + wr * 64 + (lane >> 4) * 4;
    const int cbase = n0 + wc * 64 + lm;
    #pragma unroll
    for (int m = 0; m < 4; ++m) {
        #pragma unroll
        for (int n = 0; n < 4; ++n) {
            int col = cbase + n * 16;
            float bvv = HAS_BIAS ? bias[col] : 0.0f;
            #pragma unroll
            for (int j = 0; j < 4; ++j) {
                int row = rbase + m * 16 + j;
                float v = acc[m][n][j] + bvv;
                if (OUTBF)
                    ((unsigned short*)Cout)[(size_t)row * Ncols + col] = f2bf(v);
                else
                    ((float*)Cout)[(size_t)row * Ncols + col] = v;
            }
        }
    }
}

#define GEMM_SHARED \
    __shared__ unsigned short lA0[8192]; __shared__ unsigned short lA1[8192]; \
    __shared__ unsigned short lB0[8192]; __shared__ unsigned short lB1[8192];

// split-K2, bf16 partials: z selects K half -> P + z*pStride  (G2 and G4')
__global__ __launch_bounds__(256) void gemm_sk2_bf16_kernel(
    const unsigned short* A, const unsigned short* Bt, unsigned short* P,
    int N, int sA, int sB, int kHalf, size_t pStride)
{
    GEMM_SHARED
    const int z = blockIdx.z;
    gemm_core<1,false>(A + (size_t)z * kHalf, Bt + (size_t)z * kHalf, nullptr,
                       P + (size_t)z * pStride, N, sA, sB, kHalf,
                       lA0, lA1, lB0, lB1);
}

// G8: C f32 + bias
__global__ __launch_bounds__(256) void gemm_f32b_kernel(
    const unsigned short* A, const unsigned short* Bt, const float* bias, float* C,
    int N, int sA, int sB, int kLen)
{
    GEMM_SHARED
    gemm_core<0,true>(A, Bt, bias, C, N, sA, sB, kLen, lA0, lA1, lB0, lB1);
}

// G1+G3 merged: z selects (B,C); f32 out
__global__ __launch_bounds__(256) void gemm_dual_kernel(
    const unsigned short* A, const unsigned short* B0, const unsigned short* B1,
    float* C0, float* C1, int N, int K)
{
    GEMM_SHARED
    const unsigned short* Bt = blockIdx.z ? B1 : B0;
    float* C = blockIdx.z ? C1 : C0;
    gemm_core<0,false>(A, Bt, nullptr, C, N, K, K, K, lA0, lA1, lB0, lB1);
}

// G5 split-K4: partials f32
__global__ __launch_bounds__(256) void gemm5_kernel(
    const unsigned short* A, const unsigned short* Bt, float* P)
{
    GEMM_SHARED
    const int z = blockIdx.z;
    gemm_core<0,false>(A + z * 768, Bt + z * 768, nullptr,
                       P + (size_t)z * 524288, 2048, 3072, 3072, 768,
                       lA0, lA1, lB0, lB1);
}

// G6+G7 merged, split-K2 each: z = g*2+s; partials -> pg[z]
__global__ __launch_bounds__(256) void gemm67_kernel(
    const unsigned short* xb, const unsigned short* hb,
    const unsigned short* Wih, const unsigned short* Whh, float* pg)
{
    GEMM_SHARED
    const int g = blockIdx.z >> 1, s = blockIdx.z & 1;
    const unsigned short* A  = g ? hb  + s * 512 : xb  + s * 1024;
    const unsigned short* Bt = g ? Whh + s * 512 : Wih + s * 1024;
    const int sAB  = g ? 1024 : 2048;
    const int kLen = g ? 512  : 1024;
    float* C = pg + (size_t)blockIdx.z * 786432;
    gemm_core<0,false>(A, Bt, nullptr, C, 3072, sAB, sAB, kLen, lA0, lA1, lB0, lB1);
}

// ---------------- ingredient scores: key = kP0[bm] + kP1[bm] (bf16 partials) -
__global__ __launch_bounds__(256) void attn_scores2_kernel(
    const float* __restrict__ q, const unsigned short* __restrict__ kP,
    size_t kStride, const float* __restrict__ wa, float* __restrict__ scores)
{
    const int bm = blockIdx.x;          // b*20 + m
    const int b  = bm / 20;
    const int tid = threadIdx.x;
    float4 qv  = ((const float4*)(q + (size_t)b * 1024))[tid];
    ushort4 k0 = ((const ushort4*)(kP + (size_t)bm * 1024))[tid];
    ushort4 k1 = ((const ushort4*)(kP + kStride + (size_t)bm * 1024))[tid];
    float4 wv  = ((const float4*)wa)[tid];
    float p = tanhf(qv.x + bf2f(k0.x) + bf2f(k1.x)) * wv.x
            + tanhf(qv.y + bf2f(k0.y) + bf2f(k1.y)) * wv.y
            + tanhf(qv.z + bf2f(k0.z) + bf2f(k1.z)) * wv.z
            + tanhf(qv.w + bf2f(k0.w) + bf2f(k1.w)) * wv.w;
    #pragma unroll
    for (int off = 32; off > 0; off >>= 1) p += __shfl_down(p, off);
    __shared__ float sp[4];
    if ((tid & 63) == 0) sp[tid >> 6] = p;
    __syncthreads();
    if (tid == 0) scores[bm] = sp[0] + sp[1] + sp[2] + sp[3];
}

// argmax over ingredient scores (first-max tiebreak = jnp) -> ingredient id
__device__ __forceinline__ int argmax_ing(
    const float* __restrict__ sc_i, const int* __restrict__ input_tensor, int b)
{
    float best = sc_i[b * 20]; int bi = 0;
    #pragma unroll
    for (int m = 1; m < 20; ++m) {
        float v = sc_i[b * 20 + m];
        if (v > best) { best = v; bi = m; }
    }
    return input_tensor[b * 20 + bi];
}

// ---------------- pairing scores: gather kp_all rows by comp_id -------------
__global__ __launch_bounds__(256) void attn_scores_gather_kernel(
    const float* __restrict__ q, const unsigned short* __restrict__ kP,
    size_t kStride, const float* __restrict__ wa, const float* __restrict__ ba,
    const float* __restrict__ sc_i, const int* __restrict__ input_tensor,
    const int* __restrict__ pairing_ids, float* __restrict__ scores)
{
    const int bm = blockIdx.x;          // b*20 + k
    const int b  = bm / 20;
    const int kk = bm - b * 20;
    const int tid = threadIdx.x;
    const int ing = argmax_ing(sc_i, input_tensor, b);
    const int cid = pairing_ids[ing * 20 + kk];
    float4 qv  = ((const float4*)(q + (size_t)b * 1024))[tid];
    ushort4 k0 = ((const ushort4*)(kP + (size_t)cid * 1024))[tid];
    ushort4 k1 = ((const ushort4*)(kP + kStride + (size_t)cid * 1024))[tid];
    float4 wv  = ((const float4*)wa)[tid];
    float p = tanhf(qv.x + bf2f(k0.x) + bf2f(k1.x)) * wv.x
            + tanhf(qv.y + bf2f(k0.y) + bf2f(k1.y)) * wv.y
            + tanhf(qv.z + bf2f(k0.z) + bf2f(k1.z)) * wv.z
            + tanhf(qv.w + bf2f(k0.w) + bf2f(k1.w)) * wv.w;
    #pragma unroll
    for (int off = 32; off > 0; off >>= 1) p += __shfl_down(p, off);
    __shared__ float sp[4];
    if ((tid & 63) == 0) sp[tid >> 6] = p;
    __syncthreads();
    if (tid == 0) scores[bm] = sp[0] + sp[1] + sp[2] + sp[3] + ba[0];
}

// ---------------- gather comp_emb rows -> bf16 (argmax folded) --------------
__global__ __launch_bounds__(256) void gather_comp_kernel(
    const float* __restrict__ sc_i, const int* __restrict__ input_tensor,
    const int* __restrict__ pairing_ids, const float* __restrict__ enc_emb,
    unsigned short* __restrict__ comp_embb)
{
    const int bk = blockIdx.x;          // b*20 + k
    const int b  = bk / 20;
    const int kk = bk - b * 20;
    const int ing = argmax_ing(sc_i, input_tensor, b);
    const int cid = pairing_ids[ing * 20 + kk];
    const float4* src = (const float4*)(enc_emb + (size_t)cid * 2048);
    ushort4* dst = (ushort4*)(comp_embb + (size_t)bk * 2048);
    const int tid = threadIdx.x;
    #pragma unroll
    for (int i = 0; i < 2; ++i) {
        float4 v = src[tid + 256 * i];
        dst[tid + 256 * i] = make_ushort4(f2bf(v.x), f2bf(v.y), f2bf(v.z), f2bf(v.w));
    }
}

// ---------------- out_pair assembly (softmax*s folded in) -------------------
__global__ __launch_bounds__(256) void out_pair_kernel(
    const float* __restrict__ s_p, const unsigned short* __restrict__ comp_embb,
    const float* __restrict__ emb_dec, const int* __restrict__ input_ids,
    unsigned short* __restrict__ out_pairb)
{
    const int b = blockIdx.x / 6, seg = blockIdx.x % 6;
    const int tid = threadIdx.x;
    const int d = seg * 512 + tid * 2;
    ushort2 o;
    if (seg < 2) {                       // emb part, d < 1024
        float2 v = *(const float2*)(emb_dec + (size_t)input_ids[b] * 1024 + d);
        o.x = f2bf(v.x); o.y = f2bf(v.y);
    } else {                             // attn_app part
        __shared__ float s_raw[20];
        if (tid < 20) s_raw[tid] = s_p[b * 20 + tid];
        __syncthreads();
        float mx = -1e30f;
        #pragma unroll
        for (int m = 0; m < 20; ++m) mx = fmaxf(mx, s_raw[m]);
        float den = 0.f; float w[20];
        #pragma unroll
        for (int m = 0; m < 20; ++m) { w[m] = expf(s_raw[m] - mx); den += w[m]; }
        const float inv = 1.f / den;
        const int dd = d - 1024;
        float a0 = 0.f, a1 = 0.f;
        #pragma unroll
        for (int k = 0; k < 20; ++k) {
            float a = w[k] * inv * s_raw[k];           // softmax * raw score
            unsigned u = *(const unsigned*)(comp_embb + ((size_t)b * 20 + k) * 2048 + dd);
            a0 += a * bf2f((unsigned short)(u & 0xffff));
            a1 += a * bf2f((unsigned short)(u >> 16));
        }
        o.x = f2bf(a0); o.y = f2bf(a1);
    }
    *(ushort2*)(out_pairb + (size_t)b * 3072 + d) = o;
}

// ---------------- G5 split-K reduce + bias -> bf16 x ------------------------
__global__ __launch_bounds__(256) void reduce5_kernel(
    const float* __restrict__ P, const float* __restrict__ bias,
    unsigned short* __restrict__ xb)
{
    int i = blockIdx.x * 256 + threadIdx.x;        // 131072 float4s
    const float4* p = (const float4*)P;
    float4 a = p[i], b = p[i + 131072], c = p[i + 262144], d = p[i + 393216];
    float4 bb = ((const float4*)bias)[i & 511];
    ((ushort4*)xb)[i] = make_ushort4(f2bf(a.x + b.x + c.x + d.x + bb.x),
                                     f2bf(a.y + b.y + c.y + d.y + bb.y),
                                     f2bf(a.z + b.z + c.z + d.z + bb.z),
                                     f2bf(a.w + b.w + c.w + d.w + bb.w));
}

// ---------------- GRU pointwise + split-K reduce (gate order r,z,n) ---------
__global__ __launch_bounds__(256) void gru_kernel(
    const float* __restrict__ pg, const float* __restrict__ b_ih,
    const float* __restrict__ b_hh, const float* __restrict__ h,
    unsigned short* __restrict__ hnewb)
{
    int idx = blockIdx.x * 256 + threadIdx.x;       // 262144
    int b = idx >> 10, j = idx & 1023;
    const float* gi0 = pg + (size_t)b * 3072;
    const float* gi1 = gi0 + 786432;
    const float* gh0 = gi0 + 2 * 786432;
    const float* gh1 = gi0 + 3 * 786432;
    float ir  = gi0[j]        + gi1[j]        + b_ih[j];
    float iz  = gi0[1024 + j] + gi1[1024 + j] + b_ih[1024 + j];
    float in_ = gi0[2048 + j] + gi1[2048 + j] + b_ih[2048 + j];
    float hr  = gh0[j]        + gh1[j]        + b_hh[j];
    float hz  = gh0[1024 + j] + gh1[1024 + j] + b_hh[1024 + j];
    float hn  = gh0[2048 + j] + gh1[2048 + j] + b_hh[2048 + j];
    float r = 1.f / (1.f + expf(-(ir + hr)));
    float z = 1.f / (1.f + expf(-(iz + hz)));
    float n = tanhf(in_ + r * hn);
    hnewb[idx] = f2bf((1.f - z) * n + z * h[idx]);
}

// ---------------------------------------------------------------------------
extern "C" void kernel_launch(void* const* d_in, const int* in_sizes, int n_in,
                              void* d_out, int out_size, void* d_ws, size_t ws_size,
                              hipStream_t stream)
{
    const int*   input_ids    = (const int*)  d_in[0];
    const float* hidden       = (const float*)d_in[1];
    const float* enc_out      = (const float*)d_in[2];
    const int*   input_tensor = (const int*)  d_in[3];
    const int*   pairing_ids  = (const int*)  d_in[4];
    const float* emb_dec      = (const float*)d_in[5];
    const float* enc_emb      = (const float*)d_in[6];
    const float* Wq_i  = (const float*)d_in[7];
    const float* Wk_i  = (const float*)d_in[8];
    const float* wa_i  = (const float*)d_in[9];
    const float* Wq_p  = (const float*)d_in[10];
    const float* Wk_p  = (const float*)d_in[11];
    const float* wa_p  = (const float*)d_in[12];
    const float* ba_p  = (const float*)d_in[13];
    const float* W_lin = (const float*)d_in[14];
    const float* b_lin = (const float*)d_in[15];
    const float* W_ih  = (const float*)d_in[16];
    const float* W_hh  = (const float*)d_in[17];
    const float* b_ih  = (const float*)d_in[18];
    const float* b_hh  = (const float*)d_in[19];
    const float* W_out = (const float*)d_in[20];
    const float* b_out = (const float*)d_in[21];

    // ---- workspace layout (time-shared slots, all lifetimes serial) --------
    constexpr size_t OFF_HB    = 0;            // bf16 h, alive all
    constexpr size_t OFF_HNEW  = 524288;       // bf16 h_new, GRU..G8
    constexpr size_t OFF_WQI   = 1048576;      // ..dual
    constexpr size_t OFF_WQP   = 3145728;      // ..dual
    constexpr size_t OFF_WKI   = 5242880;      // ..G2
    constexpr size_t OFF_WKP   = 9437184;      // ..G4'
    constexpr size_t OFF_ENC   = 13631488;     // encb(..G2) -> comp_embb(..outpair)
    constexpr size_t OFF_SLOT1 = 34603008;     // kpP(G4'..scores_p) -> outp/pG5/xb
    constexpr size_t OFF_SLOT2 = 55574528;     // encembb(..G4') -> keyP(G2..scores_i)
                                               //   -> WlinT(..G5) -> Wihb/Whhb(..G67)
    constexpr size_t OFF_QUERY = 76546048;     // f32, ..scores_i
    constexpr size_t OFF_QP    = 77594624;     // f32, ..scores_p
    constexpr size_t OFF_SCI   = 78643200;     // 24KB
    constexpr size_t OFF_SCP   = 78667776;     // 20KB
    constexpr size_t OFF_PGI   = 1048576;      // G67 partials 12.6MB (..gru)
    constexpr size_t OFF_WOUT  = 1048576;      // W_outT 65.5MB (..G8)
    constexpr size_t NEED      = 79167488;
    if (ws_size < NEED) {
        fprintf(stderr, "kernel_launch: ws_size %zu < needed %zu\n", ws_size, NEED);
        return;
    }
    char* ws = (char*)d_ws;
    unsigned short* hb     = (unsigned short*)(ws + OFF_HB);
    unsigned short* hnewb  = (unsigned short*)(ws + OFF_HNEW);
    unsigned short* WqiT   = (unsigned short*)(ws + OFF_WQI);
    unsigned short* WqpT   = (unsigned short*)(ws + OFF_WQP);
    unsigned short* WkiT   = (unsigned short*)(ws + OFF_WKI);
    unsigned short* WkpT   = (unsigned short*)(ws + OFF_WKP);
    unsigned short* encb   = (unsigned short*)(ws + OFF_ENC);     // -> comp_embb
    unsigned short* kpP    = (unsigned short*)(ws + OFF_SLOT1);   // 2 x 5120x1024
    unsigned short* encembb= (unsigned short*)(ws + OFF_SLOT2);   // 5120 rows (5000 used)
    unsigned short* keyP   = (unsigned short*)(ws + OFF_SLOT2);   // after G4'
    unsigned short* WlinT  = (unsigned short*)(ws + OFF_SLOT2);   // after scores_i
    unsigned short* Wihb   = (unsigned short*)(ws + OFF_SLOT2);   // after G5
    unsigned short* Whhb   = (unsigned short*)(ws + OFF_SLOT2 + 12582912);
    unsigned short* outp   = (unsigned short*)(ws + OFF_SLOT1);            // after scores_p
    float*          pG5    = (float*)         (ws + OFF_SLOT1 + 1572864);
    unsigned short* xb     = (unsigned short*)(ws + OFF_SLOT1 + 9961472);
    float*          query  = (float*)         (ws + OFF_QUERY);
    float*          qp     = (float*)         (ws + OFF_QP);
    float*          sc_i   = (float*)         (ws + OFF_SCI);
    float*          sc_p   = (float*)         (ws + OFF_SCP);
    float*          pgi    = (float*)         (ws + OFF_PGI);
    unsigned short* WoutT  = (unsigned short*)(ws + OFF_WOUT);

    constexpr size_t KP_STRIDE = 5120 * 1024;   // elements per partial slice

    // 1. all activation/table converts -> bf16 (one launch)
    prep_conv_kernel<<<20496, 256, 0, stream>>>(hidden, enc_out, enc_emb,
                                                hb, encb, encembb);

    // 2-3. Wq transposes; G1+G3 dual: query/q_p = h @ Wq_{i,p} (f32 out)
    transpose2_kernel<<<dim3(32, 8, 2), 256, 0, stream>>>(Wq_i, Wq_p, WqiT, WqpT, 1024, 1024);
    gemm_dual_kernel<<<dim3(8, 2, 2), 256, 0, stream>>>(hb, WqiT, WqpT, query, qp, 1024, 1024);

    // 4. Wk transposes
    transpose2_kernel<<<dim3(32, 16, 2), 256, 0, stream>>>(Wk_i, Wk_p, WkiT, WkpT, 2048, 1024);

    // 5. G4': kp_all = enc_emb(bf16) @ Wk_p, split-K2 bf16 partials (table GEMM)
    gemm_sk2_bf16_kernel<<<dim3(8, 40, 2), 256, 0, stream>>>(
        encembb, WkpT, kpP, 1024, 2048, 2048, 1024, KP_STRIDE);

    // 6. G2: key = enc @ Wk_i, split-K2 bf16 partials (keyP overwrites encembb)
    gemm_sk2_bf16_kernel<<<dim3(8, 40, 2), 256, 0, stream>>>(
        encb, WkiT, keyP, 1024, 2048, 2048, 1024, KP_STRIDE);

    // 7. ingredient scores
    attn_scores2_kernel<<<5120, 256, 0, stream>>>(query, keyP, KP_STRIDE, wa_i, sc_i);

    // 8. gather comp_emb rows (argmax folded; comp_embb overwrites encb)
    gather_comp_kernel<<<5120, 256, 0, stream>>>(sc_i, input_tensor, pairing_ids,
                                                 enc_emb, encb);

    // 9. pairing scores: gather kp_all rows (argmax folded)
    attn_scores_gather_kernel<<<5120, 256, 0, stream>>>(qp, kpP, KP_STRIDE, wa_p, ba_p,
                                                        sc_i, input_tensor, pairing_ids, sc_p);

    // 10. out_pair = [emb | softmax(s)*s @ comp_emb]  (softmax folded)
    out_pair_kernel<<<1536, 256, 0, stream>>>(sc_p, encb, emb_dec, input_ids, outp);

    // 11-13. G5: x = out_pair @ W_lin + b_lin  (split-K4 -> reduce -> bf16)
    transpose1_kernel<<<dim3(64, 24), 256, 0, stream>>>(W_lin, WlinT, 3072, 2048);
    gemm5_kernel<<<dim3(16, 2, 4), 256, 0, stream>>>(outp, WlinT, pG5);
    reduce5_kernel<<<512, 256, 0, stream>>>(pG5, b_lin, xb);

    // 14-15. G6+G7 merged, split-K2 each (Wihb overwrites WlinT - dead)
    conv2w_kernel<<<9216, 256, 0, stream>>>(W_ih, W_hh, Wihb, Whhb);
    gemm67_kernel<<<dim3(24, 2, 4), 256, 0, stream>>>(xb, hb, Wihb, Whhb, pgi);

    // 16. GRU pointwise (+ split-K reduce + biases) -> h_new bf16
    gru_kernel<<<1024, 256, 0, stream>>>(pgi, b_ih, b_hh, hidden, hnewb);

    // 17-18. G8: logits = h_new @ W_out + b_out
    transpose1_kernel<<<dim3(1000, 8), 256, 0, stream>>>(W_out, WoutT, 1024, 32000);
    gemm_f32b_kernel<<<dim3(250, 2), 256, 0, stream>>>(hnewb, WoutT, b_out,
                                                       (float*)d_out, 32000, 1024, 1024, 1024);
}

// Round 6
// 257.548 us; speedup vs baseline: 1.9513x; 1.1537x over previous
//
#include <hip/hip_runtime.h>
#include <cstdio>

// ---------------------------------------------------------------------------
// PairAttnDecoderRNN forward, MI355X/gfx950.  Round 6:
//  - gemm8_fused: logits GEMM reads W_out f32 (K,N) directly, 256x128 tile,
//    B reg-staged with f32->bf16 convert + XOR-swizzled LDS (kills the 33us
//    W_out transpose; W_out read exactly once = 131MB ~ HBM floor)
//  - out_pair gathers enc_emb f32 rows directly (kills gather_comp kernel)
//  - G2+G4' merged into one z=2 launch, full-K, outputs side-by-side in SLOT1
//  - dual Wq GEMM split-K4 (z=8) + reduceq; partials overlay the WkT slots
//  16 launches total.
// ---------------------------------------------------------------------------

using f32x4   = __attribute__((ext_vector_type(4))) float;
using bf16x8  = __attribute__((ext_vector_type(8))) short;
using ushort8 = __attribute__((ext_vector_type(8))) unsigned short;

__device__ __forceinline__ unsigned short f2bf(float x) {
    unsigned u = __builtin_bit_cast(unsigned, x);
    u += 0x7fffu + ((u >> 16) & 1u);          // RNE
    return (unsigned short)(u >> 16);
}
__device__ __forceinline__ float bf2f(unsigned short u) {
    return __builtin_bit_cast(float, ((unsigned)u) << 16);
}

// async global->LDS, 16B per lane. LDS dest = wave-uniform base + lane*16.
__device__ __forceinline__ void gload16(const void* g, void* l) {
    auto gp = (const __attribute__((address_space(1))) void*)g;
    auto lp = (__attribute__((address_space(3))) void*)l;
    __builtin_amdgcn_global_load_lds(gp, lp, 16, 0, 0);
}

// ---------------- fused fp32 -> bf16 converts (hidden | enc_out | enc_emb) --
__global__ __launch_bounds__(256) void prep_conv_kernel(
    const float* __restrict__ hidden, const float* __restrict__ enc_out,
    const float* __restrict__ enc_emb,
    unsigned short* __restrict__ hb, unsigned short* __restrict__ encb,
    unsigned short* __restrict__ encembb)
{
    int i = blockIdx.x * 256 + threadIdx.x;   // float4 units; total 5,246,976
    const float* src; unsigned short* dst; int j;
    if (i < 65536)            { src = hidden;  dst = hb;      j = i; }
    else if (i < 2686976)     { src = enc_out; dst = encb;    j = i - 65536; }
    else                      { src = enc_emb; dst = encembb; j = i - 2686976; }
    float4 v = ((const float4*)src)[j];
    ((ushort4*)dst)[j] = make_ushort4(f2bf(v.x), f2bf(v.y), f2bf(v.z), f2bf(v.w));
}

// ---------------- W_ih | W_hh fp32 -> bf16 (one launch) ---------------------
// W_ih: 1,572,864 float4s; W_hh: 786,432 -> 9216 blocks total.
__global__ __launch_bounds__(256) void conv2w_kernel(
    const float* __restrict__ Wih, const float* __restrict__ Whh,
    unsigned short* __restrict__ ob0, unsigned short* __restrict__ ob1)
{
    int i = blockIdx.x * 256 + threadIdx.x;
    const float* src; unsigned short* dst; int j;
    if (i < 1572864) { src = Wih; dst = ob0; j = i; }
    else             { src = Whh; dst = ob1; j = i - 1572864; }
    float4 v = ((const float4*)src)[j];
    ((ushort4*)dst)[j] = make_ushort4(f2bf(v.x), f2bf(v.y), f2bf(v.z), f2bf(v.w));
}

// ---------------- (R,C) fp32 -> (C,R) bf16 transpose, 128r x 32c tile -------
__device__ __forceinline__ void transpose_body(
    const float* __restrict__ in, unsigned short* __restrict__ out, int R, int C)
{
    __shared__ float t[32][129];
    const int tid = threadIdx.x;
    const int c0 = blockIdx.x * 32, r0 = blockIdx.y * 128;
    const int lr = tid >> 3;              // 0..31
    const int cc = (tid & 7) * 4;         // col chunk
    #pragma unroll
    for (int i = 0; i < 4; ++i) {
        int r = lr + 32 * i;
        float4 v = *(const float4*)(in + (size_t)(r0 + r) * C + c0 + cc);
        t[cc + 0][r] = v.x; t[cc + 1][r] = v.y;
        t[cc + 2][r] = v.z; t[cc + 3][r] = v.w;
    }
    __syncthreads();
    const int rc = (tid & 15) * 8;        // r chunk (8 outputs = 16B store)
    #pragma unroll
    for (int p = 0; p < 2; ++p) {
        int c = (tid >> 4) + 16 * p;
        const float* src = &t[c][rc];
        ushort8 o;
        #pragma unroll
        for (int j = 0; j < 8; ++j) o[j] = f2bf(src[j]);
        *(ushort8*)(out + (size_t)(c0 + c) * R + r0 + rc) = o;
    }
}
__global__ __launch_bounds__(256) void transpose1_kernel(
    const float* in, unsigned short* out, int R, int C)
{ transpose_body(in, out, R, C); }

__global__ __launch_bounds__(256) void transpose2_kernel(
    const float* in0, const float* in1, unsigned short* out0, unsigned short* out1,
    int R, int C)
{ transpose_body(blockIdx.z ? in1 : in0, blockIdx.z ? out1 : out0, R, C); }

// ---------------- bf16 MFMA GEMM core: C(M,N) = A(M,K) * Bt(N,K)^T ----------
// 128x128 tile, BK=64, 4 waves 2x2, 16x16x32 MFMA, global_load_lds width=16.
// Depth-1 pipeline: stage(next) issued BEFORE compute(cur).
template<int OUTBF, bool HAS_BIAS>
__device__ __forceinline__ void gemm_core(
    const unsigned short* __restrict__ A, const unsigned short* __restrict__ Bt,
    const float* __restrict__ bias, void* __restrict__ Cout, int Ncols,
    int sA, int sB, int kLen,
    unsigned short* lA0, unsigned short* lA1,
    unsigned short* lB0, unsigned short* lB1)
{
    const int tid = threadIdx.x;
    const int lane = tid & 63, wave = tid >> 6;
    const int wr = wave >> 1, wc = wave & 1;
    const int m0 = blockIdx.y * 128, n0 = blockIdx.x * 128;
    const int srow = tid >> 3, schunk = tid & 7;
    const int lm = lane & 15, lk = (lane >> 4) * 8;

    f32x4 acc[4][4];
    #pragma unroll
    for (int m = 0; m < 4; ++m)
        #pragma unroll
        for (int n = 0; n < 4; ++n) { f32x4 z = {0.f,0.f,0.f,0.f}; acc[m][n] = z; }

    const unsigned short* Ag = A  + (size_t)(m0 + srow) * sA + schunk * 8;
    const unsigned short* Bg = Bt + (size_t)(n0 + srow) * sB + schunk * 8;
    const int nt = kLen >> 6;

    auto stage = [&](unsigned short* la_, unsigned short* lb_, int t) {
        char* la = (char*)la_ + tid * 16;
        char* lb = (char*)lb_ + tid * 16;
        #pragma unroll
        for (int i = 0; i < 4; ++i) {
            gload16(Ag + (size_t)(32 * i) * sA + t * 64, la + i * 4096);
            gload16(Bg + (size_t)(32 * i) * sB + t * 64, lb + i * 4096);
        }
    };
    auto compute = [&](const unsigned short* la_, const unsigned short* lb_) {
        #pragma unroll
        for (int kk = 0; kk < 2; ++kk) {
            bf16x8 af[4], bv[4];
            #pragma unroll
            for (int m = 0; m < 4; ++m)
                af[m] = *(const bf16x8*)((const char*)la_ +
                          (wr * 64 + m * 16 + lm) * 128 + (kk * 32 + lk) * 2);
            #pragma unroll
            for (int n = 0; n < 4; ++n)
                bv[n] = *(const bf16x8*)((const char*)lb_ +
                          (wc * 64 + n * 16 + lm) * 128 + (kk * 32 + lk) * 2);
            #pragma unroll
            for (int m = 0; m < 4; ++m)
                #pragma unroll
                for (int n = 0; n < 4; ++n)
                    acc[m][n] = __builtin_amdgcn_mfma_f32_16x16x32_bf16(
                        af[m], bv[n], acc[m][n], 0, 0, 0);
        }
    };

    stage(lA0, lB0, 0);
    __syncthreads();
    for (int t = 0; t < nt; t += 2) {
        if (t + 1 < nt) stage(lA1, lB1, t + 1);
        compute(lA0, lB0);
        __syncthreads();
        if (t + 1 < nt) {
            if (t + 2 < nt) stage(lA0, lB0, t + 2);
            compute(lA1, lB1);
            __syncthreads();
        }
    }

    // epilogue: C/D layout col=lane&15, row=(lane>>4)*4+j  [m89/m91 verified]
    const int rbase = m0 + wr * 64 + (lane >> 4) * 4;
    const int cbase = n0 + wc * 64 + lm;
    #pragma unroll
    for (int m = 0; m < 4; ++m) {
        #pragma unroll
        for (int n = 0; n < 4; ++n) {
            int col = cbase + n * 16;
            float bvv = HAS_BIAS ? bias[col] : 0.0f;
            #pragma unroll
            for (int j = 0; j < 4; ++j) {
                int row = rbase + m * 16 + j;
                float v = acc[m][n][j] + bvv;
                if (OUTBF)
                    ((unsigned short*)Cout)[(size_t)row * Ncols + col] = f2bf(v);
                else
                    ((float*)Cout)[(size_t)row * Ncols + col] = v;
            }
        }
    }
}

#define GEMM_SHARED \
    __shared__ unsigned short lA0[8192]; __shared__ unsigned short lA1[8192]; \
    __shared__ unsigned short lB0[8192]; __shared__ unsigned short lB1[8192];

// G1+G3 merged, split-K4: z = g*4+s; partials f32 -> P{g} + s*262144
__global__ __launch_bounds__(256) void gemm_dual_kernel(
    const unsigned short* A, const unsigned short* B0, const unsigned short* B1,
    float* P0, float* P1)
{
    GEMM_SHARED
    const int g = blockIdx.z >> 2, s = blockIdx.z & 3;
    const unsigned short* Bt = (g ? B1 : B0) + s * 256;
    float* C = (g ? P1 : P0) + (size_t)s * 262144;
    gemm_core<0,false>(A + s * 256, Bt, nullptr, C, 1024, 1024, 1024, 256,
                       lA0, lA1, lB0, lB1);
}

// dual split-K reduce: 131072 float4s total (query | qp)
__global__ __launch_bounds__(256) void reduceq_kernel(
    const float* __restrict__ pqQ, const float* __restrict__ pqP,
    float* __restrict__ query, float* __restrict__ qp)
{
    int i = blockIdx.x * 256 + threadIdx.x;
    const float4* p; float4* o; int j;
    if (i < 65536) { p = (const float4*)pqQ; o = (float4*)query; j = i; }
    else           { p = (const float4*)pqP; o = (float4*)qp;    j = i - 65536; }
    float4 a = p[j], b = p[j + 65536], c = p[j + 131072], d = p[j + 196608];
    o[j] = make_float4(a.x + b.x + c.x + d.x, a.y + b.y + c.y + d.y,
                       a.z + b.z + c.z + d.z, a.w + b.w + c.w + d.w);
}

// G4'+G2 merged (z=0: kp_all = enc_emb @ Wk_p; z=1: key = enc @ Wk_i) -> bf16
__global__ __launch_bounds__(256) void gemm24_kernel(
    const unsigned short* encembb, const unsigned short* encb,
    const unsigned short* WkpT, const unsigned short* WkiT,
    unsigned short* kp_all, unsigned short* key)
{
    GEMM_SHARED
    const int z = blockIdx.z;
    const unsigned short* A  = z ? encb : encembb;
    const unsigned short* Bt = z ? WkiT : WkpT;
    unsigned short* C = z ? key : kp_all;
    gemm_core<1,false>(A, Bt, nullptr, C, 1024, 2048, 2048, 2048,
                       lA0, lA1, lB0, lB1);
}

// G5 split-K4: partials f32
__global__ __launch_bounds__(256) void gemm5_kernel(
    const unsigned short* A, const unsigned short* Bt, float* P)
{
    GEMM_SHARED
    const int z = blockIdx.z;
    gemm_core<0,false>(A + z * 768, Bt + z * 768, nullptr,
                       P + (size_t)z * 524288, 2048, 3072, 3072, 768,
                       lA0, lA1, lB0, lB1);
}

// G6+G7 merged, split-K2 each: z = g*2+s; partials -> pg[z]
__global__ __launch_bounds__(256) void gemm67_kernel(
    const unsigned short* xb, const unsigned short* hb,
    const unsigned short* Wih, const unsigned short* Whh, float* pg)
{
    GEMM_SHARED
    const int g = blockIdx.z >> 1, s = blockIdx.z & 1;
    const unsigned short* A  = g ? hb  + s * 512 : xb  + s * 1024;
    const unsigned short* Bt = g ? Whh + s * 512 : Wih + s * 1024;
    const int sAB  = g ? 1024 : 2048;
    const int kLen = g ? 512  : 1024;
    float* C = pg + (size_t)blockIdx.z * 786432;
    gemm_core<0,false>(A, Bt, nullptr, C, 3072, sAB, sAB, kLen, lA0, lA1, lB0, lB1);
}

// ---------------- G8 fused: logits = hnewb @ W_out(f32,(K,N)) + b_out -------
// 256x128 tile (M=256 in ONE block-row -> W_out read exactly once), 8 waves.
// A: bf16 via global_load_lds, linear LDS [256][64].
// B: reg-staged f32 -> bf16, XOR-swizzled LDS [128 n][64 k] (T2: swizzle on
// BOTH write and read of lB; lA untouched). T14 split: loads early, writes late.
__global__ __launch_bounds__(512) void gemm8_fused_kernel(
    const unsigned short* __restrict__ A, const float* __restrict__ Wout,
    const float* __restrict__ bias, float* __restrict__ C)
{
    __shared__ unsigned short lA0[16384]; __shared__ unsigned short lA1[16384];
    __shared__ unsigned short lB0[8192];  __shared__ unsigned short lB1[8192];
    const int tid  = threadIdx.x;
    const int lane = tid & 63, wave = tid >> 6;
    const int wr = wave >> 1, wc = wave & 1;          // 4x2 waves: 64x64 each
    const int n0 = blockIdx.x * 128;
    const int lm = lane & 15, lk = (lane >> 4) * 8;
    const int srow = tid >> 3, schunk = tid & 7;      // A staging (rows 0..63 x4)
    const int bcol = tid & 127, bko = tid >> 7;       // B staging (col, k-16-group)
    const int bsw  = (bcol & 7) << 4;                 // B LDS XOR swizzle

    f32x4 acc[4][4];
    #pragma unroll
    for (int m = 0; m < 4; ++m)
        #pragma unroll
        for (int n = 0; n < 4; ++n) { f32x4 z = {0.f,0.f,0.f,0.f}; acc[m][n] = z; }

    const unsigned short* Ag = A + (size_t)srow * 1024 + schunk * 8;

    auto stageA = [&](unsigned short* la_, int t) {
        char* la = (char*)la_ + tid * 16;
        #pragma unroll
        for (int i = 0; i < 4; ++i)
            gload16(Ag + (size_t)(64 * i) * 1024 + t * 64, la + i * 8192);
    };
    float bv_[16];
    auto loadB = [&](int t) {
        const float* src = Wout + (size_t)(t * 64 + bko * 16) * 32000 + n0 + bcol;
        #pragma unroll
        for (int j = 0; j < 16; ++j) bv_[j] = src[(size_t)j * 32000];
    };
    auto writeB = [&](unsigned short* lb_) {
        ushort8 o0, o1;
        #pragma unroll
        for (int j = 0; j < 8; ++j) { o0[j] = f2bf(bv_[j]); o1[j] = f2bf(bv_[j + 8]); }
        char* base = (char*)lb_ + bcol * 128;
        *(ushort8*)(base + ((bko * 32)      ^ bsw)) = o0;
        *(ushort8*)(base + ((bko * 32 + 16) ^ bsw)) = o1;
    };
    auto compute = [&](const unsigned short* la_, const unsigned short* lb_) {
        #pragma unroll
        for (int kk = 0; kk < 2; ++kk) {
            bf16x8 af[4], bv[4];
            #pragma unroll
            for (int m = 0; m < 4; ++m)
                af[m] = *(const bf16x8*)((const char*)la_ +
                          (wr * 64 + m * 16 + lm) * 128 + (kk * 32 + lk) * 2);
            #pragma unroll
            for (int n = 0; n < 4; ++n) {
                int r = wc * 64 + n * 16 + lm;
                bv[n] = *(const bf16x8*)((const char*)lb_ +
                          r * 128 + (((kk * 32 + lk) * 2) ^ ((r & 7) << 4)));
            }
            #pragma unroll
            for (int m = 0; m < 4; ++m)
                #pragma unroll
                for (int n = 0; n < 4; ++n)
                    acc[m][n] = __builtin_amdgcn_mfma_f32_16x16x32_bf16(
                        af[m], bv[n], acc[m][n], 0, 0, 0);
        }
    };

    // prologue: tile 0
    stageA(lA0, 0); loadB(0); writeB(lB0);
    __syncthreads();
    const int nt = 16;                                 // K=1024 / 64
    for (int t = 0; t < nt; t += 2) {
        if (t + 1 < nt) { stageA(lA1, t + 1); loadB(t + 1); }
        compute(lA0, lB0);
        if (t + 1 < nt) writeB(lB1);
        __syncthreads();
        if (t + 1 < nt) {
            if (t + 2 < nt) { stageA(lA0, t + 2); loadB(t + 2); }
            compute(lA1, lB1);
            if (t + 2 < nt) writeB(lB0);
            __syncthreads();
        }
    }

    const int rbase = wr * 64 + (lane >> 4) * 4;
    const int cbase = n0 + wc * 64 + lm;
    #pragma unroll
    for (int m = 0; m < 4; ++m) {
        #pragma unroll
        for (int n = 0; n < 4; ++n) {
            int col = cbase + n * 16;
            float bvv = bias[col];
            #pragma unroll
            for (int j = 0; j < 4; ++j)
                C[(size_t)(rbase + m * 16 + j) * 32000 + col] = acc[m][n][j] + bvv;
        }
    }
}

// ---------------- additive-attention scores (k bf16, full row) --------------
__global__ __launch_bounds__(256) void attn_scores_kernel(
    const float* __restrict__ q, const unsigned short* __restrict__ k,
    const float* __restrict__ wa, float* __restrict__ scores)
{
    const int bm = blockIdx.x;          // b*20 + m
    const int b  = bm / 20;
    const int tid = threadIdx.x;
    float4 qv  = ((const float4*)(q + (size_t)b * 1024))[tid];
    ushort4 kv = ((const ushort4*)(k + (size_t)bm * 1024))[tid];
    float4 wv  = ((const float4*)wa)[tid];
    float p = tanhf(qv.x + bf2f(kv.x)) * wv.x + tanhf(qv.y + bf2f(kv.y)) * wv.y
            + tanhf(qv.z + bf2f(kv.z)) * wv.z + tanhf(qv.w + bf2f(kv.w)) * wv.w;
    #pragma unroll
    for (int off = 32; off > 0; off >>= 1) p += __shfl_down(p, off);
    __shared__ float sp[4];
    if ((tid & 63) == 0) sp[tid >> 6] = p;
    __syncthreads();
    if (tid == 0) scores[bm] = sp[0] + sp[1] + sp[2] + sp[3];
}

// argmax over ingredient scores (first-max tiebreak = jnp) -> ingredient id
__device__ __forceinline__ int argmax_ing(
    const float* __restrict__ sc_i, const int* __restrict__ input_tensor, int b)
{
    float best = sc_i[b * 20]; int bi = 0;
    #pragma unroll
    for (int m = 1; m < 20; ++m) {
        float v = sc_i[b * 20 + m];
        if (v > best) { best = v; bi = m; }
    }
    return input_tensor[b * 20 + bi];
}

// ---------------- pairing scores: gather kp_all rows by comp_id -------------
__global__ __launch_bounds__(256) void attn_scores_gather_kernel(
    const float* __restrict__ q, const unsigned short* __restrict__ kp_all,
    const float* __restrict__ wa, const float* __restrict__ ba,
    const float* __restrict__ sc_i, const int* __restrict__ input_tensor,
    const int* __restrict__ pairing_ids, float* __restrict__ scores)
{
    const int bm = blockIdx.x;          // b*20 + k
    const int b  = bm / 20;
    const int kk = bm - b * 20;
    const int tid = threadIdx.x;
    const int ing = argmax_ing(sc_i, input_tensor, b);
    const int cid = pairing_ids[ing * 20 + kk];
    float4 qv  = ((const float4*)(q + (size_t)b * 1024))[tid];
    ushort4 kv = ((const ushort4*)(kp_all + (size_t)cid * 1024))[tid];
    float4 wv  = ((const float4*)wa)[tid];
    float p = tanhf(qv.x + bf2f(kv.x)) * wv.x + tanhf(qv.y + bf2f(kv.y)) * wv.y
            + tanhf(qv.z + bf2f(kv.z)) * wv.z + tanhf(qv.w + bf2f(kv.w)) * wv.w;
    #pragma unroll
    for (int off = 32; off > 0; off >>= 1) p += __shfl_down(p, off);
    __shared__ float sp[4];
    if ((tid & 63) == 0) sp[tid >> 6] = p;
    __syncthreads();
    if (tid == 0) scores[bm] = sp[0] + sp[1] + sp[2] + sp[3] + ba[0];
}

// ---------------- out_pair assembly (softmax*s + enc_emb gather folded) -----
__global__ __launch_bounds__(256) void out_pair_kernel(
    const float* __restrict__ s_p, const float* __restrict__ enc_emb,
    const float* __restrict__ sc_i, const int* __restrict__ input_tensor,
    const int* __restrict__ pairing_ids,
    const float* __restrict__ emb_dec, const int* __restrict__ input_ids,
    unsigned short* __restrict__ out_pairb)
{
    const int b = blockIdx.x / 6, seg = blockIdx.x % 6;
    const int tid = threadIdx.x;
    const int d = seg * 512 + tid * 2;
    ushort2 o;
    if (seg < 2) {                       // emb part, d < 1024
        float2 v = *(const float2*)(emb_dec + (size_t)input_ids[b] * 1024 + d);
        o.x = f2bf(v.x); o.y = f2bf(v.y);
    } else {                             // attn_app part: gather enc_emb f32
        const int ing = argmax_ing(sc_i, input_tensor, b);
        __shared__ float s_raw[20];
        if (tid < 20) s_raw[tid] = s_p[b * 20 + tid];
        __syncthreads();
        float mx = -1e30f;
        #pragma unroll
        for (int m = 0; m < 20; ++m) mx = fmaxf(mx, s_raw[m]);
        float den = 0.f; float w[20];
        #pragma unroll
        for (int m = 0; m < 20; ++m) { w[m] = expf(s_raw[m] - mx); den += w[m]; }
        const float inv = 1.f / den;
        const int dd = d - 1024;
        float a0 = 0.f, a1 = 0.f;
        #pragma unroll
        for (int k = 0; k < 20; ++k) {
            const int cid = pairing_ids[ing * 20 + k];
            float2 v = *(const float2*)(enc_emb + (size_t)cid * 2048 + dd);
            float a = w[k] * inv * s_raw[k];           // softmax * raw score
            a0 += a * v.x; a1 += a * v.y;
        }
        o.x = f2bf(a0); o.y = f2bf(a1);
    }
    *(ushort2*)(out_pairb + (size_t)b * 3072 + d) = o;
}

// ---------------- G5 split-K reduce + bias -> bf16 x ------------------------
__global__ __launch_bounds__(256) void reduce5_kernel(
    const float* __restrict__ P, const float* __restrict__ bias,
    unsigned short* __restrict__ xb)
{
    int i = blockIdx.x * 256 + threadIdx.x;        // 131072 float4s
    const float4* p = (const float4*)P;
    float4 a = p[i], b = p[i + 131072], c = p[i + 262144], d = p[i + 393216];
    float4 bb = ((const float4*)bias)[i & 511];
    ((ushort4*)xb)[i] = make_ushort4(f2bf(a.x + b.x + c.x + d.x + bb.x),
                                     f2bf(a.y + b.y + c.y + d.y + bb.y),
                                     f2bf(a.z + b.z + c.z + d.z + bb.z),
                                     f2bf(a.w + b.w + c.w + d.w + bb.w));
}

// ---------------- GRU pointwise + split-K reduce (gate order r,z,n) ---------
__global__ __launch_bounds__(256) void gru_kernel(
    const float* __restrict__ pg, const float* __restrict__ b_ih,
    const float* __restrict__ b_hh, const float* __restrict__ h,
    unsigned short* __restrict__ hnewb)
{
    int idx = blockIdx.x * 256 + threadIdx.x;       // 262144
    int b = idx >> 10, j = idx & 1023;
    const float* gi0 = pg + (size_t)b * 3072;
    const float* gi1 = gi0 + 786432;
    const float* gh0 = gi0 + 2 * 786432;
    const float* gh1 = gi0 + 3 * 786432;
    float ir  = gi0[j]        + gi1[j]        + b_ih[j];
    float iz  = gi0[1024 + j] + gi1[1024 + j] + b_ih[1024 + j];
    float in_ = gi0[2048 + j] + gi1[2048 + j] + b_ih[2048 + j];
    float hr  = gh0[j]        + gh1[j]        + b_hh[j];
    float hz  = gh0[1024 + j] + gh1[1024 + j] + b_hh[1024 + j];
    float hn  = gh0[2048 + j] + gh1[2048 + j] + b_hh[2048 + j];
    float r = 1.f / (1.f + expf(-(ir + hr)));
    float z = 1.f / (1.f + expf(-(iz + hz)));
    float n = tanhf(in_ + r * hn);
    hnewb[idx] = f2bf((1.f - z) * n + z * h[idx]);
}

// ---------------------------------------------------------------------------
extern "C" void kernel_launch(void* const* d_in, const int* in_sizes, int n_in,
                              void* d_out, int out_size, void* d_ws, size_t ws_size,
                              hipStream_t stream)
{
    const int*   input_ids    = (const int*)  d_in[0];
    const float* hidden       = (const float*)d_in[1];
    const float* enc_out      = (const float*)d_in[2];
    const int*   input_tensor = (const int*)  d_in[3];
    const int*   pairing_ids  = (const int*)  d_in[4];
    const float* emb_dec      = (const float*)d_in[5];
    const float* enc_emb      = (const float*)d_in[6];
    const float* Wq_i  = (const float*)d_in[7];
    const float* Wk_i  = (const float*)d_in[8];
    const float* wa_i  = (const float*)d_in[9];
    const float* Wq_p  = (const float*)d_in[10];
    const float* Wk_p  = (const float*)d_in[11];
    const float* wa_p  = (const float*)d_in[12];
    const float* ba_p  = (const float*)d_in[13];
    const float* W_lin = (const float*)d_in[14];
    const float* b_lin = (const float*)d_in[15];
    const float* W_ih  = (const float*)d_in[16];
    const float* W_hh  = (const float*)d_in[17];
    const float* b_ih  = (const float*)d_in[18];
    const float* b_hh  = (const float*)d_in[19];
    const float* W_out = (const float*)d_in[20];
    const float* b_out = (const float*)d_in[21];

    // ---- workspace layout (time-shared slots, lifetimes serial) ------------
    constexpr size_t OFF_HB    = 0;            // bf16 h, alive all
    constexpr size_t OFF_HNEW  = 524288;       // bf16 h_new, gru..G8
    constexpr size_t OFF_WQI   = 1048576;      // WqiT 2MB (..dual)
    constexpr size_t OFF_WQP   = 3145728;      // WqpT 2MB (..dual)
    constexpr size_t OFF_WKI   = 5242880;      // pqQ 4MB (dual..reduceq) -> WkiT
    constexpr size_t OFF_WKP   = 9437184;      // pqP 4MB (dual..reduceq) -> WkpT
    constexpr size_t OFF_ENC   = 13631488;     // encb 21MB (prep..gemm24)
    constexpr size_t OFF_SLOT1 = 34603008;     // kp_all[0,10.5M)+key[10.5,21M)
                                               //   -> outp/pG5/xb
    constexpr size_t OFF_SLOT2 = 55574528;     // encembb (..gemm24) -> WlinT(..G5)
                                               //   -> Wihb/Whhb (..G67)
    constexpr size_t OFF_QUERY = 76546048;     // f32 1MB (reduceq..scores_i)
    constexpr size_t OFF_QP    = 77594624;     // f32 1MB (reduceq..scores_p)
    constexpr size_t OFF_SCI   = 78643200;     // 24KB
    constexpr size_t OFF_SCP   = 78667776;     // 20KB
    constexpr size_t OFF_PGI   = 1048576;      // G67 partials 12.6MB (..gru)
    constexpr size_t NEED      = 79167488;
    if (ws_size < NEED) {
        fprintf(stderr, "kernel_launch: ws_size %zu < needed %zu\n", ws_size, NEED);
        return;
    }
    char* ws = (char*)d_ws;
    unsigned short* hb     = (unsigned short*)(ws + OFF_HB);
    unsigned short* hnewb  = (unsigned short*)(ws + OFF_HNEW);
    unsigned short* WqiT   = (unsigned short*)(ws + OFF_WQI);
    unsigned short* WqpT   = (unsigned short*)(ws + OFF_WQP);
    float*          pqQ    = (float*)         (ws + OFF_WKI);   // dual partials
    float*          pqP    = (float*)         (ws + OFF_WKP);
    unsigned short* WkiT   = (unsigned short*)(ws + OFF_WKI);   // after reduceq
    unsigned short* WkpT   = (unsigned short*)(ws + OFF_WKP);
    unsigned short* encb   = (unsigned short*)(ws + OFF_ENC);
    unsigned short* kp_all = (unsigned short*)(ws + OFF_SLOT1);
    unsigned short* key    = (unsigned short*)(ws + OFF_SLOT1 + 10485760);
    unsigned short* encembb= (unsigned short*)(ws + OFF_SLOT2);
    unsigned short* WlinT  = (unsigned short*)(ws + OFF_SLOT2); // after gemm24
    unsigned short* Wihb   = (unsigned short*)(ws + OFF_SLOT2); // after gemm5
    unsigned short* Whhb   = (unsigned short*)(ws + OFF_SLOT2 + 12582912);
    unsigned short* outp   = (unsigned short*)(ws + OFF_SLOT1); // after scores_p
    float*          pG5    = (float*)         (ws + OFF_SLOT1 + 1572864);
    unsigned short* xb     = (unsigned short*)(ws + OFF_SLOT1 + 9961472);
    float*          query  = (float*)         (ws + OFF_QUERY);
    float*          qp     = (float*)         (ws + OFF_QP);
    float*          sc_i   = (float*)         (ws + OFF_SCI);
    float*          sc_p   = (float*)         (ws + OFF_SCP);
    float*          pgi    = (float*)         (ws + OFF_PGI);

    // 1. activation/table converts -> bf16
    prep_conv_kernel<<<20496, 256, 0, stream>>>(hidden, enc_out, enc_emb,
                                                hb, encb, encembb);

    // 2-4. Wq transposes; dual split-K4 -> partials in WkT slots; reduce
    transpose2_kernel<<<dim3(32, 8, 2), 256, 0, stream>>>(Wq_i, Wq_p, WqiT, WqpT, 1024, 1024);
    gemm_dual_kernel<<<dim3(8, 2, 8), 256, 0, stream>>>(hb, WqiT, WqpT, pqQ, pqP);
    reduceq_kernel<<<512, 256, 0, stream>>>(pqQ, pqP, query, qp);

    // 5. Wk transposes (overwrite dual partials - dead after reduceq)
    transpose2_kernel<<<dim3(32, 16, 2), 256, 0, stream>>>(Wk_i, Wk_p, WkiT, WkpT, 2048, 1024);

    // 6. G4'+G2 merged: kp_all = enc_emb @ Wk_p ; key = enc @ Wk_i (bf16)
    gemm24_kernel<<<dim3(8, 40, 2), 256, 0, stream>>>(encembb, encb, WkpT, WkiT,
                                                      kp_all, key);

    // 7-8. ingredient scores; pairing scores (argmax + kp_all gather folded)
    attn_scores_kernel<<<5120, 256, 0, stream>>>(query, key, wa_i, sc_i);
    attn_scores_gather_kernel<<<5120, 256, 0, stream>>>(qp, kp_all, wa_p, ba_p,
                                                        sc_i, input_tensor, pairing_ids, sc_p);

    // 9. out_pair = [emb | softmax(s)*s @ enc_emb-gather]  (all folded)
    out_pair_kernel<<<1536, 256, 0, stream>>>(sc_p, enc_emb, sc_i, input_tensor,
                                              pairing_ids, emb_dec, input_ids, outp);

    // 10-12. G5: x = out_pair @ W_lin + b_lin  (split-K4 -> reduce -> bf16)
    transpose1_kernel<<<dim3(64, 24), 256, 0, stream>>>(W_lin, WlinT, 3072, 2048);
    gemm5_kernel<<<dim3(16, 2, 4), 256, 0, stream>>>(outp, WlinT, pG5);
    reduce5_kernel<<<512, 256, 0, stream>>>(pG5, b_lin, xb);

    // 13-14. G6+G7 merged, split-K2 each (Wihb overwrites WlinT - dead)
    conv2w_kernel<<<9216, 256, 0, stream>>>(W_ih, W_hh, Wihb, Whhb);
    gemm67_kernel<<<dim3(24, 2, 4), 256, 0, stream>>>(xb, hb, Wihb, Whhb, pgi);

    // 15. GRU pointwise (+ split-K reduce + biases) -> h_new bf16
    gru_kernel<<<1024, 256, 0, stream>>>(pgi, b_ih, b_hh, hidden, hnewb);

    // 16. G8 fused: logits = h_new @ W_out + b_out (W_out f32 read in-GEMM)
    gemm8_fused_kernel<<<250, 512, 0, stream>>>(hnewb, W_out, b_out, (float*)d_out);
}

// Round 7
// 249.888 us; speedup vs baseline: 2.0111x; 1.0307x over previous
//
#include <hip/hip_runtime.h>
#include <cstdio>

// ---------------------------------------------------------------------------
// PairAttnDecoderRNN forward, MI355X/gfx950.  Round 7:
//  - gemm24: bijective XCD-aware 1D block swizzle (T1) — XCDs 0-3 do the
//    kp_all GEMM, 4-7 the key GEMM; 10 contiguous m-panels per XCD so the
//    shared A-panels stay in one XCD's L2 (FETCH was 171MB vs ~50 ideal)
//  - gemm8: 256x64 tile, 4 waves, grid 500 (2 blk/CU, was 1)
//  - gemm5 split-K8, gemm67 split-K8 (partials in freed [1M,34.6M) window)
//  - prep1 = converts + Wq/Wk transposes in one launch; 14 launches total
// ---------------------------------------------------------------------------

using f32x4   = __attribute__((ext_vector_type(4))) float;
using bf16x8  = __attribute__((ext_vector_type(8))) short;
using ushort8 = __attribute__((ext_vector_type(8))) unsigned short;

__device__ __forceinline__ unsigned short f2bf(float x) {
    unsigned u = __builtin_bit_cast(unsigned, x);
    u += 0x7fffu + ((u >> 16) & 1u);          // RNE
    return (unsigned short)(u >> 16);
}
__device__ __forceinline__ float bf2f(unsigned short u) {
    return __builtin_bit_cast(float, ((unsigned)u) << 16);
}

// async global->LDS, 16B per lane. LDS dest = wave-uniform base + lane*16.
__device__ __forceinline__ void gload16(const void* g, void* l) {
    auto gp = (const __attribute__((address_space(1))) void*)g;
    auto lp = (__attribute__((address_space(3))) void*)l;
    __builtin_amdgcn_global_load_lds(gp, lp, 16, 0, 0);
}

// ---------------- (R,C) fp32 -> (C,R) bf16 transpose body, 128r x 32c tile --
__device__ __forceinline__ void transpose_body(
    const float* __restrict__ in, unsigned short* __restrict__ out,
    int R, int C, int r0, int c0)
{
    __shared__ float t[32][129];
    const int tid = threadIdx.x;
    const int lr = tid >> 3;              // 0..31
    const int cc = (tid & 7) * 4;         // col chunk
    #pragma unroll
    for (int i = 0; i < 4; ++i) {
        int r = lr + 32 * i;
        float4 v = *(const float4*)(in + (size_t)(r0 + r) * C + c0 + cc);
        t[cc + 0][r] = v.x; t[cc + 1][r] = v.y;
        t[cc + 2][r] = v.z; t[cc + 3][r] = v.w;
    }
    __syncthreads();
    const int rc = (tid & 15) * 8;        // r chunk (8 outputs = 16B store)
    #pragma unroll
    for (int p = 0; p < 2; ++p) {
        int c = (tid >> 4) + 16 * p;
        const float* src = &t[c][rc];
        ushort8 o;
        #pragma unroll
        for (int j = 0; j < 8; ++j) o[j] = f2bf(src[j]);
        *(ushort8*)(out + (size_t)(c0 + c) * R + r0 + rc) = o;
    }
}

// ---------------- prep1: all input converts + Wq/Wk transposes --------------
// blocks [0,20496): f32->bf16 hidden|enc_out|enc_emb (float4 units)
// blocks [20496,21008): Wq_i/Wq_p transpose (1024x1024 each)
// blocks [21008,22032): Wk_i/Wk_p transpose (2048x1024 each)
__global__ __launch_bounds__(256) void prep1_kernel(
    const float* __restrict__ hidden, const float* __restrict__ enc_out,
    const float* __restrict__ enc_emb,
    const float* __restrict__ Wq_i, const float* __restrict__ Wq_p,
    const float* __restrict__ Wk_i, const float* __restrict__ Wk_p,
    unsigned short* __restrict__ hb, unsigned short* __restrict__ encb,
    unsigned short* __restrict__ encembb,
    unsigned short* __restrict__ WqiT, unsigned short* __restrict__ WqpT,
    unsigned short* __restrict__ WkiT, unsigned short* __restrict__ WkpT)
{
    const int bid = blockIdx.x;
    if (bid < 20496) {
        int i = bid * 256 + threadIdx.x;   // total 5,246,976 quads
        const float* src; unsigned short* dst; int j;
        if (i < 65536)        { src = hidden;  dst = hb;      j = i; }
        else if (i < 2686976) { src = enc_out; dst = encb;    j = i - 65536; }
        else                  { src = enc_emb; dst = encembb; j = i - 2686976; }
        float4 v = ((const float4*)src)[j];
        ((ushort4*)dst)[j] = make_ushort4(f2bf(v.x), f2bf(v.y), f2bf(v.z), f2bf(v.w));
    } else if (bid < 21008) {
        int local = bid - 20496;           // 512: z(2) x by(8) x bx(32)
        int bz = local >> 8, rem = local & 255;
        transpose_body(bz ? Wq_p : Wq_i, bz ? WqpT : WqiT,
                       1024, 1024, (rem >> 5) * 128, (rem & 31) * 32);
    } else {
        int local = bid - 21008;           // 1024: z(2) x by(16) x bx(32)
        int bz = local >> 9, rem = local & 511;
        transpose_body(bz ? Wk_p : Wk_i, bz ? WkpT : WkiT,
                       2048, 1024, (rem >> 5) * 128, (rem & 31) * 32);
    }
}

// ---------------- W_lin transpose (after gemm24 frees SLOT2) ----------------
__global__ __launch_bounds__(256) void transpose1_kernel(
    const float* in, unsigned short* out, int R, int C)
{ transpose_body(in, out, R, C, blockIdx.y * 128, blockIdx.x * 32); }

// ---------------- W_ih | W_hh fp32 -> bf16 (one launch) ---------------------
// W_ih: 1,572,864 float4s; W_hh: 786,432 -> 9216 blocks total.
__global__ __launch_bounds__(256) void conv2w_kernel(
    const float* __restrict__ Wih, const float* __restrict__ Whh,
    unsigned short* __restrict__ ob0, unsigned short* __restrict__ ob1)
{
    int i = blockIdx.x * 256 + threadIdx.x;
    const float* src; unsigned short* dst; int j;
    if (i < 1572864) { src = Wih; dst = ob0; j = i; }
    else             { src = Whh; dst = ob1; j = i - 1572864; }
    float4 v = ((const float4*)src)[j];
    ((ushort4*)dst)[j] = make_ushort4(f2bf(v.x), f2bf(v.y), f2bf(v.z), f2bf(v.w));
}

// ---------------- bf16 MFMA GEMM core: C(M,N) = A(M,K) * Bt(N,K)^T ----------
// 128x128 tile, BK=64, 4 waves 2x2, 16x16x32 MFMA, global_load_lds width=16.
// Depth-1 pipeline: stage(next) issued BEFORE compute(cur).
template<int OUTBF, bool HAS_BIAS>
__device__ __forceinline__ void gemm_core(
    const unsigned short* __restrict__ A, const unsigned short* __restrict__ Bt,
    const float* __restrict__ bias, void* __restrict__ Cout, int Ncols,
    int sA, int sB, int kLen, int m0, int n0,
    unsigned short* lA0, unsigned short* lA1,
    unsigned short* lB0, unsigned short* lB1)
{
    const int tid = threadIdx.x;
    const int lane = tid & 63, wave = tid >> 6;
    const int wr = wave >> 1, wc = wave & 1;
    const int srow = tid >> 3, schunk = tid & 7;
    const int lm = lane & 15, lk = (lane >> 4) * 8;

    f32x4 acc[4][4];
    #pragma unroll
    for (int m = 0; m < 4; ++m)
        #pragma unroll
        for (int n = 0; n < 4; ++n) { f32x4 z = {0.f,0.f,0.f,0.f}; acc[m][n] = z; }

    const unsigned short* Ag = A  + (size_t)(m0 + srow) * sA + schunk * 8;
    const unsigned short* Bg = Bt + (size_t)(n0 + srow) * sB + schunk * 8;
    const int nt = kLen >> 6;

    auto stage = [&](unsigned short* la_, unsigned short* lb_, int t) {
        char* la = (char*)la_ + tid * 16;
        char* lb = (char*)lb_ + tid * 16;
        #pragma unroll
        for (int i = 0; i < 4; ++i) {
            gload16(Ag + (size_t)(32 * i) * sA + t * 64, la + i * 4096);
            gload16(Bg + (size_t)(32 * i) * sB + t * 64, lb + i * 4096);
        }
    };
    auto compute = [&](const unsigned short* la_, const unsigned short* lb_) {
        #pragma unroll
        for (int kk = 0; kk < 2; ++kk) {
            bf16x8 af[4], bv[4];
            #pragma unroll
            for (int m = 0; m < 4; ++m)
                af[m] = *(const bf16x8*)((const char*)la_ +
                          (wr * 64 + m * 16 + lm) * 128 + (kk * 32 + lk) * 2);
            #pragma unroll
            for (int n = 0; n < 4; ++n)
                bv[n] = *(const bf16x8*)((const char*)lb_ +
                          (wc * 64 + n * 16 + lm) * 128 + (kk * 32 + lk) * 2);
            #pragma unroll
            for (int m = 0; m < 4; ++m)
                #pragma unroll
                for (int n = 0; n < 4; ++n)
                    acc[m][n] = __builtin_amdgcn_mfma_f32_16x16x32_bf16(
                        af[m], bv[n], acc[m][n], 0, 0, 0);
        }
    };

    stage(lA0, lB0, 0);
    __syncthreads();
    for (int t = 0; t < nt; t += 2) {
        if (t + 1 < nt) stage(lA1, lB1, t + 1);
        compute(lA0, lB0);
        __syncthreads();
        if (t + 1 < nt) {
            if (t + 2 < nt) stage(lA0, lB0, t + 2);
            compute(lA1, lB1);
            __syncthreads();
        }
    }

    // epilogue: C/D layout col=lane&15, row=(lane>>4)*4+j  [m89/m91 verified]
    const int rbase = m0 + wr * 64 + (lane >> 4) * 4;
    const int cbase = n0 + wc * 64 + lm;
    #pragma unroll
    for (int m = 0; m < 4; ++m) {
        #pragma unroll
        for (int n = 0; n < 4; ++n) {
            int col = cbase + n * 16;
            float bvv = HAS_BIAS ? bias[col] : 0.0f;
            #pragma unroll
            for (int j = 0; j < 4; ++j) {
                int row = rbase + m * 16 + j;
                float v = acc[m][n][j] + bvv;
                if (OUTBF)
                    ((unsigned short*)Cout)[(size_t)row * Ncols + col] = f2bf(v);
                else
                    ((float*)Cout)[(size_t)row * Ncols + col] = v;
            }
        }
    }
}

#define GEMM_SHARED \
    __shared__ unsigned short lA0[8192]; __shared__ unsigned short lA1[8192]; \
    __shared__ unsigned short lB0[8192]; __shared__ unsigned short lB1[8192];

// G1+G3 merged, split-K4: z = g*4+s; partials f32 -> P{g} + s*262144
__global__ __launch_bounds__(256) void gemm_dual_kernel(
    const unsigned short* A, const unsigned short* B0, const unsigned short* B1,
    float* P0, float* P1)
{
    GEMM_SHARED
    const int g = blockIdx.z >> 2, s = blockIdx.z & 3;
    const unsigned short* Bt = (g ? B1 : B0) + s * 256;
    float* C = (g ? P1 : P0) + (size_t)s * 262144;
    gemm_core<0,false>(A + s * 256, Bt, nullptr, C, 1024, 1024, 1024, 256,
                       blockIdx.y * 128, blockIdx.x * 128, lA0, lA1, lB0, lB1);
}

// dual split-K reduce: 131072 float4s total (query | qp)
__global__ __launch_bounds__(256) void reduceq_kernel(
    const float* __restrict__ pqQ, const float* __restrict__ pqP,
    float* __restrict__ query, float* __restrict__ qp)
{
    int i = blockIdx.x * 256 + threadIdx.x;
    const float4* p; float4* o; int j;
    if (i < 65536) { p = (const float4*)pqQ; o = (float4*)query; j = i; }
    else           { p = (const float4*)pqP; o = (float4*)qp;    j = i - 65536; }
    float4 a = p[j], b = p[j + 65536], c = p[j + 131072], d = p[j + 196608];
    o[j] = make_float4(a.x + b.x + c.x + d.x, a.y + b.y + c.y + d.y,
                       a.z + b.z + c.z + d.z, a.w + b.w + c.w + d.w);
}

// G4'+G2 merged with bijective XCD swizzle (T1). 1D grid 640.
// xcd = id&7: XCDs 0-3 -> z=0 (kp_all = enc_emb @ Wk_p), 4-7 -> z=1 (key).
// Each XCD owns 10 contiguous m-panels x all 8 n-panels -> A-panel L2-local.
__global__ __launch_bounds__(256) void gemm24_kernel(
    const unsigned short* encembb, const unsigned short* encb,
    const unsigned short* WkpT, const unsigned short* WkiT,
    unsigned short* kp_all, unsigned short* key)
{
    GEMM_SHARED
    const int id  = blockIdx.x;
    const int xcd = id & 7;
    const int z   = xcd >> 2, q = xcd & 3;
    const int r   = id >> 3;              // 0..79
    const int mi  = q * 10 + (r >> 3);    // 0..39
    const int n   = r & 7;
    const unsigned short* A  = z ? encb : encembb;
    const unsigned short* Bt = z ? WkiT : WkpT;
    unsigned short* C = z ? key : kp_all;
    gemm_core<1,false>(A, Bt, nullptr, C, 1024, 2048, 2048, 2048,
                       mi * 128, n * 128, lA0, lA1, lB0, lB1);
}

// G5 split-K8: z=0..7, kLen 384; partials f32
__global__ __launch_bounds__(256) void gemm5_kernel(
    const unsigned short* A, const unsigned short* Bt, float* P)
{
    GEMM_SHARED
    const int z = blockIdx.z;
    gemm_core<0,false>(A + z * 384, Bt + z * 384, nullptr,
                       P + (size_t)z * 524288, 2048, 3072, 3072, 384,
                       blockIdx.y * 128, blockIdx.x * 128, lA0, lA1, lB0, lB1);
}

// G6+G7 merged, split-K4 each: z = g*4+s; partials -> pg + z*786432
__global__ __launch_bounds__(256) void gemm67_kernel(
    const unsigned short* xb, const unsigned short* hb,
    const unsigned short* Wih, const unsigned short* Whh, float* pg)
{
    GEMM_SHARED
    const int g = blockIdx.z >> 2, s = blockIdx.z & 3;
    const unsigned short* A  = g ? hb  + s * 256 : xb  + s * 512;
    const unsigned short* Bt = g ? Whh + s * 256 : Wih + s * 512;
    const int sAB  = g ? 1024 : 2048;
    const int kLen = g ? 256  : 512;
    float* C = pg + (size_t)blockIdx.z * 786432;
    gemm_core<0,false>(A, Bt, nullptr, C, 3072, sAB, sAB, kLen,
                       blockIdx.y * 128, blockIdx.x * 128, lA0, lA1, lB0, lB1);
}

// ---------------- G8 fused: logits = hnewb @ W_out(f32,(K,N)) + b_out -------
// 256x64 tile, 4 waves stacked on M, grid 500 (2 blk/CU, LDS 80KB).
// A: bf16 gload_lds, linear [256][64]. B: reg-staged f32->bf16, XOR-swizzled
// LDS (write AND read). W_out read exactly once; A is L2-resident.
__global__ __launch_bounds__(256) void gemm8_kernel(
    const unsigned short* __restrict__ A, const float* __restrict__ Wout,
    const float* __restrict__ bias, float* __restrict__ C)
{
    __shared__ unsigned short lA0[16384]; __shared__ unsigned short lA1[16384];
    __shared__ unsigned short lB0[4096];  __shared__ unsigned short lB1[4096];
    const int tid  = threadIdx.x;
    const int lane = tid & 63, wave = tid >> 6;
    const int n0 = blockIdx.x * 64;
    const int lm = lane & 15, lk = (lane >> 4) * 8;
    const int srow = tid >> 3, schunk = tid & 7;      // A staging
    const int bcol = tid & 63, bkg = tid >> 6;        // B staging (col, k-grp)
    const int bsw  = (bcol & 7) << 4;                 // B LDS XOR swizzle

    f32x4 acc[4][4];
    #pragma unroll
    for (int m = 0; m < 4; ++m)
        #pragma unroll
        for (int n = 0; n < 4; ++n) { f32x4 z = {0.f,0.f,0.f,0.f}; acc[m][n] = z; }

    const unsigned short* Ag = A + (size_t)srow * 1024 + schunk * 8;

    auto stageA = [&](unsigned short* la_, int t) {
        char* la = (char*)la_ + tid * 16;
        #pragma unroll
        for (int i = 0; i < 8; ++i)
            gload16(Ag + (size_t)(32 * i) * 1024 + t * 64, la + i * 4096);
    };
    float bv_[16];
    auto loadB = [&](int t) {
        const float* src = Wout + (size_t)(t * 64 + bkg * 16) * 32000 + n0 + bcol;
        #pragma unroll
        for (int j = 0; j < 16; ++j) bv_[j] = src[(size_t)j * 32000];
    };
    auto writeB = [&](unsigned short* lb_) {
        ushort8 o0, o1;
        #pragma unroll
        for (int j = 0; j < 8; ++j) { o0[j] = f2bf(bv_[j]); o1[j] = f2bf(bv_[j + 8]); }
        char* base = (char*)lb_ + bcol * 128;
        *(ushort8*)(base + ((bkg * 32)      ^ bsw)) = o0;
        *(ushort8*)(base + ((bkg * 32 + 16) ^ bsw)) = o1;
    };
    auto compute = [&](const unsigned short* la_, const unsigned short* lb_) {
        #pragma unroll
        for (int kk = 0; kk < 2; ++kk) {
            bf16x8 af[4], bv[4];
            #pragma unroll
            for (int m = 0; m < 4; ++m)
                af[m] = *(const bf16x8*)((const char*)la_ +
                          (wave * 64 + m * 16 + lm) * 128 + (kk * 32 + lk) * 2);
            #pragma unroll
            for (int n = 0; n < 4; ++n) {
                int rr = n * 16 + lm;
                bv[n] = *(const bf16x8*)((const char*)lb_ +
                          rr * 128 + (((kk * 32 + lk) * 2) ^ ((rr & 7) << 4)));
            }
            #pragma unroll
            for (int m = 0; m < 4; ++m)
                #pragma unroll
                for (int n = 0; n < 4; ++n)
                    acc[m][n] = __builtin_amdgcn_mfma_f32_16x16x32_bf16(
                        af[m], bv[n], acc[m][n], 0, 0, 0);
        }
    };

    stageA(lA0, 0); loadB(0); writeB(lB0);
    __syncthreads();
    const int nt = 16;                                 // K=1024 / 64
    for (int t = 0; t < nt; t += 2) {
        if (t + 1 < nt) { stageA(lA1, t + 1); loadB(t + 1); }
        compute(lA0, lB0);
        if (t + 1 < nt) writeB(lB1);
        __syncthreads();
        if (t + 1 < nt) {
            if (t + 2 < nt) { stageA(lA0, t + 2); loadB(t + 2); }
            compute(lA1, lB1);
            if (t + 2 < nt) writeB(lB0);
            __syncthreads();
        }
    }

    const int rbase = wave * 64 + (lane >> 4) * 4;
    const int cbase = n0 + lm;
    #pragma unroll
    for (int m = 0; m < 4; ++m) {
        #pragma unroll
        for (int n = 0; n < 4; ++n) {
            int col = cbase + n * 16;
            float bvv = bias[col];
            #pragma unroll
            for (int j = 0; j < 4; ++j)
                C[(size_t)(rbase + m * 16 + j) * 32000 + col] = acc[m][n][j] + bvv;
        }
    }
}

// ---------------- additive-attention scores (k bf16, full row) --------------
__global__ __launch_bounds__(256) void attn_scores_kernel(
    const float* __restrict__ q, const unsigned short* __restrict__ k,
    const float* __restrict__ wa, float* __restrict__ scores)
{
    const int bm = blockIdx.x;          // b*20 + m
    const int b  = bm / 20;
    const int tid = threadIdx.x;
    float4 qv  = ((const float4*)(q + (size_t)b * 1024))[tid];
    ushort4 kv = ((const ushort4*)(k + (size_t)bm * 1024))[tid];
    float4 wv  = ((const float4*)wa)[tid];
    float p = tanhf(qv.x + bf2f(kv.x)) * wv.x + tanhf(qv.y + bf2f(kv.y)) * wv.y
            + tanhf(qv.z + bf2f(kv.z)) * wv.z + tanhf(qv.w + bf2f(kv.w)) * wv.w;
    #pragma unroll
    for (int off = 32; off > 0; off >>= 1) p += __shfl_down(p, off);
    __shared__ float sp[4];
    if ((tid & 63) == 0) sp[tid >> 6] = p;
    __syncthreads();
    if (tid == 0) scores[bm] = sp[0] + sp[1] + sp[2] + sp[3];
}

// argmax over ingredient scores (first-max tiebreak = jnp) -> ingredient id
__device__ __forceinline__ int argmax_ing(
    const float* __restrict__ sc_i, const int* __restrict__ input_tensor, int b)
{
    float best = sc_i[b * 20]; int bi = 0;
    #pragma unroll
    for (int m = 1; m < 20; ++m) {
        float v = sc_i[b * 20 + m];
        if (v > best) { best = v; bi = m; }
    }
    return input_tensor[b * 20 + bi];
}

// ---------------- pairing scores: gather kp_all rows by comp_id -------------
__global__ __launch_bounds__(256) void attn_scores_gather_kernel(
    const float* __restrict__ q, const unsigned short* __restrict__ kp_all,
    const float* __restrict__ wa, const float* __restrict__ ba,
    const float* __restrict__ sc_i, const int* __restrict__ input_tensor,
    const int* __restrict__ pairing_ids, float* __restrict__ scores)
{
    const int bm = blockIdx.x;          // b*20 + k
    const int b  = bm / 20;
    const int kk = bm - b * 20;
    const int tid = threadIdx.x;
    const int ing = argmax_ing(sc_i, input_tensor, b);
    const int cid = pairing_ids[ing * 20 + kk];
    float4 qv  = ((const float4*)(q + (size_t)b * 1024))[tid];
    ushort4 kv = ((const ushort4*)(kp_all + (size_t)cid * 1024))[tid];
    float4 wv  = ((const float4*)wa)[tid];
    float p = tanhf(qv.x + bf2f(kv.x)) * wv.x + tanhf(qv.y + bf2f(kv.y)) * wv.y
            + tanhf(qv.z + bf2f(kv.z)) * wv.z + tanhf(qv.w + bf2f(kv.w)) * wv.w;
    #pragma unroll
    for (int off = 32; off > 0; off >>= 1) p += __shfl_down(p, off);
    __shared__ float sp[4];
    if ((tid & 63) == 0) sp[tid >> 6] = p;
    __syncthreads();
    if (tid == 0) scores[bm] = sp[0] + sp[1] + sp[2] + sp[3] + ba[0];
}

// ---------------- out_pair assembly (softmax*s + enc_emb gather folded) -----
__global__ __launch_bounds__(256) void out_pair_kernel(
    const float* __restrict__ s_p, const float* __restrict__ enc_emb,
    const float* __restrict__ sc_i, const int* __restrict__ input_tensor,
    const int* __restrict__ pairing_ids,
    const float* __restrict__ emb_dec, const int* __restrict__ input_ids,
    unsigned short* __restrict__ out_pairb)
{
    const int b = blockIdx.x / 6, seg = blockIdx.x % 6;
    const int tid = threadIdx.x;
    const int d = seg * 512 + tid * 2;
    ushort2 o;
    if (seg < 2) {                       // emb part, d < 1024
        float2 v = *(const float2*)(emb_dec + (size_t)input_ids[b] * 1024 + d);
        o.x = f2bf(v.x); o.y = f2bf(v.y);
    } else {                             // attn_app part: gather enc_emb f32
        const int ing = argmax_ing(sc_i, input_tensor, b);
        __shared__ float s_raw[20];
        if (tid < 20) s_raw[tid] = s_p[b * 20 + tid];
        __syncthreads();
        float mx = -1e30f;
        #pragma unroll
        for (int m = 0; m < 20; ++m) mx = fmaxf(mx, s_raw[m]);
        float den = 0.f; float w[20];
        #pragma unroll
        for (int m = 0; m < 20; ++m) { w[m] = expf(s_raw[m] - mx); den += w[m]; }
        const float inv = 1.f / den;
        const int dd = d - 1024;
        float a0 = 0.f, a1 = 0.f;
        #pragma unroll
        for (int k = 0; k < 20; ++k) {
            const int cid = pairing_ids[ing * 20 + k];
            float2 v = *(const float2*)(enc_emb + (size_t)cid * 2048 + dd);
            float a = w[k] * inv * s_raw[k];           // softmax * raw score
            a0 += a * v.x; a1 += a * v.y;
        }
        o.x = f2bf(a0); o.y = f2bf(a1);
    }
    *(ushort2*)(out_pairb + (size_t)b * 3072 + d) = o;
}

// ---------------- G5 split-K8 reduce + bias -> bf16 x -----------------------
__global__ __launch_bounds__(256) void reduce5_kernel(
    const float* __restrict__ P, const float* __restrict__ bias,
    unsigned short* __restrict__ xb)
{
    int i = blockIdx.x * 256 + threadIdx.x;        // 131072 float4s
    const float4* p = (const float4*)P;
    float4 bb = ((const float4*)bias)[i & 511];
    float s0 = bb.x, s1 = bb.y, s2 = bb.z, s3 = bb.w;
    #pragma unroll
    for (int s = 0; s < 8; ++s) {
        float4 v = p[i + s * 131072];
        s0 += v.x; s1 += v.y; s2 += v.z; s3 += v.w;
    }
    ((ushort4*)xb)[i] = make_ushort4(f2bf(s0), f2bf(s1), f2bf(s2), f2bf(s3));
}

// ---------------- GRU pointwise + split-K8 reduce (gate order r,z,n) --------
__global__ __launch_bounds__(256) void gru_kernel(
    const float* __restrict__ pg, const float* __restrict__ b_ih,
    const float* __restrict__ b_hh, const float* __restrict__ h,
    unsigned short* __restrict__ hnewb)
{
    int idx = blockIdx.x * 256 + threadIdx.x;       // 262144
    int b = idx >> 10, j = idx & 1023;
    float ir = b_ih[j], iz = b_ih[1024 + j], in_ = b_ih[2048 + j];
    float hr = b_hh[j], hz = b_hh[1024 + j], hn  = b_hh[2048 + j];
    #pragma unroll
    for (int s = 0; s < 4; ++s) {
        const float* gi = pg + (size_t)s * 786432 + (size_t)b * 3072;
        ir  += gi[j]; iz += gi[1024 + j]; in_ += gi[2048 + j];
        const float* gh = pg + (size_t)(4 + s) * 786432 + (size_t)b * 3072;
        hr  += gh[j]; hz += gh[1024 + j]; hn  += gh[2048 + j];
    }
    float r = 1.f / (1.f + expf(-(ir + hr)));
    float z = 1.f / (1.f + expf(-(iz + hz)));
    float n = tanhf(in_ + r * hn);
    hnewb[idx] = f2bf((1.f - z) * n + z * h[idx]);
}

// ---------------------------------------------------------------------------
extern "C" void kernel_launch(void* const* d_in, const int* in_sizes, int n_in,
                              void* d_out, int out_size, void* d_ws, size_t ws_size,
                              hipStream_t stream)
{
    const int*   input_ids    = (const int*)  d_in[0];
    const float* hidden       = (const float*)d_in[1];
    const float* enc_out      = (const float*)d_in[2];
    const int*   input_tensor = (const int*)  d_in[3];
    const int*   pairing_ids  = (const int*)  d_in[4];
    const float* emb_dec      = (const float*)d_in[5];
    const float* enc_emb      = (const float*)d_in[6];
    const float* Wq_i  = (const float*)d_in[7];
    const float* Wk_i  = (const float*)d_in[8];
    const float* wa_i  = (const float*)d_in[9];
    const float* Wq_p  = (const float*)d_in[10];
    const float* Wk_p  = (const float*)d_in[11];
    const float* wa_p  = (const float*)d_in[12];
    const float* ba_p  = (const float*)d_in[13];
    const float* W_lin = (const float*)d_in[14];
    const float* b_lin = (const float*)d_in[15];
    const float* W_ih  = (const float*)d_in[16];
    const float* W_hh  = (const float*)d_in[17];
    const float* b_ih  = (const float*)d_in[18];
    const float* b_hh  = (const float*)d_in[19];
    const float* W_out = (const float*)d_in[20];
    const float* b_out = (const float*)d_in[21];

    // ---- workspace layout (time-shared slots, lifetimes serial) ------------
    constexpr size_t OFF_HB    = 0;            // bf16 h, alive all
    constexpr size_t OFF_HNEW  = 524288;       // bf16 h_new, gru..G8
    constexpr size_t OFF_WQI   = 1048576;      // WqiT 2MB (..dual)
    constexpr size_t OFF_WQP   = 3145728;      // WqpT 2MB (..dual)
    constexpr size_t OFF_WKI   = 5242880;      // WkiT 4MB (..gemm24)
    constexpr size_t OFF_WKP   = 9437184;      // WkpT 4MB (..gemm24)
    constexpr size_t OFF_ENC   = 13631488;     // encb 21MB (..gemm24)
    constexpr size_t OFF_SLOT1 = 34603008;     // pq partials (dual..reduceq)
                                               // -> kp_all+key (gemm24..scores)
                                               // -> outp/pG5/xb
    constexpr size_t OFF_SLOT2 = 55574528;     // encembb (..gemm24) -> WlinT(..G5)
                                               //   -> Wihb/Whhb (..G67)
    constexpr size_t OFF_QUERY = 76546048;     // f32 1MB (..scores_i)
    constexpr size_t OFF_QP    = 77594624;     // f32 1MB (..scores_p)
    constexpr size_t OFF_SCI   = 78643200;     // 24KB
    constexpr size_t OFF_SCP   = 78667776;     // 20KB
    constexpr size_t OFF_PGI   = 1048576;      // G67 partials 8x3MB=24MB
                                               //   ([1M,34.6M) free after gemm24)
    constexpr size_t NEED      = 79167488;
    if (ws_size < NEED) {
        fprintf(stderr, "kernel_launch: ws_size %zu < needed %zu\n", ws_size, NEED);
        return;
    }
    char* ws = (char*)d_ws;
    unsigned short* hb     = (unsigned short*)(ws + OFF_HB);
    unsigned short* hnewb  = (unsigned short*)(ws + OFF_HNEW);
    unsigned short* WqiT   = (unsigned short*)(ws + OFF_WQI);
    unsigned short* WqpT   = (unsigned short*)(ws + OFF_WQP);
    unsigned short* WkiT   = (unsigned short*)(ws + OFF_WKI);
    unsigned short* WkpT   = (unsigned short*)(ws + OFF_WKP);
    unsigned short* encb   = (unsigned short*)(ws + OFF_ENC);
    float*          pqQ    = (float*)         (ws + OFF_SLOT1);          // 4MB
    float*          pqP    = (float*)         (ws + OFF_SLOT1 + 4194304);
    unsigned short* kp_all = (unsigned short*)(ws + OFF_SLOT1);          // after reduceq
    unsigned short* key    = (unsigned short*)(ws + OFF_SLOT1 + 10485760);
    unsigned short* encembb= (unsigned short*)(ws + OFF_SLOT2);
    unsigned short* WlinT  = (unsigned short*)(ws + OFF_SLOT2);          // after gemm24
    unsigned short* Wihb   = (unsigned short*)(ws + OFF_SLOT2);          // after gemm5
    unsigned short* Whhb   = (unsigned short*)(ws + OFF_SLOT2 + 12582912);
    unsigned short* outp   = (unsigned short*)(ws + OFF_SLOT1);          // after scores
    float*          pG5    = (float*)         (ws + OFF_SLOT1 + 1572864);   // 16.8MB
    unsigned short* xb     = (unsigned short*)(ws + OFF_SLOT1 + 18350080);  // 1MB
    float*          query  = (float*)         (ws + OFF_QUERY);
    float*          qp     = (float*)         (ws + OFF_QP);
    float*          sc_i   = (float*)         (ws + OFF_SCI);
    float*          sc_p   = (float*)         (ws + OFF_SCP);
    float*          pgi    = (float*)         (ws + OFF_PGI);

    // 1. prep1: all converts + Wq/Wk transposes (one launch)
    prep1_kernel<<<22032, 256, 0, stream>>>(hidden, enc_out, enc_emb,
                                            Wq_i, Wq_p, Wk_i, Wk_p,
                                            hb, encb, encembb,
                                            WqiT, WqpT, WkiT, WkpT);

    // 2-3. dual split-K4 (partials in SLOT1, dead before gemm24); reduce
    gemm_dual_kernel<<<dim3(8, 2, 8), 256, 0, stream>>>(hb, WqiT, WqpT, pqQ, pqP);
    reduceq_kernel<<<512, 256, 0, stream>>>(pqQ, pqP, query, qp);

    // 4. gemm24 XCD-swizzled: kp_all = enc_emb @ Wk_p ; key = enc @ Wk_i
    gemm24_kernel<<<640, 256, 0, stream>>>(encembb, encb, WkpT, WkiT, kp_all, key);

    // 5-6. ingredient scores; pairing scores (argmax + kp_all gather folded)
    attn_scores_kernel<<<5120, 256, 0, stream>>>(query, key, wa_i, sc_i);
    attn_scores_gather_kernel<<<5120, 256, 0, stream>>>(qp, kp_all, wa_p, ba_p,
                                                        sc_i, input_tensor, pairing_ids, sc_p);

    // 7. out_pair = [emb | softmax(s)*s @ enc_emb-gather]
    out_pair_kernel<<<1536, 256, 0, stream>>>(sc_p, enc_emb, sc_i, input_tensor,
                                              pairing_ids, emb_dec, input_ids, outp);

    // 8-10. G5: x = out_pair @ W_lin + b_lin  (split-K8 -> reduce -> bf16)
    transpose1_kernel<<<dim3(64, 24), 256, 0, stream>>>(W_lin, WlinT, 3072, 2048);
    gemm5_kernel<<<dim3(16, 2, 8), 256, 0, stream>>>(outp, WlinT, pG5);
    reduce5_kernel<<<512, 256, 0, stream>>>(pG5, b_lin, xb);

    // 11-12. G6+G7 merged, split-K4 each (partials in freed [1M,26.2M))
    conv2w_kernel<<<9216, 256, 0, stream>>>(W_ih, W_hh, Wihb, Whhb);
    gemm67_kernel<<<dim3(24, 2, 8), 256, 0, stream>>>(xb, hb, Wihb, Whhb, pgi);

    // 13. GRU pointwise (+ split-K8 reduce + biases) -> h_new bf16
    gru_kernel<<<1024, 256, 0, stream>>>(pgi, b_ih, b_hh, hidden, hnewb);

    // 14. G8 fused: logits = h_new @ W_out + b_out (256x64 tile, grid 500)
    gemm8_kernel<<<500, 256, 0, stream>>>(hnewb, W_out, b_out, (float*)d_out);
}

// Round 8
// 241.205 us; speedup vs baseline: 2.0835x; 1.0360x over previous
//
#include <hip/hip_runtime.h>
#include <cstdio>

// ---------------------------------------------------------------------------
// PairAttnDecoderRNN forward, MI355X/gfx950.  Round 8:
//  - gemm_core reverted to SINGLE-buffered 32KB LDS (m97 structure).
//    Round-7 post-mortem: explicit dbuf = 64KB LDS = 2 blocks/CU = the m132
//    regression (508 TF); overlap comes from >=3 co-resident blocks (m114),
//    not intra-block prefetch (barrier drains vmcnt(0) anyway, m99/m100).
//  - gemm24 XCD swizzle dropped (kernel is 10.7% HBM - not BW-bound; swizzle
//    measured -4us, the known L3-fit penalty).
//  - everything else unchanged from round 7 (A/B-clean isolation).
// ---------------------------------------------------------------------------

using f32x4   = __attribute__((ext_vector_type(4))) float;
using bf16x8  = __attribute__((ext_vector_type(8))) short;
using ushort8 = __attribute__((ext_vector_type(8))) unsigned short;

__device__ __forceinline__ unsigned short f2bf(float x) {
    unsigned u = __builtin_bit_cast(unsigned, x);
    u += 0x7fffu + ((u >> 16) & 1u);          // RNE
    return (unsigned short)(u >> 16);
}
__device__ __forceinline__ float bf2f(unsigned short u) {
    return __builtin_bit_cast(float, ((unsigned)u) << 16);
}

// async global->LDS, 16B per lane. LDS dest = wave-uniform base + lane*16.
__device__ __forceinline__ void gload16(const void* g, void* l) {
    auto gp = (const __attribute__((address_space(1))) void*)g;
    auto lp = (__attribute__((address_space(3))) void*)l;
    __builtin_amdgcn_global_load_lds(gp, lp, 16, 0, 0);
}

// ---------------- (R,C) fp32 -> (C,R) bf16 transpose body, 128r x 32c tile --
__device__ __forceinline__ void transpose_body(
    const float* __restrict__ in, unsigned short* __restrict__ out,
    int R, int C, int r0, int c0)
{
    __shared__ float t[32][129];
    const int tid = threadIdx.x;
    const int lr = tid >> 3;              // 0..31
    const int cc = (tid & 7) * 4;         // col chunk
    #pragma unroll
    for (int i = 0; i < 4; ++i) {
        int r = lr + 32 * i;
        float4 v = *(const float4*)(in + (size_t)(r0 + r) * C + c0 + cc);
        t[cc + 0][r] = v.x; t[cc + 1][r] = v.y;
        t[cc + 2][r] = v.z; t[cc + 3][r] = v.w;
    }
    __syncthreads();
    const int rc = (tid & 15) * 8;        // r chunk (8 outputs = 16B store)
    #pragma unroll
    for (int p = 0; p < 2; ++p) {
        int c = (tid >> 4) + 16 * p;
        const float* src = &t[c][rc];
        ushort8 o;
        #pragma unroll
        for (int j = 0; j < 8; ++j) o[j] = f2bf(src[j]);
        *(ushort8*)(out + (size_t)(c0 + c) * R + r0 + rc) = o;
    }
}

// ---------------- prep1: all input converts + Wq/Wk transposes --------------
// blocks [0,20496): f32->bf16 hidden|enc_out|enc_emb (float4 units)
// blocks [20496,21008): Wq_i/Wq_p transpose (1024x1024 each)
// blocks [21008,22032): Wk_i/Wk_p transpose (2048x1024 each)
__global__ __launch_bounds__(256) void prep1_kernel(
    const float* __restrict__ hidden, const float* __restrict__ enc_out,
    const float* __restrict__ enc_emb,
    const float* __restrict__ Wq_i, const float* __restrict__ Wq_p,
    const float* __restrict__ Wk_i, const float* __restrict__ Wk_p,
    unsigned short* __restrict__ hb, unsigned short* __restrict__ encb,
    unsigned short* __restrict__ encembb,
    unsigned short* __restrict__ WqiT, unsigned short* __restrict__ WqpT,
    unsigned short* __restrict__ WkiT, unsigned short* __restrict__ WkpT)
{
    const int bid = blockIdx.x;
    if (bid < 20496) {
        int i = bid * 256 + threadIdx.x;   // total 5,246,976 quads
        const float* src; unsigned short* dst; int j;
        if (i < 65536)        { src = hidden;  dst = hb;      j = i; }
        else if (i < 2686976) { src = enc_out; dst = encb;    j = i - 65536; }
        else                  { src = enc_emb; dst = encembb; j = i - 2686976; }
        float4 v = ((const float4*)src)[j];
        ((ushort4*)dst)[j] = make_ushort4(f2bf(v.x), f2bf(v.y), f2bf(v.z), f2bf(v.w));
    } else if (bid < 21008) {
        int local = bid - 20496;           // 512: z(2) x by(8) x bx(32)
        int bz = local >> 8, rem = local & 255;
        transpose_body(bz ? Wq_p : Wq_i, bz ? WqpT : WqiT,
                       1024, 1024, (rem >> 5) * 128, (rem & 31) * 32);
    } else {
        int local = bid - 21008;           // 1024: z(2) x by(16) x bx(32)
        int bz = local >> 9, rem = local & 511;
        transpose_body(bz ? Wk_p : Wk_i, bz ? WkpT : WkiT,
                       2048, 1024, (rem >> 5) * 128, (rem & 31) * 32);
    }
}

// ---------------- W_lin transpose (after gemm24 frees SLOT2) ----------------
__global__ __launch_bounds__(256) void transpose1_kernel(
    const float* in, unsigned short* out, int R, int C)
{ transpose_body(in, out, R, C, blockIdx.y * 128, blockIdx.x * 32); }

// ---------------- W_ih | W_hh fp32 -> bf16 (one launch) ---------------------
// W_ih: 1,572,864 float4s; W_hh: 786,432 -> 9216 blocks total.
__global__ __launch_bounds__(256) void conv2w_kernel(
    const float* __restrict__ Wih, const float* __restrict__ Whh,
    unsigned short* __restrict__ ob0, unsigned short* __restrict__ ob1)
{
    int i = blockIdx.x * 256 + threadIdx.x;
    const float* src; unsigned short* dst; int j;
    if (i < 1572864) { src = Wih; dst = ob0; j = i; }
    else             { src = Whh; dst = ob1; j = i - 1572864; }
    float4 v = ((const float4*)src)[j];
    ((ushort4*)dst)[j] = make_ushort4(f2bf(v.x), f2bf(v.y), f2bf(v.z), f2bf(v.w));
}

// ---------------- bf16 MFMA GEMM core: C(M,N) = A(M,K) * Bt(N,K)^T ----------
// 128x128 tile, BK=64, 4 waves 2x2, 16x16x32 MFMA, global_load_lds width=16.
// SINGLE-buffered 32KB LDS (m97 structure): {stage; bar; compute; bar}.
// Inter-block wave-level overlap (m114) supplies the pipeline - needs the
// 32KB footprint so >=3 blocks/CU co-reside.
template<int OUTBF, bool HAS_BIAS>
__device__ __forceinline__ void gemm_core(
    const unsigned short* __restrict__ A, const unsigned short* __restrict__ Bt,
    const float* __restrict__ bias, void* __restrict__ Cout, int Ncols,
    int sA, int sB, int kLen, int m0, int n0,
    unsigned short* lA, unsigned short* lB)
{
    const int tid = threadIdx.x;
    const int lane = tid & 63, wave = tid >> 6;
    const int wr = wave >> 1, wc = wave & 1;
    const int srow = tid >> 3, schunk = tid & 7;
    const int lm = lane & 15, lk = (lane >> 4) * 8;

    f32x4 acc[4][4];
    #pragma unroll
    for (int m = 0; m < 4; ++m)
        #pragma unroll
        for (int n = 0; n < 4; ++n) { f32x4 z = {0.f,0.f,0.f,0.f}; acc[m][n] = z; }

    const unsigned short* Ag = A  + (size_t)(m0 + srow) * sA + schunk * 8;
    const unsigned short* Bg = Bt + (size_t)(n0 + srow) * sB + schunk * 8;
    const int nt = kLen >> 6;

    char* lap = (char*)lA + tid * 16;
    char* lbp = (char*)lB + tid * 16;

    for (int t = 0; t < nt; ++t) {
        #pragma unroll
        for (int i = 0; i < 4; ++i) {
            gload16(Ag + (size_t)(32 * i) * sA + t * 64, lap + i * 4096);
            gload16(Bg + (size_t)(32 * i) * sB + t * 64, lbp + i * 4096);
        }
        __syncthreads();
        #pragma unroll
        for (int kk = 0; kk < 2; ++kk) {
            bf16x8 af[4], bv[4];
            #pragma unroll
            for (int m = 0; m < 4; ++m)
                af[m] = *(const bf16x8*)((const char*)lA +
                          (wr * 64 + m * 16 + lm) * 128 + (kk * 32 + lk) * 2);
            #pragma unroll
            for (int n = 0; n < 4; ++n)
                bv[n] = *(const bf16x8*)((const char*)lB +
                          (wc * 64 + n * 16 + lm) * 128 + (kk * 32 + lk) * 2);
            #pragma unroll
            for (int m = 0; m < 4; ++m)
                #pragma unroll
                for (int n = 0; n < 4; ++n)
                    acc[m][n] = __builtin_amdgcn_mfma_f32_16x16x32_bf16(
                        af[m], bv[n], acc[m][n], 0, 0, 0);
        }
        __syncthreads();
    }

    // epilogue: C/D layout col=lane&15, row=(lane>>4)*4+j  [m89/m91 verified]
    const int rbase = m0 + wr * 64 + (lane >> 4) * 4;
    const int cbase = n0 + wc * 64 + lm;
    #pragma unroll
    for (int m = 0; m < 4; ++m) {
        #pragma unroll
        for (int n = 0; n < 4; ++n) {
            int col = cbase + n * 16;
            float bvv = HAS_BIAS ? bias[col] : 0.0f;
            #pragma unroll
            for (int j = 0; j < 4; ++j) {
                int row = rbase + m * 16 + j;
                float v = acc[m][n][j] + bvv;
                if (OUTBF)
                    ((unsigned short*)Cout)[(size_t)row * Ncols + col] = f2bf(v);
                else
                    ((float*)Cout)[(size_t)row * Ncols + col] = v;
            }
        }
    }
}

#define GEMM_SHARED \
    __shared__ unsigned short lA[8192]; __shared__ unsigned short lB[8192];

// G1+G3 merged, split-K4: z = g*4+s; partials f32 -> P{g} + s*262144
__global__ __launch_bounds__(256) void gemm_dual_kernel(
    const unsigned short* A, const unsigned short* B0, const unsigned short* B1,
    float* P0, float* P1)
{
    GEMM_SHARED
    const int g = blockIdx.z >> 2, s = blockIdx.z & 3;
    const unsigned short* Bt = (g ? B1 : B0) + s * 256;
    float* C = (g ? P1 : P0) + (size_t)s * 262144;
    gemm_core<0,false>(A + s * 256, Bt, nullptr, C, 1024, 1024, 1024, 256,
                       blockIdx.y * 128, blockIdx.x * 128, lA, lB);
}

// dual split-K reduce: 131072 float4s total (query | qp)
__global__ __launch_bounds__(256) void reduceq_kernel(
    const float* __restrict__ pqQ, const float* __restrict__ pqP,
    float* __restrict__ query, float* __restrict__ qp)
{
    int i = blockIdx.x * 256 + threadIdx.x;
    const float4* p; float4* o; int j;
    if (i < 65536) { p = (const float4*)pqQ; o = (float4*)query; j = i; }
    else           { p = (const float4*)pqP; o = (float4*)qp;    j = i - 65536; }
    float4 a = p[j], b = p[j + 65536], c = p[j + 131072], d = p[j + 196608];
    o[j] = make_float4(a.x + b.x + c.x + d.x, a.y + b.y + c.y + d.y,
                       a.z + b.z + c.z + d.z, a.w + b.w + c.w + d.w);
}

// G4'+G2 merged (z=0: kp_all = enc_emb @ Wk_p; z=1: key = enc @ Wk_i) -> bf16
__global__ __launch_bounds__(256) void gemm24_kernel(
    const unsigned short* encembb, const unsigned short* encb,
    const unsigned short* WkpT, const unsigned short* WkiT,
    unsigned short* kp_all, unsigned short* key)
{
    GEMM_SHARED
    const int z = blockIdx.z;
    const unsigned short* A  = z ? encb : encembb;
    const unsigned short* Bt = z ? WkiT : WkpT;
    unsigned short* C = z ? key : kp_all;
    gemm_core<1,false>(A, Bt, nullptr, C, 1024, 2048, 2048, 2048,
                       blockIdx.y * 128, blockIdx.x * 128, lA, lB);
}

// G5 split-K8: z=0..7, kLen 384; partials f32
__global__ __launch_bounds__(256) void gemm5_kernel(
    const unsigned short* A, const unsigned short* Bt, float* P)
{
    GEMM_SHARED
    const int z = blockIdx.z;
    gemm_core<0,false>(A + z * 384, Bt + z * 384, nullptr,
                       P + (size_t)z * 524288, 2048, 3072, 3072, 384,
                       blockIdx.y * 128, blockIdx.x * 128, lA, lB);
}

// G6+G7 merged, split-K4 each: z = g*4+s; partials -> pg + z*786432
__global__ __launch_bounds__(256) void gemm67_kernel(
    const unsigned short* xb, const unsigned short* hb,
    const unsigned short* Wih, const unsigned short* Whh, float* pg)
{
    GEMM_SHARED
    const int g = blockIdx.z >> 2, s = blockIdx.z & 3;
    const unsigned short* A  = g ? hb  + s * 256 : xb  + s * 512;
    const unsigned short* Bt = g ? Whh + s * 256 : Wih + s * 512;
    const int sAB  = g ? 1024 : 2048;
    const int kLen = g ? 256  : 512;
    float* C = pg + (size_t)blockIdx.z * 786432;
    gemm_core<0,false>(A, Bt, nullptr, C, 3072, sAB, sAB, kLen,
                       blockIdx.y * 128, blockIdx.x * 128, lA, lB);
}

// ---------------- G8 fused: logits = hnewb @ W_out(f32,(K,N)) + b_out -------
// 256x64 tile, 4 waves stacked on M, grid 500 (LDS 80KB).
// A: bf16 gload_lds, linear [256][64]. B: reg-staged f32->bf16, XOR-swizzled
// LDS (write AND read). W_out read exactly once; A is L2-resident.
__global__ __launch_bounds__(256) void gemm8_kernel(
    const unsigned short* __restrict__ A, const float* __restrict__ Wout,
    const float* __restrict__ bias, float* __restrict__ C)
{
    __shared__ unsigned short lA0[16384]; __shared__ unsigned short lA1[16384];
    __shared__ unsigned short lB0[4096];  __shared__ unsigned short lB1[4096];
    const int tid  = threadIdx.x;
    const int lane = tid & 63, wave = tid >> 6;
    const int n0 = blockIdx.x * 64;
    const int lm = lane & 15, lk = (lane >> 4) * 8;
    const int srow = tid >> 3, schunk = tid & 7;      // A staging
    const int bcol = tid & 63, bkg = tid >> 6;        // B staging (col, k-grp)
    const int bsw  = (bcol & 7) << 4;                 // B LDS XOR swizzle

    f32x4 acc[4][4];
    #pragma unroll
    for (int m = 0; m < 4; ++m)
        #pragma unroll
        for (int n = 0; n < 4; ++n) { f32x4 z = {0.f,0.f,0.f,0.f}; acc[m][n] = z; }

    const unsigned short* Ag = A + (size_t)srow * 1024 + schunk * 8;

    auto stageA = [&](unsigned short* la_, int t) {
        char* la = (char*)la_ + tid * 16;
        #pragma unroll
        for (int i = 0; i < 8; ++i)
            gload16(Ag + (size_t)(32 * i) * 1024 + t * 64, la + i * 4096);
    };
    float bv_[16];
    auto loadB = [&](int t) {
        const float* src = Wout + (size_t)(t * 64 + bkg * 16) * 32000 + n0 + bcol;
        #pragma unroll
        for (int j = 0; j < 16; ++j) bv_[j] = src[(size_t)j * 32000];
    };
    auto writeB = [&](unsigned short* lb_) {
        ushort8 o0, o1;
        #pragma unroll
        for (int j = 0; j < 8; ++j) { o0[j] = f2bf(bv_[j]); o1[j] = f2bf(bv_[j + 8]); }
        char* base = (char*)lb_ + bcol * 128;
        *(ushort8*)(base + ((bkg * 32)      ^ bsw)) = o0;
        *(ushort8*)(base + ((bkg * 32 + 16) ^ bsw)) = o1;
    };
    auto compute = [&](const unsigned short* la_, const unsigned short* lb_) {
        #pragma unroll
        for (int kk = 0; kk < 2; ++kk) {
            bf16x8 af[4], bv[4];
            #pragma unroll
            for (int m = 0; m < 4; ++m)
                af[m] = *(const bf16x8*)((const char*)la_ +
                          (wave * 64 + m * 16 + lm) * 128 + (kk * 32 + lk) * 2);
            #pragma unroll
            for (int n = 0; n < 4; ++n) {
                int rr = n * 16 + lm;
                bv[n] = *(const bf16x8*)((const char*)lb_ +
                          rr * 128 + (((kk * 32 + lk) * 2) ^ ((rr & 7) << 4)));
            }
            #pragma unroll
            for (int m = 0; m < 4; ++m)
                #pragma unroll
                for (int n = 0; n < 4; ++n)
                    acc[m][n] = __builtin_amdgcn_mfma_f32_16x16x32_bf16(
                        af[m], bv[n], acc[m][n], 0, 0, 0);
        }
    };

    stageA(lA0, 0); loadB(0); writeB(lB0);
    __syncthreads();
    const int nt = 16;                                 // K=1024 / 64
    for (int t = 0; t < nt; t += 2) {
        if (t + 1 < nt) { stageA(lA1, t + 1); loadB(t + 1); }
        compute(lA0, lB0);
        if (t + 1 < nt) writeB(lB1);
        __syncthreads();
        if (t + 1 < nt) {
            if (t + 2 < nt) { stageA(lA0, t + 2); loadB(t + 2); }
            compute(lA1, lB1);
            if (t + 2 < nt) writeB(lB0);
            __syncthreads();
        }
    }

    const int rbase = wave * 64 + (lane >> 4) * 4;
    const int cbase = n0 + lm;
    #pragma unroll
    for (int m = 0; m < 4; ++m) {
        #pragma unroll
        for (int n = 0; n < 4; ++n) {
            int col = cbase + n * 16;
            float bvv = bias[col];
            #pragma unroll
            for (int j = 0; j < 4; ++j)
                C[(size_t)(rbase + m * 16 + j) * 32000 + col] = acc[m][n][j] + bvv;
        }
    }
}

// ---------------- additive-attention scores (k bf16, full row) --------------
__global__ __launch_bounds__(256) void attn_scores_kernel(
    const float* __restrict__ q, const unsigned short* __restrict__ k,
    const float* __restrict__ wa, float* __restrict__ scores)
{
    const int bm = blockIdx.x;          // b*20 + m
    const int b  = bm / 20;
    const int tid = threadIdx.x;
    float4 qv  = ((const float4*)(q + (size_t)b * 1024))[tid];
    ushort4 kv = ((const ushort4*)(k + (size_t)bm * 1024))[tid];
    float4 wv  = ((const float4*)wa)[tid];
    float p = tanhf(qv.x + bf2f(kv.x)) * wv.x + tanhf(qv.y + bf2f(kv.y)) * wv.y
            + tanhf(qv.z + bf2f(kv.z)) * wv.z + tanhf(qv.w + bf2f(kv.w)) * wv.w;
    #pragma unroll
    for (int off = 32; off > 0; off >>= 1) p += __shfl_down(p, off);
    __shared__ float sp[4];
    if ((tid & 63) == 0) sp[tid >> 6] = p;
    __syncthreads();
    if (tid == 0) scores[bm] = sp[0] + sp[1] + sp[2] + sp[3];
}

// argmax over ingredient scores (first-max tiebreak = jnp) -> ingredient id
__device__ __forceinline__ int argmax_ing(
    const float* __restrict__ sc_i, const int* __restrict__ input_tensor, int b)
{
    float best = sc_i[b * 20]; int bi = 0;
    #pragma unroll
    for (int m = 1; m < 20; ++m) {
        float v = sc_i[b * 20 + m];
        if (v > best) { best = v; bi = m; }
    }
    return input_tensor[b * 20 + bi];
}

// ---------------- pairing scores: gather kp_all rows by comp_id -------------
__global__ __launch_bounds__(256) void attn_scores_gather_kernel(
    const float* __restrict__ q, const unsigned short* __restrict__ kp_all,
    const float* __restrict__ wa, const float* __restrict__ ba,
    const float* __restrict__ sc_i, const int* __restrict__ input_tensor,
    const int* __restrict__ pairing_ids, float* __restrict__ scores)
{
    const int bm = blockIdx.x;          // b*20 + k
    const int b  = bm / 20;
    const int kk = bm - b * 20;
    const int tid = threadIdx.x;
    const int ing = argmax_ing(sc_i, input_tensor, b);
    const int cid = pairing_ids[ing * 20 + kk];
    float4 qv  = ((const float4*)(q + (size_t)b * 1024))[tid];
    ushort4 kv = ((const ushort4*)(kp_all + (size_t)cid * 1024))[tid];
    float4 wv  = ((const float4*)wa)[tid];
    float p = tanhf(qv.x + bf2f(kv.x)) * wv.x + tanhf(qv.y + bf2f(kv.y)) * wv.y
            + tanhf(qv.z + bf2f(kv.z)) * wv.z + tanhf(qv.w + bf2f(kv.w)) * wv.w;
    #pragma unroll
    for (int off = 32; off > 0; off >>= 1) p += __shfl_down(p, off);
    __shared__ float sp[4];
    if ((tid & 63) == 0) sp[tid >> 6] = p;
    __syncthreads();
    if (tid == 0) scores[bm] = sp[0] + sp[1] + sp[2] + sp[3] + ba[0];
}

// ---------------- out_pair assembly (softmax*s + enc_emb gather folded) -----
__global__ __launch_bounds__(256) void out_pair_kernel(
    const float* __restrict__ s_p, const float* __restrict__ enc_emb,
    const float* __restrict__ sc_i, const int* __restrict__ input_tensor,
    const int* __restrict__ pairing_ids,
    const float* __restrict__ emb_dec, const int* __restrict__ input_ids,
    unsigned short* __restrict__ out_pairb)
{
    const int b = blockIdx.x / 6, seg = blockIdx.x % 6;
    const int tid = threadIdx.x;
    const int d = seg * 512 + tid * 2;
    ushort2 o;
    if (seg < 2) {                       // emb part, d < 1024
        float2 v = *(const float2*)(emb_dec + (size_t)input_ids[b] * 1024 + d);
        o.x = f2bf(v.x); o.y = f2bf(v.y);
    } else {                             // attn_app part: gather enc_emb f32
        const int ing = argmax_ing(sc_i, input_tensor, b);
        __shared__ float s_raw[20];
        if (tid < 20) s_raw[tid] = s_p[b * 20 + tid];
        __syncthreads();
        float mx = -1e30f;
        #pragma unroll
        for (int m = 0; m < 20; ++m) mx = fmaxf(mx, s_raw[m]);
        float den = 0.f; float w[20];
        #pragma unroll
        for (int m = 0; m < 20; ++m) { w[m] = expf(s_raw[m] - mx); den += w[m]; }
        const float inv = 1.f / den;
        const int dd = d - 1024;
        float a0 = 0.f, a1 = 0.f;
        #pragma unroll
        for (int k = 0; k < 20; ++k) {
            const int cid = pairing_ids[ing * 20 + k];
            float2 v = *(const float2*)(enc_emb + (size_t)cid * 2048 + dd);
            float a = w[k] * inv * s_raw[k];           // softmax * raw score
            a0 += a * v.x; a1 += a * v.y;
        }
        o.x = f2bf(a0); o.y = f2bf(a1);
    }
    *(ushort2*)(out_pairb + (size_t)b * 3072 + d) = o;
}

// ---------------- G5 split-K8 reduce + bias -> bf16 x -----------------------
__global__ __launch_bounds__(256) void reduce5_kernel(
    const float* __restrict__ P, const float* __restrict__ bias,
    unsigned short* __restrict__ xb)
{
    int i = blockIdx.x * 256 + threadIdx.x;        // 131072 float4s
    const float4* p = (const float4*)P;
    float4 bb = ((const float4*)bias)[i & 511];
    float s0 = bb.x, s1 = bb.y, s2 = bb.z, s3 = bb.w;
    #pragma unroll
    for (int s = 0; s < 8; ++s) {
        float4 v = p[i + s * 131072];
        s0 += v.x; s1 += v.y; s2 += v.z; s3 += v.w;
    }
    ((ushort4*)xb)[i] = make_ushort4(f2bf(s0), f2bf(s1), f2bf(s2), f2bf(s3));
}

// ---------------- GRU pointwise + split-K8 reduce (gate order r,z,n) --------
__global__ __launch_bounds__(256) void gru_kernel(
    const float* __restrict__ pg, const float* __restrict__ b_ih,
    const float* __restrict__ b_hh, const float* __restrict__ h,
    unsigned short* __restrict__ hnewb)
{
    int idx = blockIdx.x * 256 + threadIdx.x;       // 262144
    int b = idx >> 10, j = idx & 1023;
    float ir = b_ih[j], iz = b_ih[1024 + j], in_ = b_ih[2048 + j];
    float hr = b_hh[j], hz = b_hh[1024 + j], hn  = b_hh[2048 + j];
    #pragma unroll
    for (int s = 0; s < 4; ++s) {
        const float* gi = pg + (size_t)s * 786432 + (size_t)b * 3072;
        ir  += gi[j]; iz += gi[1024 + j]; in_ += gi[2048 + j];
        const float* gh = pg + (size_t)(4 + s) * 786432 + (size_t)b * 3072;
        hr  += gh[j]; hz += gh[1024 + j]; hn  += gh[2048 + j];
    }
    float r = 1.f / (1.f + expf(-(ir + hr)));
    float z = 1.f / (1.f + expf(-(iz + hz)));
    float n = tanhf(in_ + r * hn);
    hnewb[idx] = f2bf((1.f - z) * n + z * h[idx]);
}

// ---------------------------------------------------------------------------
extern "C" void kernel_launch(void* const* d_in, const int* in_sizes, int n_in,
                              void* d_out, int out_size, void* d_ws, size_t ws_size,
                              hipStream_t stream)
{
    const int*   input_ids    = (const int*)  d_in[0];
    const float* hidden       = (const float*)d_in[1];
    const float* enc_out      = (const float*)d_in[2];
    const int*   input_tensor = (const int*)  d_in[3];
    const int*   pairing_ids  = (const int*)  d_in[4];
    const float* emb_dec      = (const float*)d_in[5];
    const float* enc_emb      = (const float*)d_in[6];
    const float* Wq_i  = (const float*)d_in[7];
    const float* Wk_i  = (const float*)d_in[8];
    const float* wa_i  = (const float*)d_in[9];
    const float* Wq_p  = (const float*)d_in[10];
    const float* Wk_p  = (const float*)d_in[11];
    const float* wa_p  = (const float*)d_in[12];
    const float* ba_p  = (const float*)d_in[13];
    const float* W_lin = (const float*)d_in[14];
    const float* b_lin = (const float*)d_in[15];
    const float* W_ih  = (const float*)d_in[16];
    const float* W_hh  = (const float*)d_in[17];
    const float* b_ih  = (const float*)d_in[18];
    const float* b_hh  = (const float*)d_in[19];
    const float* W_out = (const float*)d_in[20];
    const float* b_out = (const float*)d_in[21];

    // ---- workspace layout (time-shared slots, lifetimes serial) ------------
    constexpr size_t OFF_HB    = 0;            // bf16 h, alive all
    constexpr size_t OFF_HNEW  = 524288;       // bf16 h_new, gru..G8
    constexpr size_t OFF_WQI   = 1048576;      // WqiT 2MB (..dual)
    constexpr size_t OFF_WQP   = 3145728;      // WqpT 2MB (..dual)
    constexpr size_t OFF_WKI   = 5242880;      // WkiT 4MB (..gemm24)
    constexpr size_t OFF_WKP   = 9437184;      // WkpT 4MB (..gemm24)
    constexpr size_t OFF_ENC   = 13631488;     // encb 21MB (..gemm24)
    constexpr size_t OFF_SLOT1 = 34603008;     // pq partials (dual..reduceq)
                                               // -> kp_all+key (gemm24..scores)
                                               // -> outp/pG5/xb
    constexpr size_t OFF_SLOT2 = 55574528;     // encembb (..gemm24) -> WlinT(..G5)
                                               //   -> Wihb/Whhb (..G67)
    constexpr size_t OFF_QUERY = 76546048;     // f32 1MB (..scores_i)
    constexpr size_t OFF_QP    = 77594624;     // f32 1MB (..scores_p)
    constexpr size_t OFF_SCI   = 78643200;     // 24KB
    constexpr size_t OFF_SCP   = 78667776;     // 20KB
    constexpr size_t OFF_PGI   = 1048576;      // G67 partials 8x3MB=24MB
                                               //   ([1M,34.6M) free after gemm24)
    constexpr size_t NEED      = 79167488;
    if (ws_size < NEED) {
        fprintf(stderr, "kernel_launch: ws_size %zu < needed %zu\n", ws_size, NEED);
        return;
    }
    char* ws = (char*)d_ws;
    unsigned short* hb     = (unsigned short*)(ws + OFF_HB);
    unsigned short* hnewb  = (unsigned short*)(ws + OFF_HNEW);
    unsigned short* WqiT   = (unsigned short*)(ws + OFF_WQI);
    unsigned short* WqpT   = (unsigned short*)(ws + OFF_WQP);
    unsigned short* WkiT   = (unsigned short*)(ws + OFF_WKI);
    unsigned short* WkpT   = (unsigned short*)(ws + OFF_WKP);
    unsigned short* encb   = (unsigned short*)(ws + OFF_ENC);
    float*          pqQ    = (float*)         (ws + OFF_SLOT1);          // 4MB
    float*          pqP    = (float*)         (ws + OFF_SLOT1 + 4194304);
    unsigned short* kp_all = (unsigned short*)(ws + OFF_SLOT1);          // after reduceq
    unsigned short* key    = (unsigned short*)(ws + OFF_SLOT1 + 10485760);
    unsigned short* encembb= (unsigned short*)(ws + OFF_SLOT2);
    unsigned short* WlinT  = (unsigned short*)(ws + OFF_SLOT2);          // after gemm24
    unsigned short* Wihb   = (unsigned short*)(ws + OFF_SLOT2);          // after gemm5
    unsigned short* Whhb   = (unsigned short*)(ws + OFF_SLOT2 + 12582912);
    unsigned short* outp   = (unsigned short*)(ws + OFF_SLOT1);          // after scores
    float*          pG5    = (float*)         (ws + OFF_SLOT1 + 1572864);   // 16.8MB
    unsigned short* xb     = (unsigned short*)(ws + OFF_SLOT1 + 18350080);  // 1MB
    float*          query  = (float*)         (ws + OFF_QUERY);
    float*          qp     = (float*)         (ws + OFF_QP);
    float*          sc_i   = (float*)         (ws + OFF_SCI);
    float*          sc_p   = (float*)         (ws + OFF_SCP);
    float*          pgi    = (float*)         (ws + OFF_PGI);

    // 1. prep1: all converts + Wq/Wk transposes (one launch)
    prep1_kernel<<<22032, 256, 0, stream>>>(hidden, enc_out, enc_emb,
                                            Wq_i, Wq_p, Wk_i, Wk_p,
                                            hb, encb, encembb,
                                            WqiT, WqpT, WkiT, WkpT);

    // 2-3. dual split-K4 (partials in SLOT1, dead before gemm24); reduce
    gemm_dual_kernel<<<dim3(8, 2, 8), 256, 0, stream>>>(hb, WqiT, WqpT, pqQ, pqP);
    reduceq_kernel<<<512, 256, 0, stream>>>(pqQ, pqP, query, qp);

    // 4. gemm24: kp_all = enc_emb @ Wk_p ; key = enc @ Wk_i (bf16)
    gemm24_kernel<<<dim3(8, 40, 2), 256, 0, stream>>>(encembb, encb, WkpT, WkiT,
                                                      kp_all, key);

    // 5-6. ingredient scores; pairing scores (argmax + kp_all gather folded)
    attn_scores_kernel<<<5120, 256, 0, stream>>>(query, key, wa_i, sc_i);
    attn_scores_gather_kernel<<<5120, 256, 0, stream>>>(qp, kp_all, wa_p, ba_p,
                                                        sc_i, input_tensor, pairing_ids, sc_p);

    // 7. out_pair = [emb | softmax(s)*s @ enc_emb-gather]
    out_pair_kernel<<<1536, 256, 0, stream>>>(sc_p, enc_emb, sc_i, input_tensor,
                                              pairing_ids, emb_dec, input_ids, outp);

    // 8-10. G5: x = out_pair @ W_lin + b_lin  (split-K8 -> reduce -> bf16)
    transpose1_kernel<<<dim3(64, 24), 256, 0, stream>>>(W_lin, WlinT, 3072, 2048);
    gemm5_kernel<<<dim3(16, 2, 8), 256, 0, stream>>>(outp, WlinT, pG5);
    reduce5_kernel<<<512, 256, 0, stream>>>(pG5, b_lin, xb);

    // 11-12. G6+G7 merged, split-K4 each (partials in freed [1M,26.2M))
    conv2w_kernel<<<9216, 256, 0, stream>>>(W_ih, W_hh, Wihb, Whhb);
    gemm67_kernel<<<dim3(24, 2, 8), 256, 0, stream>>>(xb, hb, Wihb, Whhb, pgi);

    // 13. GRU pointwise (+ split-K8 reduce + biases) -> h_new bf16
    gru_kernel<<<1024, 256, 0, stream>>>(pgi, b_ih, b_hh, hidden, hnewb);

    // 14. G8 fused: logits = h_new @ W_out + b_out (256x64 tile, grid 500)
    gemm8_kernel<<<500, 256, 0, stream>>>(hnewb, W_out, b_out, (float*)d_out);
}

// Round 9
// 230.637 us; speedup vs baseline: 2.1789x; 1.0458x over previous
//
#include <hip/hip_runtime.h>
#include <cstdio>

// ---------------------------------------------------------------------------
// PairAttnDecoderRNN forward, MI355X/gfx950.  Round 9:
//  - gemm24 split-K2 on BOTH GEMMs: grid (8,40,4)=1280 = exactly 5 blk/CU
//    (32KB LDS cap), zero dispatch tail. bf16 partials summed in consumers
//    (round-5-proven numerics). key partials live in d_out (dead until gemm8
//    fully overwrites it); kp partials exactly fill SLOT1.
//  - gemm5f: W_lin^T transpose folded into the GEMM (B reg-staged from f32,
//    strided loads + XOR-swizzled LDS, gemm8-proven pattern).
//  - gemm67f: W_ih/W_hh converts folded in (row-major f32 B reg-stage).
//  12 launches total.
// ---------------------------------------------------------------------------

using f32x4   = __attribute__((ext_vector_type(4))) float;
using bf16x8  = __attribute__((ext_vector_type(8))) short;
using ushort8 = __attribute__((ext_vector_type(8))) unsigned short;

__device__ __forceinline__ unsigned short f2bf(float x) {
    unsigned u = __builtin_bit_cast(unsigned, x);
    u += 0x7fffu + ((u >> 16) & 1u);          // RNE
    return (unsigned short)(u >> 16);
}
__device__ __forceinline__ float bf2f(unsigned short u) {
    return __builtin_bit_cast(float, ((unsigned)u) << 16);
}

// async global->LDS, 16B per lane. LDS dest = wave-uniform base + lane*16.
__device__ __forceinline__ void gload16(const void* g, void* l) {
    auto gp = (const __attribute__((address_space(1))) void*)g;
    auto lp = (__attribute__((address_space(3))) void*)l;
    __builtin_amdgcn_global_load_lds(gp, lp, 16, 0, 0);
}

// ---------------- (R,C) fp32 -> (C,R) bf16 transpose body, 128r x 32c tile --
__device__ __forceinline__ void transpose_body(
    const float* __restrict__ in, unsigned short* __restrict__ out,
    int R, int C, int r0, int c0)
{
    __shared__ float t[32][129];
    const int tid = threadIdx.x;
    const int lr = tid >> 3;              // 0..31
    const int cc = (tid & 7) * 4;         // col chunk
    #pragma unroll
    for (int i = 0; i < 4; ++i) {
        int r = lr + 32 * i;
        float4 v = *(const float4*)(in + (size_t)(r0 + r) * C + c0 + cc);
        t[cc + 0][r] = v.x; t[cc + 1][r] = v.y;
        t[cc + 2][r] = v.z; t[cc + 3][r] = v.w;
    }
    __syncthreads();
    const int rc = (tid & 15) * 8;        // r chunk (8 outputs = 16B store)
    #pragma unroll
    for (int p = 0; p < 2; ++p) {
        int c = (tid >> 4) + 16 * p;
        const float* src = &t[c][rc];
        ushort8 o;
        #pragma unroll
        for (int j = 0; j < 8; ++j) o[j] = f2bf(src[j]);
        *(ushort8*)(out + (size_t)(c0 + c) * R + r0 + rc) = o;
    }
}

// ---------------- prep1: all input converts + Wq/Wk transposes --------------
// blocks [0,20496): f32->bf16 hidden|enc_out|enc_emb (float4 units)
// blocks [20496,21008): Wq_i/Wq_p transpose (1024x1024 each)
// blocks [21008,22032): Wk_i/Wk_p transpose (2048x1024 each)
__global__ __launch_bounds__(256) void prep1_kernel(
    const float* __restrict__ hidden, const float* __restrict__ enc_out,
    const float* __restrict__ enc_emb,
    const float* __restrict__ Wq_i, const float* __restrict__ Wq_p,
    const float* __restrict__ Wk_i, const float* __restrict__ Wk_p,
    unsigned short* __restrict__ hb, unsigned short* __restrict__ encb,
    unsigned short* __restrict__ encembb,
    unsigned short* __restrict__ WqiT, unsigned short* __restrict__ WqpT,
    unsigned short* __restrict__ WkiT, unsigned short* __restrict__ WkpT)
{
    const int bid = blockIdx.x;
    if (bid < 20496) {
        int i = bid * 256 + threadIdx.x;   // total 5,246,976 quads
        const float* src; unsigned short* dst; int j;
        if (i < 65536)        { src = hidden;  dst = hb;      j = i; }
        else if (i < 2686976) { src = enc_out; dst = encb;    j = i - 65536; }
        else                  { src = enc_emb; dst = encembb; j = i - 2686976; }
        float4 v = ((const float4*)src)[j];
        ((ushort4*)dst)[j] = make_ushort4(f2bf(v.x), f2bf(v.y), f2bf(v.z), f2bf(v.w));
    } else if (bid < 21008) {
        int local = bid - 20496;           // 512: z(2) x by(8) x bx(32)
        int bz = local >> 8, rem = local & 255;
        transpose_body(bz ? Wq_p : Wq_i, bz ? WqpT : WqiT,
                       1024, 1024, (rem >> 5) * 128, (rem & 31) * 32);
    } else {
        int local = bid - 21008;           // 1024: z(2) x by(16) x bx(32)
        int bz = local >> 9, rem = local & 511;
        transpose_body(bz ? Wk_p : Wk_i, bz ? WkpT : WkiT,
                       2048, 1024, (rem >> 5) * 128, (rem & 31) * 32);
    }
}

// ---------------- bf16 MFMA GEMM core: C(M,N) = A(M,K) * Bt(N,K)^T ----------
// 128x128 tile, BK=64, 4 waves 2x2, 16x16x32 MFMA, global_load_lds width=16.
// SINGLE-buffered 32KB LDS (m97 structure): {stage; bar; compute; bar}.
template<int OUTBF, bool HAS_BIAS>
__device__ __forceinline__ void gemm_core(
    const unsigned short* __restrict__ A, const unsigned short* __restrict__ Bt,
    const float* __restrict__ bias, void* __restrict__ Cout, int Ncols,
    int sA, int sB, int kLen, int m0, int n0,
    unsigned short* lA, unsigned short* lB)
{
    const int tid = threadIdx.x;
    const int lane = tid & 63, wave = tid >> 6;
    const int wr = wave >> 1, wc = wave & 1;
    const int srow = tid >> 3, schunk = tid & 7;
    const int lm = lane & 15, lk = (lane >> 4) * 8;

    f32x4 acc[4][4];
    #pragma unroll
    for (int m = 0; m < 4; ++m)
        #pragma unroll
        for (int n = 0; n < 4; ++n) { f32x4 z = {0.f,0.f,0.f,0.f}; acc[m][n] = z; }

    const unsigned short* Ag = A  + (size_t)(m0 + srow) * sA + schunk * 8;
    const unsigned short* Bg = Bt + (size_t)(n0 + srow) * sB + schunk * 8;
    const int nt = kLen >> 6;

    char* lap = (char*)lA + tid * 16;
    char* lbp = (char*)lB + tid * 16;

    for (int t = 0; t < nt; ++t) {
        #pragma unroll
        for (int i = 0; i < 4; ++i) {
            gload16(Ag + (size_t)(32 * i) * sA + t * 64, lap + i * 4096);
            gload16(Bg + (size_t)(32 * i) * sB + t * 64, lbp + i * 4096);
        }
        __syncthreads();
        #pragma unroll
        for (int kk = 0; kk < 2; ++kk) {
            bf16x8 af[4], bv[4];
            #pragma unroll
            for (int m = 0; m < 4; ++m)
                af[m] = *(const bf16x8*)((const char*)lA +
                          (wr * 64 + m * 16 + lm) * 128 + (kk * 32 + lk) * 2);
            #pragma unroll
            for (int n = 0; n < 4; ++n)
                bv[n] = *(const bf16x8*)((const char*)lB +
                          (wc * 64 + n * 16 + lm) * 128 + (kk * 32 + lk) * 2);
            #pragma unroll
            for (int m = 0; m < 4; ++m)
                #pragma unroll
                for (int n = 0; n < 4; ++n)
                    acc[m][n] = __builtin_amdgcn_mfma_f32_16x16x32_bf16(
                        af[m], bv[n], acc[m][n], 0, 0, 0);
        }
        __syncthreads();
    }

    // epilogue: C/D layout col=lane&15, row=(lane>>4)*4+j  [m89/m91 verified]
    const int rbase = m0 + wr * 64 + (lane >> 4) * 4;
    const int cbase = n0 + wc * 64 + lm;
    #pragma unroll
    for (int m = 0; m < 4; ++m) {
        #pragma unroll
        for (int n = 0; n < 4; ++n) {
            int col = cbase + n * 16;
            float bvv = HAS_BIAS ? bias[col] : 0.0f;
            #pragma unroll
            for (int j = 0; j < 4; ++j) {
                int row = rbase + m * 16 + j;
                float v = acc[m][n][j] + bvv;
                if (OUTBF)
                    ((unsigned short*)Cout)[(size_t)row * Ncols + col] = f2bf(v);
                else
                    ((float*)Cout)[(size_t)row * Ncols + col] = v;
            }
        }
    }
}

#define GEMM_SHARED \
    __shared__ unsigned short lA[8192]; __shared__ unsigned short lB[8192];

// G1+G3 merged, split-K4: z = g*4+s; partials f32 -> P{g} + s*262144
__global__ __launch_bounds__(256) void gemm_dual_kernel(
    const unsigned short* A, const unsigned short* B0, const unsigned short* B1,
    float* P0, float* P1)
{
    GEMM_SHARED
    const int g = blockIdx.z >> 2, s = blockIdx.z & 3;
    const unsigned short* Bt = (g ? B1 : B0) + s * 256;
    float* C = (g ? P1 : P0) + (size_t)s * 262144;
    gemm_core<0,false>(A + s * 256, Bt, nullptr, C, 1024, 1024, 1024, 256,
                       blockIdx.y * 128, blockIdx.x * 128, lA, lB);
}

// dual split-K reduce: 131072 float4s total (query | qp)
__global__ __launch_bounds__(256) void reduceq_kernel(
    const float* __restrict__ pqQ, const float* __restrict__ pqP,
    float* __restrict__ query, float* __restrict__ qp)
{
    int i = blockIdx.x * 256 + threadIdx.x;
    const float4* p; float4* o; int j;
    if (i < 65536) { p = (const float4*)pqQ; o = (float4*)query; j = i; }
    else           { p = (const float4*)pqP; o = (float4*)qp;    j = i - 65536; }
    float4 a = p[j], b = p[j + 65536], c = p[j + 131072], d = p[j + 196608];
    o[j] = make_float4(a.x + b.x + c.x + d.x, a.y + b.y + c.y + d.y,
                       a.z + b.z + c.z + d.z, a.w + b.w + c.w + d.w);
}

// G4'+G2 merged, split-K2 each: z = g*2+h (g: 0=kp_all, 1=key; h: K half).
// grid (8,40,4) = 1280 blocks = exactly 5 blocks/CU (32KB LDS cap), no tail.
// bf16 partials: kp -> SLOT1 (2 x 10.5MB), key -> d_out scratch (2 x 10.5MB).
__global__ __launch_bounds__(256) void gemm24_kernel(
    const unsigned short* encembb, const unsigned short* encb,
    const unsigned short* WkpT, const unsigned short* WkiT,
    unsigned short* kpP, unsigned short* keyP, size_t pStride)
{
    GEMM_SHARED
    const int g = blockIdx.z >> 1, h = blockIdx.z & 1;
    const unsigned short* A  = (g ? encb : encembb) + h * 1024;
    const unsigned short* Bt = (g ? WkiT : WkpT)    + h * 1024;
    unsigned short* C = (g ? keyP : kpP) + (size_t)h * pStride;
    gemm_core<1,false>(A, Bt, nullptr, C, 1024, 2048, 2048, 1024,
                       blockIdx.y * 128, blockIdx.x * 128, lA, lB);
}

// ---------------- G5 fused: x-partials = out_pair @ W_lin^T (W_lin f32) -----
// 128x128 tile, split-K8 (z: k in [z*384,(z+1)*384)). A bf16 via gload_lds;
// B reg-staged from W_lin f32 (K,N)=(3072,2048) column-reads, cvt->bf16,
// XOR-swizzled LDS write+read (gemm8-proven pattern).
__global__ __launch_bounds__(256) void gemm5f_kernel(
    const unsigned short* __restrict__ A, const float* __restrict__ Wlin,
    float* __restrict__ P)
{
    __shared__ unsigned short lA[8192];
    __shared__ unsigned short lB[8192];
    const int tid = threadIdx.x;
    const int lane = tid & 63, wave = tid >> 6;
    const int wr = wave >> 1, wc = wave & 1;
    const int m0 = blockIdx.y * 128, n0 = blockIdx.x * 128;
    const int koff = blockIdx.z * 384;
    const int srow = tid >> 3, schunk = tid & 7;
    const int lm = lane & 15, lk = (lane >> 4) * 8;
    const int bcol = tid & 127, bkg = tid >> 7;    // B: col 0..127, k-half 0..1
    const int bsw  = (bcol & 7) << 4;

    f32x4 acc[4][4];
    #pragma unroll
    for (int m = 0; m < 4; ++m)
        #pragma unroll
        for (int n = 0; n < 4; ++n) { f32x4 z = {0.f,0.f,0.f,0.f}; acc[m][n] = z; }

    const unsigned short* Ag = A + (size_t)(m0 + srow) * 3072 + koff + schunk * 8;
    char* lap = (char*)lA + tid * 16;

    for (int t = 0; t < 6; ++t) {
        #pragma unroll
        for (int i = 0; i < 4; ++i)
            gload16(Ag + (size_t)(32 * i) * 3072 + t * 64, lap + i * 4096);
        #pragma unroll
        for (int hh = 0; hh < 2; ++hh) {
            const int kbase = koff + t * 64 + bkg * 32 + hh * 16;
            ushort8 o0, o1;
            #pragma unroll
            for (int j = 0; j < 8; ++j)
                o0[j] = f2bf(Wlin[(size_t)(kbase + j) * 2048 + n0 + bcol]);
            #pragma unroll
            for (int j = 0; j < 8; ++j)
                o1[j] = f2bf(Wlin[(size_t)(kbase + 8 + j) * 2048 + n0 + bcol]);
            char* base = (char*)lB + bcol * 128;
            *(ushort8*)(base + ((bkg * 64 + hh * 32)      ^ bsw)) = o0;
            *(ushort8*)(base + ((bkg * 64 + hh * 32 + 16) ^ bsw)) = o1;
        }
        __syncthreads();
        #pragma unroll
        for (int kk = 0; kk < 2; ++kk) {
            bf16x8 af[4], bv[4];
            #pragma unroll
            for (int m = 0; m < 4; ++m)
                af[m] = *(const bf16x8*)((const char*)lA +
                          (wr * 64 + m * 16 + lm) * 128 + (kk * 32 + lk) * 2);
            #pragma unroll
            for (int n = 0; n < 4; ++n) {
                int rr = wc * 64 + n * 16 + lm;
                bv[n] = *(const bf16x8*)((const char*)lB +
                          rr * 128 + (((kk * 32 + lk) * 2) ^ ((rr & 7) << 4)));
            }
            #pragma unroll
            for (int m = 0; m < 4; ++m)
                #pragma unroll
                for (int n = 0; n < 4; ++n)
                    acc[m][n] = __builtin_amdgcn_mfma_f32_16x16x32_bf16(
                        af[m], bv[n], acc[m][n], 0, 0, 0);
        }
        __syncthreads();
    }

    float* C = P + (size_t)blockIdx.z * 524288;
    const int rbase = m0 + wr * 64 + (lane >> 4) * 4;
    const int cbase = n0 + wc * 64 + lm;
    #pragma unroll
    for (int m = 0; m < 4; ++m)
        #pragma unroll
        for (int n = 0; n < 4; ++n)
            #pragma unroll
            for (int j = 0; j < 4; ++j)
                C[(size_t)(rbase + m * 16 + j) * 2048 + cbase + n * 16] = acc[m][n][j];
}

// ---------------- G6+G7 fused: gi/gh partials, B from f32 (N,K) row-major ---
// z = g*4+s (g: 0=gi(W_ih), 1=gh(W_hh)); split-K4. A bf16 gload_lds;
// B reg-staged from f32 rows (already (N,K)), cvt->bf16, swizzled LDS.
__global__ __launch_bounds__(256) void gemm67f_kernel(
    const unsigned short* __restrict__ xb, const unsigned short* __restrict__ hb,
    const float* __restrict__ Wih, const float* __restrict__ Whh,
    float* __restrict__ pg)
{
    __shared__ unsigned short lA[8192];
    __shared__ unsigned short lB[8192];
    const int tid = threadIdx.x;
    const int lane = tid & 63, wave = tid >> 6;
    const int wr = wave >> 1, wc = wave & 1;
    const int g = blockIdx.z >> 2, s = blockIdx.z & 3;
    const unsigned short* A = g ? hb : xb;
    const float* Bf = g ? Whh : Wih;
    const int sA   = g ? 1024 : 2048;
    const int koff = g ? s * 256 : s * 512;
    const int nt   = g ? 4 : 8;                    // kLen/64
    const int m0 = blockIdx.y * 128, n0 = blockIdx.x * 128;
    const int srow = tid >> 3, schunk = tid & 7;
    const int lm = lane & 15, lk = (lane >> 4) * 8;
    const int bsw = (srow & 7) << 4;               // (row&7), rows srow+32i

    f32x4 acc[4][4];
    #pragma unroll
    for (int m = 0; m < 4; ++m)
        #pragma unroll
        for (int n = 0; n < 4; ++n) { f32x4 z = {0.f,0.f,0.f,0.f}; acc[m][n] = z; }

    const unsigned short* Ag = A  + (size_t)(m0 + srow) * sA + koff + schunk * 8;
    const float*          Bg = Bf + (size_t)(n0 + srow) * sA + koff + schunk * 8;
    char* lap = (char*)lA + tid * 16;

    for (int t = 0; t < nt; ++t) {
        #pragma unroll
        for (int i = 0; i < 4; ++i)
            gload16(Ag + (size_t)(32 * i) * sA + t * 64, lap + i * 4096);
        #pragma unroll
        for (int i = 0; i < 4; ++i) {
            const float* src = Bg + (size_t)(32 * i) * sA + t * 64;
            float4 v0 = *(const float4*)(src);
            float4 v1 = *(const float4*)(src + 4);
            ushort8 o;
            o[0] = f2bf(v0.x); o[1] = f2bf(v0.y); o[2] = f2bf(v0.z); o[3] = f2bf(v0.w);
            o[4] = f2bf(v1.x); o[5] = f2bf(v1.y); o[6] = f2bf(v1.z); o[7] = f2bf(v1.w);
            *(ushort8*)((char*)lB + (srow + 32 * i) * 128 + ((schunk * 16) ^ bsw)) = o;
        }
        __syncthreads();
        #pragma unroll
        for (int kk = 0; kk < 2; ++kk) {
            bf16x8 af[4], bv[4];
            #pragma unroll
            for (int m = 0; m < 4; ++m)
                af[m] = *(const bf16x8*)((const char*)lA +
                          (wr * 64 + m * 16 + lm) * 128 + (kk * 32 + lk) * 2);
            #pragma unroll
            for (int n = 0; n < 4; ++n) {
                int rr = wc * 64 + n * 16 + lm;
                bv[n] = *(const bf16x8*)((const char*)lB +
                          rr * 128 + (((kk * 32 + lk) * 2) ^ ((rr & 7) << 4)));
            }
            #pragma unroll
            for (int m = 0; m < 4; ++m)
                #pragma unroll
                for (int n = 0; n < 4; ++n)
                    acc[m][n] = __builtin_amdgcn_mfma_f32_16x16x32_bf16(
                        af[m], bv[n], acc[m][n], 0, 0, 0);
        }
        __syncthreads();
    }

    float* C = pg + (size_t)blockIdx.z * 786432;
    const int rbase = m0 + wr * 64 + (lane >> 4) * 4;
    const int cbase = n0 + wc * 64 + lm;
    #pragma unroll
    for (int m = 0; m < 4; ++m)
        #pragma unroll
        for (int n = 0; n < 4; ++n)
            #pragma unroll
            for (int j = 0; j < 4; ++j)
                C[(size_t)(rbase + m * 16 + j) * 3072 + cbase + n * 16] = acc[m][n][j];
}

// ---------------- G8 fused: logits = hnewb @ W_out(f32,(K,N)) + b_out -------
// 256x64 tile, 4 waves stacked on M, grid 500.
__global__ __launch_bounds__(256) void gemm8_kernel(
    const unsigned short* __restrict__ A, const float* __restrict__ Wout,
    const float* __restrict__ bias, float* __restrict__ C)
{
    __shared__ unsigned short lA0[16384]; __shared__ unsigned short lA1[16384];
    __shared__ unsigned short lB0[4096];  __shared__ unsigned short lB1[4096];
    const int tid  = threadIdx.x;
    const int lane = tid & 63, wave = tid >> 6;
    const int n0 = blockIdx.x * 64;
    const int lm = lane & 15, lk = (lane >> 4) * 8;
    const int srow = tid >> 3, schunk = tid & 7;      // A staging
    const int bcol = tid & 63, bkg = tid >> 6;        // B staging (col, k-grp)
    const int bsw  = (bcol & 7) << 4;                 // B LDS XOR swizzle

    f32x4 acc[4][4];
    #pragma unroll
    for (int m = 0; m < 4; ++m)
        #pragma unroll
        for (int n = 0; n < 4; ++n) { f32x4 z = {0.f,0.f,0.f,0.f}; acc[m][n] = z; }

    const unsigned short* Ag = A + (size_t)srow * 1024 + schunk * 8;

    auto stageA = [&](unsigned short* la_, int t) {
        char* la = (char*)la_ + tid * 16;
        #pragma unroll
        for (int i = 0; i < 8; ++i)
            gload16(Ag + (size_t)(32 * i) * 1024 + t * 64, la + i * 4096);
    };
    float bv_[16];
    auto loadB = [&](int t) {
        const float* src = Wout + (size_t)(t * 64 + bkg * 16) * 32000 + n0 + bcol;
        #pragma unroll
        for (int j = 0; j < 16; ++j) bv_[j] = src[(size_t)j * 32000];
    };
    auto writeB = [&](unsigned short* lb_) {
        ushort8 o0, o1;
        #pragma unroll
        for (int j = 0; j < 8; ++j) { o0[j] = f2bf(bv_[j]); o1[j] = f2bf(bv_[j + 8]); }
        char* base = (char*)lb_ + bcol * 128;
        *(ushort8*)(base + ((bkg * 32)      ^ bsw)) = o0;
        *(ushort8*)(base + ((bkg * 32 + 16) ^ bsw)) = o1;
    };
    auto compute = [&](const unsigned short* la_, const unsigned short* lb_) {
        #pragma unroll
        for (int kk = 0; kk < 2; ++kk) {
            bf16x8 af[4], bv[4];
            #pragma unroll
            for (int m = 0; m < 4; ++m)
                af[m] = *(const bf16x8*)((const char*)la_ +
                          (wave * 64 + m * 16 + lm) * 128 + (kk * 32 + lk) * 2);
            #pragma unroll
            for (int n = 0; n < 4; ++n) {
                int rr = n * 16 + lm;
                bv[n] = *(const bf16x8*)((const char*)lb_ +
                          rr * 128 + (((kk * 32 + lk) * 2) ^ ((rr & 7) << 4)));
            }
            #pragma unroll
            for (int m = 0; m < 4; ++m)
                #pragma unroll
                for (int n = 0; n < 4; ++n)
                    acc[m][n] = __builtin_amdgcn_mfma_f32_16x16x32_bf16(
                        af[m], bv[n], acc[m][n], 0, 0, 0);
        }
    };

    stageA(lA0, 0); loadB(0); writeB(lB0);
    __syncthreads();
    const int nt = 16;                                 // K=1024 / 64
    for (int t = 0; t < nt; t += 2) {
        if (t + 1 < nt) { stageA(lA1, t + 1); loadB(t + 1); }
        compute(lA0, lB0);
        if (t + 1 < nt) writeB(lB1);
        __syncthreads();
        if (t + 1 < nt) {
            if (t + 2 < nt) { stageA(lA0, t + 2); loadB(t + 2); }
            compute(lA1, lB1);
            if (t + 2 < nt) writeB(lB0);
            __syncthreads();
        }
    }

    const int rbase = wave * 64 + (lane >> 4) * 4;
    const int cbase = n0 + lm;
    #pragma unroll
    for (int m = 0; m < 4; ++m) {
        #pragma unroll
        for (int n = 0; n < 4; ++n) {
            int col = cbase + n * 16;
            float bvv = bias[col];
            #pragma unroll
            for (int j = 0; j < 4; ++j)
                C[(size_t)(rbase + m * 16 + j) * 32000 + col] = acc[m][n][j] + bvv;
        }
    }
}

// ---------------- ingredient scores: key = keyP0[bm] + keyP1[bm] ------------
__global__ __launch_bounds__(256) void attn_scores2_kernel(
    const float* __restrict__ q, const unsigned short* __restrict__ kP,
    size_t kStride, const float* __restrict__ wa, float* __restrict__ scores)
{
    const int bm = blockIdx.x;          // b*20 + m
    const int b  = bm / 20;
    const int tid = threadIdx.x;
    float4 qv  = ((const float4*)(q + (size_t)b * 1024))[tid];
    ushort4 k0 = ((const ushort4*)(kP + (size_t)bm * 1024))[tid];
    ushort4 k1 = ((const ushort4*)(kP + kStride + (size_t)bm * 1024))[tid];
    float4 wv  = ((const float4*)wa)[tid];
    float p = tanhf(qv.x + bf2f(k0.x) + bf2f(k1.x)) * wv.x
            + tanhf(qv.y + bf2f(k0.y) + bf2f(k1.y)) * wv.y
            + tanhf(qv.z + bf2f(k0.z) + bf2f(k1.z)) * wv.z
            + tanhf(qv.w + bf2f(k0.w) + bf2f(k1.w)) * wv.w;
    #pragma unroll
    for (int off = 32; off > 0; off >>= 1) p += __shfl_down(p, off);
    __shared__ float sp[4];
    if ((tid & 63) == 0) sp[tid >> 6] = p;
    __syncthreads();
    if (tid == 0) scores[bm] = sp[0] + sp[1] + sp[2] + sp[3];
}

// argmax over ingredient scores (first-max tiebreak = jnp) -> ingredient id
__device__ __forceinline__ int argmax_ing(
    const float* __restrict__ sc_i, const int* __restrict__ input_tensor, int b)
{
    float best = sc_i[b * 20]; int bi = 0;
    #pragma unroll
    for (int m = 1; m < 20; ++m) {
        float v = sc_i[b * 20 + m];
        if (v > best) { best = v; bi = m; }
    }
    return input_tensor[b * 20 + bi];
}

// ---------------- pairing scores: gather kpP partial-pair rows by comp_id ---
__global__ __launch_bounds__(256) void attn_scores_gather2_kernel(
    const float* __restrict__ q, const unsigned short* __restrict__ kP,
    size_t kStride, const float* __restrict__ wa, const float* __restrict__ ba,
    const float* __restrict__ sc_i, const int* __restrict__ input_tensor,
    const int* __restrict__ pairing_ids, float* __restrict__ scores)
{
    const int bm = blockIdx.x;          // b*20 + k
    const int b  = bm / 20;
    const int kk = bm - b * 20;
    const int tid = threadIdx.x;
    const int ing = argmax_ing(sc_i, input_tensor, b);
    const int cid = pairing_ids[ing * 20 + kk];
    float4 qv  = ((const float4*)(q + (size_t)b * 1024))[tid];
    ushort4 k0 = ((const ushort4*)(kP + (size_t)cid * 1024))[tid];
    ushort4 k1 = ((const ushort4*)(kP + kStride + (size_t)cid * 1024))[tid];
    float4 wv  = ((const float4*)wa)[tid];
    float p = tanhf(qv.x + bf2f(k0.x) + bf2f(k1.x)) * wv.x
            + tanhf(qv.y + bf2f(k0.y) + bf2f(k1.y)) * wv.y
            + tanhf(qv.z + bf2f(k0.z) + bf2f(k1.z)) * wv.z
            + tanhf(qv.w + bf2f(k0.w) + bf2f(k1.w)) * wv.w;
    #pragma unroll
    for (int off = 32; off > 0; off >>= 1) p += __shfl_down(p, off);
    __shared__ float sp[4];
    if ((tid & 63) == 0) sp[tid >> 6] = p;
    __syncthreads();
    if (tid == 0) scores[bm] = sp[0] + sp[1] + sp[2] + sp[3] + ba[0];
}

// ---------------- out_pair assembly (softmax*s + enc_emb gather folded) -----
__global__ __launch_bounds__(256) void out_pair_kernel(
    const float* __restrict__ s_p, const float* __restrict__ enc_emb,
    const float* __restrict__ sc_i, const int* __restrict__ input_tensor,
    const int* __restrict__ pairing_ids,
    const float* __restrict__ emb_dec, const int* __restrict__ input_ids,
    unsigned short* __restrict__ out_pairb)
{
    const int b = blockIdx.x / 6, seg = blockIdx.x % 6;
    const int tid = threadIdx.x;
    const int d = seg * 512 + tid * 2;
    ushort2 o;
    if (seg < 2) {                       // emb part, d < 1024
        float2 v = *(const float2*)(emb_dec + (size_t)input_ids[b] * 1024 + d);
        o.x = f2bf(v.x); o.y = f2bf(v.y);
    } else {                             // attn_app part: gather enc_emb f32
        const int ing = argmax_ing(sc_i, input_tensor, b);
        __shared__ float s_raw[20];
        if (tid < 20) s_raw[tid] = s_p[b * 20 + tid];
        __syncthreads();
        float mx = -1e30f;
        #pragma unroll
        for (int m = 0; m < 20; ++m) mx = fmaxf(mx, s_raw[m]);
        float den = 0.f; float w[20];
        #pragma unroll
        for (int m = 0; m < 20; ++m) { w[m] = expf(s_raw[m] - mx); den += w[m]; }
        const float inv = 1.f / den;
        const int dd = d - 1024;
        float a0 = 0.f, a1 = 0.f;
        #pragma unroll
        for (int k = 0; k < 20; ++k) {
            const int cid = pairing_ids[ing * 20 + k];
            float2 v = *(const float2*)(enc_emb + (size_t)cid * 2048 + dd);
            float a = w[k] * inv * s_raw[k];           // softmax * raw score
            a0 += a * v.x; a1 += a * v.y;
        }
        o.x = f2bf(a0); o.y = f2bf(a1);
    }
    *(ushort2*)(out_pairb + (size_t)b * 3072 + d) = o;
}

// ---------------- G5 split-K8 reduce + bias -> bf16 x -----------------------
__global__ __launch_bounds__(256) void reduce5_kernel(
    const float* __restrict__ P, const float* __restrict__ bias,
    unsigned short* __restrict__ xb)
{
    int i = blockIdx.x * 256 + threadIdx.x;        // 131072 float4s
    const float4* p = (const float4*)P;
    float4 bb = ((const float4*)bias)[i & 511];
    float s0 = bb.x, s1 = bb.y, s2 = bb.z, s3 = bb.w;
    #pragma unroll
    for (int s = 0; s < 8; ++s) {
        float4 v = p[i + s * 131072];
        s0 += v.x; s1 += v.y; s2 += v.z; s3 += v.w;
    }
    ((ushort4*)xb)[i] = make_ushort4(f2bf(s0), f2bf(s1), f2bf(s2), f2bf(s3));
}

// ---------------- GRU pointwise + split-K8 reduce (gate order r,z,n) --------
__global__ __launch_bounds__(256) void gru_kernel(
    const float* __restrict__ pg, const float* __restrict__ b_ih,
    const float* __restrict__ b_hh, const float* __restrict__ h,
    unsigned short* __restrict__ hnewb)
{
    int idx = blockIdx.x * 256 + threadIdx.x;       // 262144
    int b = idx >> 10, j = idx & 1023;
    float ir = b_ih[j], iz = b_ih[1024 + j], in_ = b_ih[2048 + j];
    float hr = b_hh[j], hz = b_hh[1024 + j], hn  = b_hh[2048 + j];
    #pragma unroll
    for (int s = 0; s < 4; ++s) {
        const float* gi = pg + (size_t)s * 786432 + (size_t)b * 3072;
        ir  += gi[j]; iz += gi[1024 + j]; in_ += gi[2048 + j];
        const float* gh = pg + (size_t)(4 + s) * 786432 + (size_t)b * 3072;
        hr  += gh[j]; hz += gh[1024 + j]; hn  += gh[2048 + j];
    }
    float r = 1.f / (1.f + expf(-(ir + hr)));
    float z = 1.f / (1.f + expf(-(iz + hz)));
    float n = tanhf(in_ + r * hn);
    hnewb[idx] = f2bf((1.f - z) * n + z * h[idx]);
}

// ---------------------------------------------------------------------------
extern "C" void kernel_launch(void* const* d_in, const int* in_sizes, int n_in,
                              void* d_out, int out_size, void* d_ws, size_t ws_size,
                              hipStream_t stream)
{
    const int*   input_ids    = (const int*)  d_in[0];
    const float* hidden       = (const float*)d_in[1];
    const float* enc_out      = (const float*)d_in[2];
    const int*   input_tensor = (const int*)  d_in[3];
    const int*   pairing_ids  = (const int*)  d_in[4];
    const float* emb_dec      = (const float*)d_in[5];
    const float* enc_emb      = (const float*)d_in[6];
    const float* Wq_i  = (const float*)d_in[7];
    const float* Wk_i  = (const float*)d_in[8];
    const float* wa_i  = (const float*)d_in[9];
    const float* Wq_p  = (const float*)d_in[10];
    const float* Wk_p  = (const float*)d_in[11];
    const float* wa_p  = (const float*)d_in[12];
    const float* ba_p  = (const float*)d_in[13];
    const float* W_lin = (const float*)d_in[14];
    const float* b_lin = (const float*)d_in[15];
    const float* W_ih  = (const float*)d_in[16];
    const float* W_hh  = (const float*)d_in[17];
    const float* b_ih  = (const float*)d_in[18];
    const float* b_hh  = (const float*)d_in[19];
    const float* W_out = (const float*)d_in[20];
    const float* b_out = (const float*)d_in[21];

    // ---- workspace layout (time-shared slots, lifetimes serial) ------------
    constexpr size_t OFF_HB    = 0;            // bf16 h, alive all
    constexpr size_t OFF_HNEW  = 524288;       // bf16 h_new, gru..G8
    constexpr size_t OFF_WQI   = 1048576;      // WqiT 2MB (..dual)
    constexpr size_t OFF_WQP   = 3145728;      // WqpT 2MB (..dual)
    constexpr size_t OFF_WKI   = 5242880;      // WkiT 4MB (..gemm24)
    constexpr size_t OFF_WKP   = 9437184;      // WkpT 4MB (..gemm24)
    constexpr size_t OFF_ENC   = 13631488;     // encb 21MB (..gemm24)
    constexpr size_t OFF_SLOT1 = 34603008;     // pq partials (dual..reduceq)
                                               // -> kpP 2x10.5MB (gemm24..scores_p)
                                               // -> outp/pG5/xb
    constexpr size_t OFF_SLOT2 = 55574528;     // encembb (..gemm24)
    constexpr size_t OFF_QUERY = 76546048;     // f32 1MB (..scores_i)
    constexpr size_t OFF_QP    = 77594624;     // f32 1MB (..scores_p)
    constexpr size_t OFF_SCI   = 78643200;     // 24KB
    constexpr size_t OFF_SCP   = 78667776;     // 20KB
    constexpr size_t OFF_PGI   = 1048576;      // G67 partials 8x3MB=24MB
                                               //   ([1M,34.6M) free after gemm24)
    constexpr size_t NEED      = 79167488;
    if (ws_size < NEED) {
        fprintf(stderr, "kernel_launch: ws_size %zu < needed %zu\n", ws_size, NEED);
        return;
    }
    char* ws = (char*)d_ws;
    unsigned short* hb     = (unsigned short*)(ws + OFF_HB);
    unsigned short* hnewb  = (unsigned short*)(ws + OFF_HNEW);
    unsigned short* WqiT   = (unsigned short*)(ws + OFF_WQI);
    unsigned short* WqpT   = (unsigned short*)(ws + OFF_WQP);
    unsigned short* WkiT   = (unsigned short*)(ws + OFF_WKI);
    unsigned short* WkpT   = (unsigned short*)(ws + OFF_WKP);
    unsigned short* encb   = (unsigned short*)(ws + OFF_ENC);
    float*          pqQ    = (float*)         (ws + OFF_SLOT1);          // 4MB
    float*          pqP    = (float*)         (ws + OFF_SLOT1 + 4194304);
    unsigned short* kpP    = (unsigned short*)(ws + OFF_SLOT1);          // after reduceq
    unsigned short* encembb= (unsigned short*)(ws + OFF_SLOT2);
    unsigned short* outp   = (unsigned short*)(ws + OFF_SLOT1);          // after scores_p
    float*          pG5    = (float*)         (ws + OFF_SLOT1 + 1572864);   // 16.8MB
    unsigned short* xb     = (unsigned short*)(ws + OFF_SLOT1 + 18350080);  // 1MB
    float*          query  = (float*)         (ws + OFF_QUERY);
    float*          qp     = (float*)         (ws + OFF_QP);
    float*          sc_i   = (float*)         (ws + OFF_SCI);
    float*          sc_p   = (float*)         (ws + OFF_SCP);
    float*          pgi    = (float*)         (ws + OFF_PGI);
    // key partials live in d_out (32.8MB, fully overwritten by gemm8 later)
    unsigned short* keyP   = (unsigned short*)d_out;

    constexpr size_t KP_STRIDE = 5120 * 1024;   // elements per partial slice

    // 1. prep1: all converts + Wq/Wk transposes (one launch)
    prep1_kernel<<<22032, 256, 0, stream>>>(hidden, enc_out, enc_emb,
                                            Wq_i, Wq_p, Wk_i, Wk_p,
                                            hb, encb, encembb,
                                            WqiT, WqpT, WkiT, WkpT);

    // 2-3. dual split-K4 (partials in SLOT1, dead before gemm24); reduce
    gemm_dual_kernel<<<dim3(8, 2, 8), 256, 0, stream>>>(hb, WqiT, WqpT, pqQ, pqP);
    reduceq_kernel<<<512, 256, 0, stream>>>(pqQ, pqP, query, qp);

    // 4. gemm24 split-K2 x2: kp_all partials -> SLOT1, key partials -> d_out
    gemm24_kernel<<<dim3(8, 40, 4), 256, 0, stream>>>(encembb, encb, WkpT, WkiT,
                                                      kpP, keyP, KP_STRIDE);

    // 5-6. ingredient scores (key partial pair); pairing scores (kp pair + gather)
    attn_scores2_kernel<<<5120, 256, 0, stream>>>(query, keyP, KP_STRIDE, wa_i, sc_i);
    attn_scores_gather2_kernel<<<5120, 256, 0, stream>>>(qp, kpP, KP_STRIDE, wa_p, ba_p,
                                                         sc_i, input_tensor, pairing_ids, sc_p);

    // 7. out_pair = [emb | softmax(s)*s @ enc_emb-gather]  (overwrites kpP)
    out_pair_kernel<<<1536, 256, 0, stream>>>(sc_p, enc_emb, sc_i, input_tensor,
                                              pairing_ids, emb_dec, input_ids, outp);

    // 8-9. G5 fused (W_lin f32 in-GEMM): split-K8 -> reduce -> bf16 x
    gemm5f_kernel<<<dim3(16, 2, 8), 256, 0, stream>>>(outp, W_lin, pG5);
    reduce5_kernel<<<512, 256, 0, stream>>>(pG5, b_lin, xb);

    // 10. G6+G7 fused (W_ih/W_hh f32 in-GEMM), split-K4 each
    gemm67f_kernel<<<dim3(24, 2, 8), 256, 0, stream>>>(xb, hb, W_ih, W_hh, pgi);

    // 11. GRU pointwise (+ split-K8 reduce + biases) -> h_new bf16
    gru_kernel<<<1024, 256, 0, stream>>>(pgi, b_ih, b_hh, hidden, hnewb);

    // 12. G8 fused: logits = h_new @ W_out + b_out (overwrites keyP scratch)
    gemm8_kernel<<<500, 256, 0, stream>>>(hnewb, W_out, b_out, (float*)d_out);
}